// Round 19
// baseline (439.426 us; speedup 1.0000x reference)
//
#include <hip/hip_runtime.h>
#include <hip/hip_bf16.h>
#include <math.h>

#define LRELU 0.2f
#define BN_EPS 1e-5f
#define SN_EPS 1e-12f

typedef __attribute__((ext_vector_type(4))) float f32x4;
typedef __attribute__((ext_vector_type(8))) short bf16x8;
typedef __attribute__((ext_vector_type(4))) short bf16x4;

__device__ inline float bf2f(short s) {
  union { unsigned u; float f; } c; c.u = ((unsigned)(unsigned short)s) << 16; return c.f;
}
__device__ inline short f2bf(float f) {
  __hip_bfloat16 h = __float2bfloat16(f); return *(short*)&h;
}

// XCD-aware bijective block swizzle (requires gridDim.x % 8 == 0)
__device__ inline int xcd_swz(int bx, int nwg) {
  int chunk = nwg >> 3;
  return (bx & 7) * chunk + (bx >> 3);
}

// ---------------------------------------------------------------- reductions
__device__ inline float blockReduceSum256(float v, volatile float* red) {
  #pragma unroll
  for (int o = 32; o > 0; o >>= 1) v += __shfl_down(v, o, 64);
  const int tid = threadIdx.x;
  __syncthreads();
  if ((tid & 63) == 0) red[tid >> 6] = v;
  __syncthreads();
  return red[0] + red[1] + red[2] + red[3];
}

// ---------------------------------------------------------------- spectral norm, parallel 5-stage chain
struct SNArgs {
  const float* w[6];
  const float* u[6];
  int outc[6];
  int ink[6];
};

__global__ __launch_bounds__(256) void sn_v(SNArgs args, float* __restrict__ vpart) {
  const int l = blockIdx.z;
  const int in_k = args.ink[l], out_c = args.outc[l];
  const int tid = threadIdx.x;
  const int j = blockIdx.x * 256 + tid;
  if (blockIdx.x * 256 >= in_k) return;
  const int rows = out_c >> 3;
  const int i0 = blockIdx.y * rows;
  __shared__ float uS[64];
  if (tid < rows) uS[tid] = args.u[l][i0 + tid];
  __syncthreads();
  if (j >= in_k) return;
  const float* __restrict__ w = args.w[l] + (size_t)i0 * in_k;
  float t = 0.f;
  for (int i = 0; i < rows; ++i) t = fmaf(w[(size_t)i * in_k + j], uS[i], t);
  vpart[((size_t)(l * 8 + blockIdx.y)) * 8192 + j] = t;
}

__global__ __launch_bounds__(256) void sn_v_red(SNArgs args, const float* __restrict__ vpart,
                                                float* __restrict__ vbuf, float* __restrict__ pA) {
  const int l = blockIdx.y;
  const int in_k = args.ink[l];
  const int tid = threadIdx.x;
  const int j = blockIdx.x * 256 + tid;
  __shared__ float red[4];
  float s = 0.f;
  if (j < in_k) {
    #pragma unroll
    for (int ch = 0; ch < 8; ++ch)
      s += vpart[((size_t)(l * 8 + ch)) * 8192 + j];
    vbuf[l * 8192 + j] = s;
  }
  const float bs = blockReduceSum256((j < in_k) ? s * s : 0.f, red);
  if (tid == 0) pA[l * 32 + blockIdx.x] = bs;
}

__global__ __launch_bounds__(64) void sn_norm1(SNArgs args, const float* __restrict__ pA,
                                               float* __restrict__ rinv) {
  const int l = blockIdx.x;
  if (threadIdx.x != 0) return;
  const int nb = (args.ink[l] + 255) >> 8;
  float s = 0.f;
  for (int b = 0; b < nb; ++b) s += pA[l * 32 + b];
  rinv[l] = 1.f / (sqrtf(s) + SN_EPS);
}

__global__ __launch_bounds__(256) void sn_t2(SNArgs args, const float* __restrict__ vbuf,
                                             const float* __restrict__ rinv,
                                             float* __restrict__ pB) {
  const int l = blockIdx.y;
  const int in_k = args.ink[l], out_c = args.outc[l];
  const int lane = threadIdx.x & 63, wv = threadIdx.x >> 6;
  const int row = blockIdx.x * 4 + wv;
  __shared__ float red[4];
  float sq = 0.f;
  if (row < out_c) {
    const float* __restrict__ wr = args.w[l] + (size_t)row * in_k;
    const float* __restrict__ v = vbuf + l * 8192;
    float a0 = 0.f, a1 = 0.f, a2 = 0.f, a3 = 0.f;
    for (int j = lane * 4; j < in_k; j += 256) {
      f32x4 w4 = *(const f32x4*)(wr + j);
      f32x4 v4 = *(const f32x4*)(v + j);
      a0 = fmaf(w4[0], v4[0], a0);
      a1 = fmaf(w4[1], v4[1], a1);
      a2 = fmaf(w4[2], v4[2], a2);
      a3 = fmaf(w4[3], v4[3], a3);
    }
    float t = (a0 + a1) + (a2 + a3);
    #pragma unroll
    for (int o = 32; o > 0; o >>= 1) t += __shfl_down(t, o, 64);
    if (lane == 0) { t *= rinv[l]; sq = t * t; }
  }
  __syncthreads();
  if (lane == 0) red[wv] = sq;
  __syncthreads();
  if (threadIdx.x == 0) pB[l * 128 + blockIdx.x] = red[0] + red[1] + red[2] + red[3];
}

__global__ __launch_bounds__(64) void sn_norm2(const float* __restrict__ pB,
                                               float* __restrict__ inv_sigma) {
  const int l = blockIdx.x;
  if (threadIdx.x != 0) return;
  float s = 0.f;
  for (int b = 0; b < 128; ++b) s += pB[l * 128 + b];
  const float n2 = sqrtf(s);
  const float sigma = s / (n2 + SN_EPS);
  inv_sigma[l] = 1.f / sigma;
}

// ---------------------------------------------------------------- zero the OOB pad regions
__global__ __launch_bounds__(256) void zero_pads(__hip_bfloat16* r0, __hip_bfloat16* r1) {
  int t = blockIdx.x * 256 + threadIdx.x;
  if (t < 2048) {
    r0[16777216 + t] = __float2bfloat16(0.f);
    r1[16777216 + t] = __float2bfloat16(0.f);
  }
}

// ---------------------------------------------------------------- batched weight prepack (all 6 layers, 1 dispatch)
struct PPArgs {
  const float* w[6];
  __hip_bfloat16* dst[6];
  int cinr[6];
  int cout[6];
  int kpad[6];
  int kreal[6];
};

__global__ __launch_bounds__(256) void prepack_all(PPArgs args, const float* __restrict__ invs) {
  const int l = blockIdx.y;
  int e = blockIdx.x * 256 + threadIdx.x;
  const int total = args.kpad[l] * args.cout[l];
  if (e >= total) return;
  const int CINR = args.cinr[l], COUT = args.cout[l], KREAL = args.kreal[l];
  int j = e & 7, lane = (e >> 3) & 63, frag = e >> 9;
  int nfrags = COUT >> 4;
  int ks = frag / nfrags, nf = frag - ks * nfrags;
  int k = ks * 32 + ((lane >> 4) << 3) + j;
  int co = (nf << 4) + (lane & 15);
  float val = 0.f;
  if (k < KREAL) {
    int khw = k / CINR, ci = k - khw * CINR;
    int kh = khw >> 2, kw = khw & 3;
    val = args.w[l][(((size_t)co * CINR + ci) * 4 + kh) * 4 + kw] * invs[l];
  }
  args.dst[l][e] = __float2bfloat16(val);
}

// ---------------------------------------------------------------- L1 im2col, coalesced 16B writes
__global__ __launch_bounds__(256) void im2col_l1(const float* __restrict__ img,
                                                 __hip_bfloat16* __restrict__ a2) {
  int t = blockIdx.x * 256 + threadIdx.x;      // 2097152
  int c = t & 7;
  int m = t >> 3;
  int n = m >> 12;
  int hw = m & 4095;
  int ho = hw >> 6, wo = hw & 63;
  int ihb = 2 * ho - 1, iwb = 2 * wo - 1;
  const float* __restrict__ ib = img + (size_t)n * 49152;
  short vals[8];
  #pragma unroll
  for (int j = 0; j < 8; ++j) {
    int k = c * 8 + j;
    float val = 0.f;
    if (k < 48) {
      int khw = k / 3;
      int ci = k - khw * 3;
      int kh = khw >> 2, kw = khw & 3;
      int ih = ihb + kh, iw = iwb + kw;
      if (((unsigned)ih < 128u) & ((unsigned)iw < 128u))
        val = ib[ci * 16384 + ih * 128 + iw];
    }
    vals[j] = f2bf(val);
  }
  *(bf16x8*)(a2 + (size_t)m * 64 + c * 8) = *(bf16x8*)vals;
}

// ---------------------------------------------------------------- L1 MFMA GEMM (1x1 over pre-im2col'd A), XCD-swizzled
template<int CIN, int COUT, int MF, bool FUSE>
__global__ __launch_bounds__(256) void conv_mfma(
    const __hip_bfloat16* __restrict__ x,
    const __hip_bfloat16* __restrict__ wf,
    __hip_bfloat16* __restrict__ out)
{
  constexpr int CB = CIN / 32;

  const int bx = xcd_swz(blockIdx.x, gridDim.x);
  const int lane = threadIdx.x & 63;
  const int wid  = threadIdx.x >> 6;
  const int wm = wid >> 1, wn = wid & 1;
  const int mbase = bx * (MF * 32) + wm * (MF * 16);
  const int cobase = blockIdx.y * 64 + wn * 32;

  int offm[MF];
  #pragma unroll
  for (int mf = 0; mf < MF; ++mf) {
    int m = mbase + mf * 16 + (lane & 15);
    offm[mf] = m * CIN;
  }
  const int koff = (lane >> 4) << 3;
  const __hip_bfloat16* wfp = wf + ((size_t)((blockIdx.y * 4 + wn * 2) * 64 + lane)) * 8;

  f32x4 acc[MF][2];
  #pragma unroll
  for (int mf = 0; mf < MF; ++mf) {
    acc[mf][0] = (f32x4){0.f, 0.f, 0.f, 0.f};
    acc[mf][1] = (f32x4){0.f, 0.f, 0.f, 0.f};
  }

  #pragma unroll
  for (int cb = 0; cb < CB; ++cb) {
    bf16x8 a[MF], b[2];
    #pragma unroll
    for (int mf = 0; mf < MF; ++mf) a[mf] = *(const bf16x8*)(x + offm[mf] + koff + cb * 32);
    #pragma unroll
    for (int nf = 0; nf < 2; ++nf)
      b[nf] = *(const bf16x8*)(wfp + (size_t)cb * (COUT * 32) + nf * 512);
    #pragma unroll
    for (int mf = 0; mf < MF; ++mf)
      #pragma unroll
      for (int nf = 0; nf < 2; ++nf)
        acc[mf][nf] = __builtin_amdgcn_mfma_f32_16x16x32_bf16(a[mf], b[nf], acc[mf][nf], 0, 0, 0);
  }

  const int r0 = (lane >> 4) * 4;
  const int cw = cobase + (lane & 15);
  #pragma unroll
  for (int mf = 0; mf < MF; ++mf)
    #pragma unroll
    for (int nf = 0; nf < 2; ++nf)
      #pragma unroll
      for (int r = 0; r < 4; ++r) {
        float v = acc[mf][nf][r];
        if (FUSE) v = (v >= 0.f) ? v : LRELU * v;
        int m = mbase + mf * 16 + r0 + r;
        out[(size_t)m * COUT + (cw + nf * 16)] = __float2bfloat16(v);
      }
}

// ---------------------------------------------------------------- 4x4-fragment implicit-GEMM conv, k4 s2 p1
// XCD-swizzled. BNIN: applies per-channel scale/bias + lrelu to A fragments
// (consumer-side BN fusion); cb-outer loop hoists the 16 sb registers.
template<int CIN, int COUT, int HIN, int HOUT, int Z, bool SPLITK, bool BNIN>
__global__ __launch_bounds__(256) void conv_mfma4(
    const __hip_bfloat16* __restrict__ x,
    const __hip_bfloat16* __restrict__ wf,
    const float* __restrict__ sbp,
    __hip_bfloat16* __restrict__ outb, float* __restrict__ outp)
{
  constexpr int WIN = HIN, WO = HOUT;
  constexpr int CB = CIN / 32;
  constexpr int KHW_PER = 16 / Z;
  constexpr int PADOFF = 16777216;
  constexpr int M = 64 * HOUT * WO;

  const int bx = xcd_swz(blockIdx.x, gridDim.x);
  const int lane = threadIdx.x & 63;
  const int wid  = threadIdx.x >> 6;
  const int wm = wid >> 1, wn = wid & 1;
  const int mbase = bx * 128 + wm * 64;
  const int nbase = blockIdx.y * 128 + wn * 64;
  const int khw0 = blockIdx.z * KHW_PER;

  int offm[4], ihb[4], iwb[4];
  #pragma unroll
  for (int mf = 0; mf < 4; ++mf) {
    int m = mbase + mf * 16 + (lane & 15);
    int n = m / (HOUT * WO);
    int hw = m - n * (HOUT * WO);
    int ho = hw / WO, wo = hw - ho * WO;
    ihb[mf] = 2 * ho - 1;
    iwb[mf] = 2 * wo - 1;
    offm[mf] = ((n * HIN + ihb[mf]) * WIN + iwb[mf]) * CIN;
  }
  const int koff = (lane >> 4) << 3;
  const __hip_bfloat16* wfp = wf + ((size_t)((nbase >> 4) * 64 + lane)) * 8;

  f32x4 acc[4][4];
  #pragma unroll
  for (int mf = 0; mf < 4; ++mf)
    #pragma unroll
    for (int nf = 0; nf < 4; ++nf) acc[mf][nf] = (f32x4){0.f, 0.f, 0.f, 0.f};

  #pragma unroll
  for (int cb = 0; cb < CB; ++cb) {
    f32x4 s0, s1, o0, o1;
    if (BNIN) {
      const int cbase = cb * 32 + koff;
      s0 = *(const f32x4*)(sbp + cbase);
      s1 = *(const f32x4*)(sbp + cbase + 4);
      o0 = *(const f32x4*)(sbp + CIN + cbase);
      o1 = *(const f32x4*)(sbp + CIN + cbase + 4);
    }
    #pragma unroll
    for (int ki = 0; ki < KHW_PER; ++ki) {
      const int khw = khw0 + ki;
      const int kh = khw >> 2, kw = khw & 3;
      bf16x8 a[4], b[4];
      bool vm[4];
      #pragma unroll
      for (int mf = 0; mf < 4; ++mf) {
        int ih = ihb[mf] + kh, iw = iwb[mf] + kw;
        vm[mf] = ((unsigned)ih < (unsigned)HIN) & ((unsigned)iw < (unsigned)WIN);
        int off = vm[mf] ? (offm[mf] + (kh * WIN + kw) * CIN + koff + cb * 32)
                         : (PADOFF + koff + cb * 32);
        a[mf] = *(const bf16x8*)(x + off);
      }
      const size_t ks = (size_t)khw * CB + cb;
      #pragma unroll
      for (int nf = 0; nf < 4; ++nf)
        b[nf] = *(const bf16x8*)(wfp + ks * (COUT * 32) + nf * 512);
      if (BNIN) {
        #pragma unroll
        for (int mf = 0; mf < 4; ++mf) {
          bf16x8 t = a[mf];
          #pragma unroll
          for (int j = 0; j < 8; ++j) {
            float fv = bf2f(t[j]);
            float sc = (j < 4) ? s0[j] : s1[j - 4];
            float of = (j < 4) ? o0[j] : o1[j - 4];
            fv = fmaf(fv, sc, of);
            fv = (fv >= 0.f) ? fv : LRELU * fv;
            t[j] = vm[mf] ? f2bf(fv) : (short)0;
          }
          a[mf] = t;
        }
      }
      #pragma unroll
      for (int mf = 0; mf < 4; ++mf)
        #pragma unroll
        for (int nf = 0; nf < 4; ++nf)
          acc[mf][nf] = __builtin_amdgcn_mfma_f32_16x16x32_bf16(a[mf], b[nf], acc[mf][nf], 0, 0, 0);
    }
  }

  const int r0 = (lane >> 4) * 4;
  const int cw = nbase + (lane & 15);
  #pragma unroll
  for (int mf = 0; mf < 4; ++mf)
    #pragma unroll
    for (int nf = 0; nf < 4; ++nf)
      #pragma unroll
      for (int r = 0; r < 4; ++r) {
        const int m = mbase + mf * 16 + r0 + r;
        const int co = cw + nf * 16;
        if (SPLITK) {
          outp[(size_t)blockIdx.z * M * COUT + (size_t)m * COUT + co] = acc[mf][nf][r];
        } else {
          outb[(size_t)m * COUT + co] = __float2bfloat16(acc[mf][nf][r]);
        }
      }
}

// ---------------------------------------------------------------- fused: split-K reduce + bf16 write + BN partial stats
template<int Z, int MCHUNKS>
__global__ __launch_bounds__(256) void sk_bn_fuse(const float* __restrict__ part,
                                                  __hip_bfloat16* __restrict__ xo,
                                                  float* __restrict__ statp, int M, int C) {
  const int chunk = blockIdx.x;
  const int c0 = blockIdx.y * 64 + (threadIdx.x & 7) * 8;
  const int mrow = threadIdx.x >> 3;
  const int rows = M / MCHUNKS;
  const size_t MC = (size_t)M * C;
  float s[8], s2[8];
  #pragma unroll
  for (int j = 0; j < 8; ++j) { s[j] = 0.f; s2[j] = 0.f; }
  for (int mi = mrow; mi < rows; mi += 32) {
    const int m = chunk * rows + mi;
    const size_t base = (size_t)m * C + c0;
    f32x4 a = *(const f32x4*)(part + base);
    f32x4 b = *(const f32x4*)(part + base + 4);
    #pragma unroll
    for (int z = 1; z < Z; ++z) {
      a += *(const f32x4*)(part + (size_t)z * MC + base);
      b += *(const f32x4*)(part + (size_t)z * MC + base + 4);
    }
    bf16x8 o;
    #pragma unroll
    for (int j = 0; j < 4; ++j) {
      o[j] = f2bf(a[j]);
      o[4 + j] = f2bf(b[j]);
      s[j] += a[j];       s2[j] = fmaf(a[j], a[j], s2[j]);
      s[4+j] += b[j];     s2[4+j] = fmaf(b[j], b[j], s2[4+j]);
    }
    *(bf16x8*)(xo + base) = o;
  }
  __shared__ float ls[8][256], ls2[8][256];
  const int t = threadIdx.x;
  #pragma unroll
  for (int j = 0; j < 8; ++j) { ls[j][t] = s[j]; ls2[j][t] = s2[j]; }
  __syncthreads();
  #pragma unroll
  for (int off = 16; off >= 1; off >>= 1) {
    if (mrow < off) {
      #pragma unroll
      for (int j = 0; j < 8; ++j) {
        ls[j][t]  += ls[j][t + off * 8];
        ls2[j][t] += ls2[j][t + off * 8];
      }
    }
    __syncthreads();
  }
  if (t < 8) {
    #pragma unroll
    for (int j = 0; j < 8; ++j) {
      statp[(size_t)chunk * C + c0 + j] = ls[j][t];
      statp[(size_t)(MCHUNKS + chunk) * C + c0 + j] = ls2[j][t];
    }
  }
}

// ---------------------------------------------------------------- L6 MFMA conv with BN-fused input; writes flat part of out
__global__ __launch_bounds__(256) void conv_l6_mfma(
    const __hip_bfloat16* __restrict__ x,
    const __hip_bfloat16* __restrict__ wf,
    const float* __restrict__ sbp,
    float* __restrict__ x6, float* __restrict__ out)
{
  constexpr int CIN = 512, COUT = 64, HIN = 4;
  constexpr int CB = CIN / 32;
  constexpr int PADOFF = 16777216;

  const int lane = threadIdx.x & 63;
  const int wid  = threadIdx.x >> 6;
  const int wm = wid >> 1, wn = wid & 1;
  const int mbase = blockIdx.x * 32 + wm * 16;

  int m0 = mbase + (lane & 15);
  int n = m0 >> 2;
  int hw = m0 & 3;
  int ho = hw >> 1, wo = hw & 1;
  int ihb = 2 * ho - 1;
  int iwb = 2 * wo - 1;
  int offm = ((n * HIN + ihb) * HIN + iwb) * CIN;

  const int koff = (lane >> 4) << 3;
  const __hip_bfloat16* wfp = wf + ((size_t)((wn * 2) * 64 + lane)) * 8;

  f32x4 acc[2];
  acc[0] = (f32x4){0.f, 0.f, 0.f, 0.f};
  acc[1] = (f32x4){0.f, 0.f, 0.f, 0.f};

  #pragma unroll
  for (int cb = 0; cb < CB; ++cb) {
    const int cbase = cb * 32 + koff;
    f32x4 s0 = *(const f32x4*)(sbp + cbase);
    f32x4 s1 = *(const f32x4*)(sbp + cbase + 4);
    f32x4 o0 = *(const f32x4*)(sbp + CIN + cbase);
    f32x4 o1 = *(const f32x4*)(sbp + CIN + cbase + 4);
    #pragma unroll
    for (int khw = 0; khw < 16; ++khw) {
      const int kh = khw >> 2, kw = khw & 3;
      const int ih = ihb + kh, iw = iwb + kw;
      const bool v = ((unsigned)ih < (unsigned)HIN) & ((unsigned)iw < (unsigned)HIN);
      const int off = v ? (offm + (kh * HIN + kw) * CIN + koff + cb * 32)
                        : (PADOFF + koff + cb * 32);
      bf16x8 a = *(const bf16x8*)(x + off);
      #pragma unroll
      for (int j = 0; j < 8; ++j) {
        float fv = bf2f(a[j]);
        float sc = (j < 4) ? s0[j] : s1[j - 4];
        float of = (j < 4) ? o0[j] : o1[j - 4];
        fv = fmaf(fv, sc, of);
        fv = (fv >= 0.f) ? fv : LRELU * fv;
        a[j] = v ? f2bf(fv) : (short)0;
      }
      const size_t ks = (size_t)khw * CB + cb;
      bf16x8 b0 = *(const bf16x8*)(wfp + ks * (COUT * 32));
      bf16x8 b1 = *(const bf16x8*)(wfp + ks * (COUT * 32) + 512);
      acc[0] = __builtin_amdgcn_mfma_f32_16x16x32_bf16(a, b0, acc[0], 0, 0, 0);
      acc[1] = __builtin_amdgcn_mfma_f32_16x16x32_bf16(a, b1, acc[1], 0, 0, 0);
    }
  }

  const int r0 = (lane >> 4) * 4;
  const int cw = wn * 32 + (lane & 15);
  #pragma unroll
  for (int nf = 0; nf < 2; ++nf)
    #pragma unroll
    for (int r = 0; r < 4; ++r) {
      int m = mbase + r0 + r;
      int nn = m >> 2, p = m & 3;
      float v = acc[nf][r];
      x6[(size_t)nn * 256 + (cw + nf * 16) * 4 + p] = v;
      out[(size_t)nn * 320 + (cw + nf * 16) * 4 + p] = v;
    }
}

// ---------------------------------------------------------------- BN stats (direct-output layers), vectorized
template<int MCHUNKS>
__global__ __launch_bounds__(256) void bn_stats_a(const __hip_bfloat16* __restrict__ x,
                                                  float* __restrict__ part, int M, int C) {
  const int chunk = blockIdx.x;
  const int c0 = blockIdx.y * 64 + (threadIdx.x & 7) * 8;
  const int mrow = threadIdx.x >> 3;
  const int rows = M / MCHUNKS;
  float s[8], s2[8];
  #pragma unroll
  for (int j = 0; j < 8; ++j) { s[j] = 0.f; s2[j] = 0.f; }
  for (int mi = mrow; mi < rows; mi += 32) {
    const int m = chunk * rows + mi;
    bf16x8 v = *(const bf16x8*)(x + (size_t)m * C + c0);
    #pragma unroll
    for (int j = 0; j < 8; ++j) {
      float f = bf2f(v[j]);
      s[j] += f;
      s2[j] = fmaf(f, f, s2[j]);
    }
  }
  __shared__ float ls[8][256], ls2[8][256];
  const int t = threadIdx.x;
  #pragma unroll
  for (int j = 0; j < 8; ++j) { ls[j][t] = s[j]; ls2[j][t] = s2[j]; }
  __syncthreads();
  #pragma unroll
  for (int off = 16; off >= 1; off >>= 1) {
    if (mrow < off) {
      #pragma unroll
      for (int j = 0; j < 8; ++j) {
        ls[j][t]  += ls[j][t + off * 8];
        ls2[j][t] += ls2[j][t + off * 8];
      }
    }
    __syncthreads();
  }
  if (t < 8) {
    #pragma unroll
    for (int j = 0; j < 8; ++j) {
      part[(size_t)chunk * C + c0 + j] = ls[j][t];
      part[(size_t)(MCHUNKS + chunk) * C + c0 + j] = ls2[j][t];
    }
  }
}

template<int MCHUNKS>
__global__ __launch_bounds__(64) void bn_stats_b(const float* __restrict__ part,
                                                 const float* __restrict__ g,
                                                 const float* __restrict__ b,
                                                 float* __restrict__ sb, int M, int C) {
  int c = blockIdx.x * 64 + threadIdx.x;
  float s = 0.f, s2 = 0.f;
  for (int ch = 0; ch < MCHUNKS; ++ch) {
    s  += part[(size_t)ch * C + c];
    s2 += part[(size_t)(MCHUNKS + ch) * C + c];
  }
  float invM = 1.f / (float)M;
  float mean = s * invM;
  float var = s2 * invM - mean * mean;
  float scale = g[c] * rsqrtf(var + BN_EPS);
  sb[c] = scale;
  sb[C + c] = b[c] - mean * scale;
}

// ---------------------------------------------------------------- tail: Ms = flat @ T (256 blocks)
__global__ __launch_bounds__(256) void ms_kernel(const float* __restrict__ x6,
                                                 const float* __restrict__ T,
                                                 float* __restrict__ Ms) {
  const int cb = blockIdx.x;
  const int nb = blockIdx.y;
  const int c  = threadIdx.x & 63;
  const int ns = threadIdx.x >> 6;
  __shared__ float fsh[16][256];
  for (int t = threadIdx.x; t < 4096; t += 256) {
    int n = t >> 8, a = t & 255;
    fsh[n][a] = x6[(size_t)(nb * 16 + n) * 256 + a];
  }
  __syncthreads();
  const int col = cb * 64 + c;
  float acc0 = 0.f, acc1 = 0.f, acc2 = 0.f, acc3 = 0.f;
  #pragma unroll 8
  for (int a = 0; a < 256; ++a) {
    float tv = T[(size_t)a * 4096 + col];
    acc0 = fmaf(fsh[ns * 4 + 0][a], tv, acc0);
    acc1 = fmaf(fsh[ns * 4 + 1][a], tv, acc1);
    acc2 = fmaf(fsh[ns * 4 + 2][a], tv, acc2);
    acc3 = fmaf(fsh[ns * 4 + 3][a], tv, acc3);
  }
  const int nbase = nb * 16 + ns * 4;
  Ms[(size_t)(nbase + 0) * 4096 + col] = acc0;
  Ms[(size_t)(nbase + 1) * 4096 + col] = acc1;
  Ms[(size_t)(nbase + 2) * 4096 + col] = acc2;
  Ms[(size_t)(nbase + 3) * 4096 + col] = acc3;
}

// ---------------------------------------------------------------- minibatch discrimination (256 blocks)
__global__ __launch_bounds__(256) void mbd_kernel(const float* __restrict__ Ms,
                                                  float* __restrict__ out) {
  const int b  = blockIdx.x;
  const int ib = blockIdx.y;
  const int tid = threadIdx.x;
  __shared__ float Mb[64][65];
  for (int idx = tid; idx < 4096; idx += 256) {
    const int i = idx >> 6, cc = idx & 63;
    Mb[i][cc] = Ms[(size_t)i * 4096 + b * 64 + cc];
  }
  __syncthreads();
  const int i  = ib * 16 + (tid >> 4);
  const int jg = tid & 15;
  float ssum = 0.f;
  for (int j = jg; j < 64; j += 16) {
    float d = 0.f;
    #pragma unroll
    for (int cc = 0; cc < 64; ++cc) d += fabsf(Mb[i][cc] - Mb[j][cc]);
    ssum += expf(-d);
  }
  ssum += __shfl_xor(ssum, 1, 64);
  ssum += __shfl_xor(ssum, 2, 64);
  ssum += __shfl_xor(ssum, 4, 64);
  ssum += __shfl_xor(ssum, 8, 64);
  if (jg == 0) out[(size_t)i * 320 + 256 + b] = ssum;
}

// ---------------------------------------------------------------- launch
extern "C" void kernel_launch(void* const* d_in, const int* in_sizes, int n_in,
                              void* d_out, int out_size, void* d_ws, size_t ws_size,
                              hipStream_t stream) {
  const float* image = (const float*)d_in[0];
  const float* W[6] = {(const float*)d_in[1], (const float*)d_in[3], (const float*)d_in[5],
                       (const float*)d_in[7], (const float*)d_in[9], (const float*)d_in[11]};
  const float* U[6] = {(const float*)d_in[2], (const float*)d_in[4], (const float*)d_in[6],
                       (const float*)d_in[8], (const float*)d_in[10], (const float*)d_in[12]};
  const float* G[4] = {(const float*)d_in[13], (const float*)d_in[15],
                       (const float*)d_in[17], (const float*)d_in[19]};
  const float* Bb[4] = {(const float*)d_in[14], (const float*)d_in[16],
                        (const float*)d_in[18], (const float*)d_in[20]};
  const float* T = (const float*)d_in[21];
  float* out = (float*)d_out;

  // ---- workspace layout (floats)
  float* f = (float*)d_ws;
  float* inv_sigma = f;                                // 16
  float* part      = f + 1024;                         // 65536
  float* x6        = f + 1024 + 65536 + 1024;          // 16384
  float* Ms        = f + 1024 + 65536 + 1024 + 16384;  // 262144
  float* vbuf      = f + 360448;                       // 49152
  float* pA        = f + 360448 + 49152;               // 256 slots
  float* pB        = pA + 256;                         // 768
  float* rinv      = pB + 768;                         // 16
  float* sbL[4];                                       // per-layer BN scale/bias
  for (int i = 0; i < 4; ++i) sbL[i] = f + 412672 + i * 2048;
  __hip_bfloat16* bfb = (__hip_bfloat16*)(f + 524288);
  const size_t REGION = 16777216 + 2048;
  __hip_bfloat16* region0 = bfb;
  __hip_bfloat16* region1 = region0 + REGION;
  __hip_bfloat16* wf1 = region1 + REGION;
  __hip_bfloat16* wf2 = wf1 + 4096;
  __hip_bfloat16* wf3 = wf2 + 131072;
  __hip_bfloat16* wf4 = wf3 + 524288;
  __hip_bfloat16* wf5 = wf4 + 1048576;
  __hip_bfloat16* wf6 = wf5 + 2097152;
  float* skpart = (float*)(wf6 + 524288);              // 8388608 floats
  float* vpart  = skpart + 8388608;                    // 393216 floats

  __hip_bfloat16* a2col = region0;
  __hip_bfloat16* x1 = region1;
  __hip_bfloat16* x2 = region0;
  __hip_bfloat16* x3 = region1;
  __hip_bfloat16* x4 = region0;
  __hip_bfloat16* x5 = region1;

  zero_pads<<<8, 256, 0, stream>>>(region0, region1);

  SNArgs sa;
  const int outc[6] = {64, 128, 256, 256, 512, 64};
  const int ink[6]  = {48, 1024, 2048, 4096, 4096, 8192};
  for (int l = 0; l < 6; ++l) { sa.w[l] = W[l]; sa.u[l] = U[l]; sa.outc[l] = outc[l]; sa.ink[l] = ink[l]; }

  sn_v<<<dim3(32, 8, 6), 256, 0, stream>>>(sa, vpart);
  sn_v_red<<<dim3(32, 6), 256, 0, stream>>>(sa, vpart, vbuf, pA);
  sn_norm1<<<6, 64, 0, stream>>>(sa, pA, rinv);
  sn_t2<<<dim3(128, 6), 256, 0, stream>>>(sa, vbuf, rinv, pB);
  sn_norm2<<<6, 64, 0, stream>>>(pB, inv_sigma);

  PPArgs pa;
  __hip_bfloat16* wfp_[6] = {wf1, wf2, wf3, wf4, wf5, wf6};
  const int cinr_[6]  = {3, 64, 128, 256, 256, 512};
  const int kpad_[6]  = {64, 1024, 2048, 4096, 4096, 8192};
  const int kreal_[6] = {48, 1024, 2048, 4096, 4096, 8192};
  for (int l = 0; l < 6; ++l) {
    pa.w[l] = W[l]; pa.dst[l] = wfp_[l]; pa.cinr[l] = cinr_[l];
    pa.cout[l] = outc[l]; pa.kpad[l] = kpad_[l]; pa.kreal[l] = kreal_[l];
  }
  prepack_all<<<dim3(8192, 6), 256, 0, stream>>>(pa, inv_sigma);

  im2col_l1<<<8192, 256, 0, stream>>>(image, a2col);

  // L1: [262144 x 64] @ [64 x 64], fused lrelu
  conv_mfma<64, 64, 4, true><<<dim3(2048, 1), 256, 0, stream>>>(a2col, wf1, x1);

  // L2: raw input (lrelu already applied by L1), direct bf16 out
  conv_mfma4<64, 128, 64, 32, 1, false, false><<<dim3(512, 1, 1), 256, 0, stream>>>(x1, wf2, nullptr, x2, nullptr);
  bn_stats_a<256><<<dim3(256, 2), 256, 0, stream>>>(x2, part, 65536, 128);
  bn_stats_b<256><<<2, 64, 0, stream>>>(part, G[0], Bb[0], sbL[0], 65536, 128);

  // L3: BN1+lrelu fused on input; split-K Z=2; fused reduce+stats
  conv_mfma4<128, 256, 32, 16, 2, true, true><<<dim3(128, 2, 2), 256, 0, stream>>>(x2, wf3, sbL[0], nullptr, skpart);
  sk_bn_fuse<2, 128><<<dim3(128, 4), 256, 0, stream>>>(skpart, x3, part, 16384, 256);
  bn_stats_b<128><<<4, 64, 0, stream>>>(part, G[1], Bb[1], sbL[1], 16384, 256);

  // L4: BN2+lrelu fused; split-K Z=8; fused reduce+stats
  conv_mfma4<256, 256, 16, 8, 8, true, true><<<dim3(32, 2, 8), 256, 0, stream>>>(x3, wf4, sbL[1], nullptr, skpart);
  sk_bn_fuse<8, 128><<<dim3(128, 4), 256, 0, stream>>>(skpart, x4, part, 4096, 256);
  bn_stats_b<128><<<4, 64, 0, stream>>>(part, G[2], Bb[2], sbL[2], 4096, 256);

  // L5: BN3+lrelu fused; split-K Z=16; fused reduce+stats
  conv_mfma4<256, 512, 8, 4, 16, true, true><<<dim3(8, 4, 16), 256, 0, stream>>>(x4, wf5, sbL[2], nullptr, skpart);
  sk_bn_fuse<16, 32><<<dim3(32, 8), 256, 0, stream>>>(skpart, x5, part, 1024, 512);
  bn_stats_b<32><<<8, 64, 0, stream>>>(part, G[3], Bb[3], sbL[3], 1024, 512);

  // L6: BN4+lrelu fused on input (+ writes flat part of out)
  conv_l6_mfma<<<8, 256, 0, stream>>>(x5, wf6, sbL[3], x6, out);

  ms_kernel<<<dim3(64, 4), 256, 0, stream>>>(x6, T, Ms);
  mbd_kernel<<<dim3(64, 4), 256, 0, stream>>>(Ms, out);
}

// Round 20
// 365.417 us; speedup vs baseline: 1.2025x; 1.2025x over previous
//
#include <hip/hip_runtime.h>
#include <hip/hip_bf16.h>
#include <math.h>

#define LRELU 0.2f
#define BN_EPS 1e-5f
#define SN_EPS 1e-12f

typedef __attribute__((ext_vector_type(4))) float f32x4;
typedef __attribute__((ext_vector_type(8))) short bf16x8;
typedef __attribute__((ext_vector_type(4))) short bf16x4;

__device__ inline float bf2f(short s) {
  union { unsigned u; float f; } c; c.u = ((unsigned)(unsigned short)s) << 16; return c.f;
}
__device__ inline short f2bf(float f) {
  __hip_bfloat16 h = __float2bfloat16(f); return *(short*)&h;
}

// XCD-aware bijective block swizzle (requires gridDim.x % 8 == 0)
__device__ inline int xcd_swz(int bx, int nwg) {
  int chunk = nwg >> 3;
  return (bx & 7) * chunk + (bx >> 3);
}

// ---------------------------------------------------------------- reductions
__device__ inline float blockReduceSum256(float v, volatile float* red) {
  #pragma unroll
  for (int o = 32; o > 0; o >>= 1) v += __shfl_down(v, o, 64);
  const int tid = threadIdx.x;
  __syncthreads();
  if ((tid & 63) == 0) red[tid >> 6] = v;
  __syncthreads();
  return red[0] + red[1] + red[2] + red[3];
}

// ---------------------------------------------------------------- spectral norm, parallel 5-stage chain
struct SNArgs {
  const float* w[6];
  const float* u[6];
  int outc[6];
  int ink[6];
};

__global__ __launch_bounds__(256) void sn_v(SNArgs args, float* __restrict__ vpart) {
  const int l = blockIdx.z;
  const int in_k = args.ink[l], out_c = args.outc[l];
  const int tid = threadIdx.x;
  const int j = blockIdx.x * 256 + tid;
  if (blockIdx.x * 256 >= in_k) return;
  const int rows = out_c >> 3;
  const int i0 = blockIdx.y * rows;
  __shared__ float uS[64];
  if (tid < rows) uS[tid] = args.u[l][i0 + tid];
  __syncthreads();
  if (j >= in_k) return;
  const float* __restrict__ w = args.w[l] + (size_t)i0 * in_k;
  float t = 0.f;
  for (int i = 0; i < rows; ++i) t = fmaf(w[(size_t)i * in_k + j], uS[i], t);
  vpart[((size_t)(l * 8 + blockIdx.y)) * 8192 + j] = t;
}

__global__ __launch_bounds__(256) void sn_v_red(SNArgs args, const float* __restrict__ vpart,
                                                float* __restrict__ vbuf, float* __restrict__ pA) {
  const int l = blockIdx.y;
  const int in_k = args.ink[l];
  const int tid = threadIdx.x;
  const int j = blockIdx.x * 256 + tid;
  __shared__ float red[4];
  float s = 0.f;
  if (j < in_k) {
    #pragma unroll
    for (int ch = 0; ch < 8; ++ch)
      s += vpart[((size_t)(l * 8 + ch)) * 8192 + j];
    vbuf[l * 8192 + j] = s;
  }
  const float bs = blockReduceSum256((j < in_k) ? s * s : 0.f, red);
  if (tid == 0) pA[l * 32 + blockIdx.x] = bs;
}

__global__ __launch_bounds__(64) void sn_norm1(SNArgs args, const float* __restrict__ pA,
                                               float* __restrict__ rinv) {
  const int l = blockIdx.x;
  if (threadIdx.x != 0) return;
  const int nb = (args.ink[l] + 255) >> 8;
  float s = 0.f;
  for (int b = 0; b < nb; ++b) s += pA[l * 32 + b];
  rinv[l] = 1.f / (sqrtf(s) + SN_EPS);
}

__global__ __launch_bounds__(256) void sn_t2(SNArgs args, const float* __restrict__ vbuf,
                                             const float* __restrict__ rinv,
                                             float* __restrict__ pB) {
  const int l = blockIdx.y;
  const int in_k = args.ink[l], out_c = args.outc[l];
  const int lane = threadIdx.x & 63, wv = threadIdx.x >> 6;
  const int row = blockIdx.x * 4 + wv;
  __shared__ float red[4];
  float sq = 0.f;
  if (row < out_c) {
    const float* __restrict__ wr = args.w[l] + (size_t)row * in_k;
    const float* __restrict__ v = vbuf + l * 8192;
    float a0 = 0.f, a1 = 0.f, a2 = 0.f, a3 = 0.f;
    for (int j = lane * 4; j < in_k; j += 256) {
      f32x4 w4 = *(const f32x4*)(wr + j);
      f32x4 v4 = *(const f32x4*)(v + j);
      a0 = fmaf(w4[0], v4[0], a0);
      a1 = fmaf(w4[1], v4[1], a1);
      a2 = fmaf(w4[2], v4[2], a2);
      a3 = fmaf(w4[3], v4[3], a3);
    }
    float t = (a0 + a1) + (a2 + a3);
    #pragma unroll
    for (int o = 32; o > 0; o >>= 1) t += __shfl_down(t, o, 64);
    if (lane == 0) { t *= rinv[l]; sq = t * t; }
  }
  __syncthreads();
  if (lane == 0) red[wv] = sq;
  __syncthreads();
  if (threadIdx.x == 0) pB[l * 128 + blockIdx.x] = red[0] + red[1] + red[2] + red[3];
}

__global__ __launch_bounds__(64) void sn_norm2(const float* __restrict__ pB,
                                               float* __restrict__ inv_sigma) {
  const int l = blockIdx.x;
  if (threadIdx.x != 0) return;
  float s = 0.f;
  for (int b = 0; b < 128; ++b) s += pB[l * 128 + b];
  const float n2 = sqrtf(s);
  const float sigma = s / (n2 + SN_EPS);
  inv_sigma[l] = 1.f / sigma;
}

// ---------------------------------------------------------------- zero the OOB pad regions
__global__ __launch_bounds__(256) void zero_pads(__hip_bfloat16* r0, __hip_bfloat16* r1) {
  int t = blockIdx.x * 256 + threadIdx.x;
  if (t < 2048) {
    r0[16777216 + t] = __float2bfloat16(0.f);
    r1[16777216 + t] = __float2bfloat16(0.f);
  }
}

// ---------------------------------------------------------------- batched weight prepack (all 6 layers, 1 dispatch)
struct PPArgs {
  const float* w[6];
  __hip_bfloat16* dst[6];
  int cinr[6];
  int cout[6];
  int kpad[6];
  int kreal[6];
};

__global__ __launch_bounds__(256) void prepack_all(PPArgs args, const float* __restrict__ invs) {
  const int l = blockIdx.y;
  int e = blockIdx.x * 256 + threadIdx.x;
  const int total = args.kpad[l] * args.cout[l];
  if (e >= total) return;
  const int CINR = args.cinr[l], COUT = args.cout[l], KREAL = args.kreal[l];
  int j = e & 7, lane = (e >> 3) & 63, frag = e >> 9;
  int nfrags = COUT >> 4;
  int ks = frag / nfrags, nf = frag - ks * nfrags;
  int k = ks * 32 + ((lane >> 4) << 3) + j;
  int co = (nf << 4) + (lane & 15);
  float val = 0.f;
  if (k < KREAL) {
    int khw = k / CINR, ci = k - khw * CINR;
    int kh = khw >> 2, kw = khw & 3;
    val = args.w[l][(((size_t)co * CINR + ci) * 4 + kh) * 4 + kw] * invs[l];
  }
  args.dst[l][e] = __float2bfloat16(val);
}

// ---------------------------------------------------------------- L1 im2col, coalesced 16B writes
__global__ __launch_bounds__(256) void im2col_l1(const float* __restrict__ img,
                                                 __hip_bfloat16* __restrict__ a2) {
  int t = blockIdx.x * 256 + threadIdx.x;      // 2097152
  int c = t & 7;
  int m = t >> 3;
  int n = m >> 12;
  int hw = m & 4095;
  int ho = hw >> 6, wo = hw & 63;
  int ihb = 2 * ho - 1, iwb = 2 * wo - 1;
  const float* __restrict__ ib = img + (size_t)n * 49152;
  short vals[8];
  #pragma unroll
  for (int j = 0; j < 8; ++j) {
    int k = c * 8 + j;
    float val = 0.f;
    if (k < 48) {
      int khw = k / 3;
      int ci = k - khw * 3;
      int kh = khw >> 2, kw = khw & 3;
      int ih = ihb + kh, iw = iwb + kw;
      if (((unsigned)ih < 128u) & ((unsigned)iw < 128u))
        val = ib[ci * 16384 + ih * 128 + iw];
    }
    vals[j] = f2bf(val);
  }
  *(bf16x8*)(a2 + (size_t)m * 64 + c * 8) = *(bf16x8*)vals;
}

// ---------------------------------------------------------------- L1 MFMA GEMM (1x1 over pre-im2col'd A), XCD-swizzled
template<int CIN, int COUT, int MF, bool FUSE>
__global__ __launch_bounds__(256) void conv_mfma(
    const __hip_bfloat16* __restrict__ x,
    const __hip_bfloat16* __restrict__ wf,
    __hip_bfloat16* __restrict__ out)
{
  constexpr int CB = CIN / 32;

  const int bx = xcd_swz(blockIdx.x, gridDim.x);
  const int lane = threadIdx.x & 63;
  const int wid  = threadIdx.x >> 6;
  const int wm = wid >> 1, wn = wid & 1;
  const int mbase = bx * (MF * 32) + wm * (MF * 16);
  const int cobase = blockIdx.y * 64 + wn * 32;

  int offm[MF];
  #pragma unroll
  for (int mf = 0; mf < MF; ++mf) {
    int m = mbase + mf * 16 + (lane & 15);
    offm[mf] = m * CIN;
  }
  const int koff = (lane >> 4) << 3;
  const __hip_bfloat16* wfp = wf + ((size_t)((blockIdx.y * 4 + wn * 2) * 64 + lane)) * 8;

  f32x4 acc[MF][2];
  #pragma unroll
  for (int mf = 0; mf < MF; ++mf) {
    acc[mf][0] = (f32x4){0.f, 0.f, 0.f, 0.f};
    acc[mf][1] = (f32x4){0.f, 0.f, 0.f, 0.f};
  }

  #pragma unroll
  for (int cb = 0; cb < CB; ++cb) {
    bf16x8 a[MF], b[2];
    #pragma unroll
    for (int mf = 0; mf < MF; ++mf) a[mf] = *(const bf16x8*)(x + offm[mf] + koff + cb * 32);
    #pragma unroll
    for (int nf = 0; nf < 2; ++nf)
      b[nf] = *(const bf16x8*)(wfp + (size_t)cb * (COUT * 32) + nf * 512);
    #pragma unroll
    for (int mf = 0; mf < MF; ++mf)
      #pragma unroll
      for (int nf = 0; nf < 2; ++nf)
        acc[mf][nf] = __builtin_amdgcn_mfma_f32_16x16x32_bf16(a[mf], b[nf], acc[mf][nf], 0, 0, 0);
  }

  const int r0 = (lane >> 4) * 4;
  const int cw = cobase + (lane & 15);
  #pragma unroll
  for (int mf = 0; mf < MF; ++mf)
    #pragma unroll
    for (int nf = 0; nf < 2; ++nf)
      #pragma unroll
      for (int r = 0; r < 4; ++r) {
        float v = acc[mf][nf][r];
        if (FUSE) v = (v >= 0.f) ? v : LRELU * v;
        int m = mbase + mf * 16 + r0 + r;
        out[(size_t)m * COUT + (cw + nf * 16)] = __float2bfloat16(v);
      }
}

// ---------------------------------------------------------------- 4x4-fragment implicit-GEMM conv, k4 s2 p1
// XCD-swizzled. BNIN: applies per-channel scale/bias + lrelu to A fragments
// (consumer-side BN fusion); cb-outer loop hoists the 16 sb registers.
template<int CIN, int COUT, int HIN, int HOUT, int Z, bool SPLITK, bool BNIN>
__global__ __launch_bounds__(256) void conv_mfma4(
    const __hip_bfloat16* __restrict__ x,
    const __hip_bfloat16* __restrict__ wf,
    const float* __restrict__ sbp,
    __hip_bfloat16* __restrict__ outb, float* __restrict__ outp)
{
  constexpr int WIN = HIN, WO = HOUT;
  constexpr int CB = CIN / 32;
  constexpr int KHW_PER = 16 / Z;
  constexpr int PADOFF = 16777216;
  constexpr int M = 64 * HOUT * WO;

  const int bx = xcd_swz(blockIdx.x, gridDim.x);
  const int lane = threadIdx.x & 63;
  const int wid  = threadIdx.x >> 6;
  const int wm = wid >> 1, wn = wid & 1;
  const int mbase = bx * 128 + wm * 64;
  const int nbase = blockIdx.y * 128 + wn * 64;
  const int khw0 = blockIdx.z * KHW_PER;

  int offm[4], ihb[4], iwb[4];
  #pragma unroll
  for (int mf = 0; mf < 4; ++mf) {
    int m = mbase + mf * 16 + (lane & 15);
    int n = m / (HOUT * WO);
    int hw = m - n * (HOUT * WO);
    int ho = hw / WO, wo = hw - ho * WO;
    ihb[mf] = 2 * ho - 1;
    iwb[mf] = 2 * wo - 1;
    offm[mf] = ((n * HIN + ihb[mf]) * WIN + iwb[mf]) * CIN;
  }
  const int koff = (lane >> 4) << 3;
  const __hip_bfloat16* wfp = wf + ((size_t)((nbase >> 4) * 64 + lane)) * 8;

  f32x4 acc[4][4];
  #pragma unroll
  for (int mf = 0; mf < 4; ++mf)
    #pragma unroll
    for (int nf = 0; nf < 4; ++nf) acc[mf][nf] = (f32x4){0.f, 0.f, 0.f, 0.f};

  #pragma unroll
  for (int cb = 0; cb < CB; ++cb) {
    f32x4 s0, s1, o0, o1;
    if (BNIN) {
      const int cbase = cb * 32 + koff;
      s0 = *(const f32x4*)(sbp + cbase);
      s1 = *(const f32x4*)(sbp + cbase + 4);
      o0 = *(const f32x4*)(sbp + CIN + cbase);
      o1 = *(const f32x4*)(sbp + CIN + cbase + 4);
    }
    #pragma unroll
    for (int ki = 0; ki < KHW_PER; ++ki) {
      const int khw = khw0 + ki;
      const int kh = khw >> 2, kw = khw & 3;
      bf16x8 a[4], b[4];
      bool vm[4];
      #pragma unroll
      for (int mf = 0; mf < 4; ++mf) {
        int ih = ihb[mf] + kh, iw = iwb[mf] + kw;
        vm[mf] = ((unsigned)ih < (unsigned)HIN) & ((unsigned)iw < (unsigned)WIN);
        int off = vm[mf] ? (offm[mf] + (kh * WIN + kw) * CIN + koff + cb * 32)
                         : (PADOFF + koff + cb * 32);
        a[mf] = *(const bf16x8*)(x + off);
      }
      const size_t ks = (size_t)khw * CB + cb;
      #pragma unroll
      for (int nf = 0; nf < 4; ++nf)
        b[nf] = *(const bf16x8*)(wfp + ks * (COUT * 32) + nf * 512);
      if (BNIN) {
        #pragma unroll
        for (int mf = 0; mf < 4; ++mf) {
          bf16x8 t = a[mf];
          #pragma unroll
          for (int j = 0; j < 8; ++j) {
            float fv = bf2f(t[j]);
            float sc = (j < 4) ? s0[j] : s1[j - 4];
            float of = (j < 4) ? o0[j] : o1[j - 4];
            fv = fmaf(fv, sc, of);
            fv = (fv >= 0.f) ? fv : LRELU * fv;
            t[j] = vm[mf] ? f2bf(fv) : (short)0;
          }
          a[mf] = t;
        }
      }
      #pragma unroll
      for (int mf = 0; mf < 4; ++mf)
        #pragma unroll
        for (int nf = 0; nf < 4; ++nf)
          acc[mf][nf] = __builtin_amdgcn_mfma_f32_16x16x32_bf16(a[mf], b[nf], acc[mf][nf], 0, 0, 0);
    }
  }

  const int r0 = (lane >> 4) * 4;
  const int cw = nbase + (lane & 15);
  #pragma unroll
  for (int mf = 0; mf < 4; ++mf)
    #pragma unroll
    for (int nf = 0; nf < 4; ++nf)
      #pragma unroll
      for (int r = 0; r < 4; ++r) {
        const int m = mbase + mf * 16 + r0 + r;
        const int co = cw + nf * 16;
        if (SPLITK) {
          outp[(size_t)blockIdx.z * M * COUT + (size_t)m * COUT + co] = acc[mf][nf][r];
        } else {
          outb[(size_t)m * COUT + co] = __float2bfloat16(acc[mf][nf][r]);
        }
      }
}

// ---------------------------------------------------------------- fused: split-K reduce + bf16 write + BN partial stats
template<int Z, int MCHUNKS>
__global__ __launch_bounds__(256) void sk_bn_fuse(const float* __restrict__ part,
                                                  __hip_bfloat16* __restrict__ xo,
                                                  float* __restrict__ statp, int M, int C) {
  const int chunk = blockIdx.x;
  const int c0 = blockIdx.y * 64 + (threadIdx.x & 7) * 8;
  const int mrow = threadIdx.x >> 3;
  const int rows = M / MCHUNKS;
  const size_t MC = (size_t)M * C;
  float s[8], s2[8];
  #pragma unroll
  for (int j = 0; j < 8; ++j) { s[j] = 0.f; s2[j] = 0.f; }
  for (int mi = mrow; mi < rows; mi += 32) {
    const int m = chunk * rows + mi;
    const size_t base = (size_t)m * C + c0;
    f32x4 a = *(const f32x4*)(part + base);
    f32x4 b = *(const f32x4*)(part + base + 4);
    #pragma unroll
    for (int z = 1; z < Z; ++z) {
      a += *(const f32x4*)(part + (size_t)z * MC + base);
      b += *(const f32x4*)(part + (size_t)z * MC + base + 4);
    }
    bf16x8 o;
    #pragma unroll
    for (int j = 0; j < 4; ++j) {
      o[j] = f2bf(a[j]);
      o[4 + j] = f2bf(b[j]);
      s[j] += a[j];       s2[j] = fmaf(a[j], a[j], s2[j]);
      s[4+j] += b[j];     s2[4+j] = fmaf(b[j], b[j], s2[4+j]);
    }
    *(bf16x8*)(xo + base) = o;
  }
  __shared__ float ls[8][256], ls2[8][256];
  const int t = threadIdx.x;
  #pragma unroll
  for (int j = 0; j < 8; ++j) { ls[j][t] = s[j]; ls2[j][t] = s2[j]; }
  __syncthreads();
  #pragma unroll
  for (int off = 16; off >= 1; off >>= 1) {
    if (mrow < off) {
      #pragma unroll
      for (int j = 0; j < 8; ++j) {
        ls[j][t]  += ls[j][t + off * 8];
        ls2[j][t] += ls2[j][t + off * 8];
      }
    }
    __syncthreads();
  }
  if (t < 8) {
    #pragma unroll
    for (int j = 0; j < 8; ++j) {
      statp[(size_t)chunk * C + c0 + j] = ls[j][t];
      statp[(size_t)(MCHUNKS + chunk) * C + c0 + j] = ls2[j][t];
    }
  }
}

// ---------------------------------------------------------------- L6 MFMA conv (plain, consumes BN-applied x5); writes flat part of out
__global__ __launch_bounds__(256) void conv_l6_mfma(
    const __hip_bfloat16* __restrict__ x,
    const __hip_bfloat16* __restrict__ wf,
    float* __restrict__ x6, float* __restrict__ out)
{
  constexpr int CIN = 512, COUT = 64, HIN = 4;
  constexpr int CB = CIN / 32;
  constexpr int PADOFF = 16777216;

  const int lane = threadIdx.x & 63;
  const int wid  = threadIdx.x >> 6;
  const int wm = wid >> 1, wn = wid & 1;
  const int mbase = blockIdx.x * 32 + wm * 16;

  int m0 = mbase + (lane & 15);
  int n = m0 >> 2;
  int hw = m0 & 3;
  int ho = hw >> 1, wo = hw & 1;
  int ihb = 2 * ho - 1;
  int iwb = 2 * wo - 1;
  int offm = ((n * HIN + ihb) * HIN + iwb) * CIN;

  const int koff = (lane >> 4) << 3;
  const __hip_bfloat16* wfp = wf + ((size_t)((wn * 2) * 64 + lane)) * 8;

  f32x4 acc[2];
  acc[0] = (f32x4){0.f, 0.f, 0.f, 0.f};
  acc[1] = (f32x4){0.f, 0.f, 0.f, 0.f};

  #pragma unroll
  for (int khw = 0; khw < 16; ++khw) {
    const int kh = khw >> 2, kw = khw & 3;
    const int ih = ihb + kh, iw = iwb + kw;
    const bool v = ((unsigned)ih < (unsigned)HIN) & ((unsigned)iw < (unsigned)HIN);
    const int off = v ? (offm + (kh * HIN + kw) * CIN + koff) : (PADOFF + koff);
    const __hip_bfloat16* ap = x + off;
    #pragma unroll
    for (int cb = 0; cb < CB; ++cb) {
      const int ks = khw * CB + cb;
      bf16x8 a = *(const bf16x8*)(ap + cb * 32);
      bf16x8 b0 = *(const bf16x8*)(wfp + (size_t)ks * (COUT * 32));
      bf16x8 b1 = *(const bf16x8*)(wfp + (size_t)ks * (COUT * 32) + 512);
      acc[0] = __builtin_amdgcn_mfma_f32_16x16x32_bf16(a, b0, acc[0], 0, 0, 0);
      acc[1] = __builtin_amdgcn_mfma_f32_16x16x32_bf16(a, b1, acc[1], 0, 0, 0);
    }
  }

  const int r0 = (lane >> 4) * 4;
  const int cw = wn * 32 + (lane & 15);
  #pragma unroll
  for (int nf = 0; nf < 2; ++nf)
    #pragma unroll
    for (int r = 0; r < 4; ++r) {
      int m = mbase + r0 + r;
      int nn = m >> 2, p = m & 3;
      float v = acc[nf][r];
      x6[(size_t)nn * 256 + (cw + nf * 16) * 4 + p] = v;
      out[(size_t)nn * 320 + (cw + nf * 16) * 4 + p] = v;
    }
}

// ---------------------------------------------------------------- BN stats (direct-output layers), vectorized
template<int MCHUNKS>
__global__ __launch_bounds__(256) void bn_stats_a(const __hip_bfloat16* __restrict__ x,
                                                  float* __restrict__ part, int M, int C) {
  const int chunk = blockIdx.x;
  const int c0 = blockIdx.y * 64 + (threadIdx.x & 7) * 8;
  const int mrow = threadIdx.x >> 3;
  const int rows = M / MCHUNKS;
  float s[8], s2[8];
  #pragma unroll
  for (int j = 0; j < 8; ++j) { s[j] = 0.f; s2[j] = 0.f; }
  for (int mi = mrow; mi < rows; mi += 32) {
    const int m = chunk * rows + mi;
    bf16x8 v = *(const bf16x8*)(x + (size_t)m * C + c0);
    #pragma unroll
    for (int j = 0; j < 8; ++j) {
      float f = bf2f(v[j]);
      s[j] += f;
      s2[j] = fmaf(f, f, s2[j]);
    }
  }
  __shared__ float ls[8][256], ls2[8][256];
  const int t = threadIdx.x;
  #pragma unroll
  for (int j = 0; j < 8; ++j) { ls[j][t] = s[j]; ls2[j][t] = s2[j]; }
  __syncthreads();
  #pragma unroll
  for (int off = 16; off >= 1; off >>= 1) {
    if (mrow < off) {
      #pragma unroll
      for (int j = 0; j < 8; ++j) {
        ls[j][t]  += ls[j][t + off * 8];
        ls2[j][t] += ls2[j][t + off * 8];
      }
    }
    __syncthreads();
  }
  if (t < 8) {
    #pragma unroll
    for (int j = 0; j < 8; ++j) {
      part[(size_t)chunk * C + c0 + j] = ls[j][t];
      part[(size_t)(MCHUNKS + chunk) * C + c0 + j] = ls2[j][t];
    }
  }
}

template<int MCHUNKS>
__global__ __launch_bounds__(64) void bn_stats_b(const float* __restrict__ part,
                                                 const float* __restrict__ g,
                                                 const float* __restrict__ b,
                                                 float* __restrict__ sb, int M, int C) {
  int c = blockIdx.x * 64 + threadIdx.x;
  float s = 0.f, s2 = 0.f;
  for (int ch = 0; ch < MCHUNKS; ++ch) {
    s  += part[(size_t)ch * C + c];
    s2 += part[(size_t)(MCHUNKS + ch) * C + c];
  }
  float invM = 1.f / (float)M;
  float mean = s * invM;
  float var = s2 * invM - mean * mean;
  float scale = g[c] * rsqrtf(var + BN_EPS);
  sb[c] = scale;
  sb[C + c] = b[c] - mean * scale;
}

// ---------------------------------------------------------------- BN apply (only x5 before L6)
__global__ __launch_bounds__(256) void bn_apply(__hip_bfloat16* __restrict__ x,
                                                const float* __restrict__ sb,
                                                int C, int nvec) {
  int idx = blockIdx.x * 256 + threadIdx.x;
  if (idx >= nvec) return;
  size_t e = (size_t)idx * 8;
  int c0 = (int)(e % (size_t)C);
  bf16x8 v = *(bf16x8*)(x + e);
  bf16x8 o;
  #pragma unroll
  for (int j = 0; j < 8; ++j) {
    int c = c0 + j;
    float f = bf2f(v[j]);
    f = fmaf(f, sb[c], sb[C + c]);
    f = (f >= 0.f) ? f : LRELU * f;
    o[j] = f2bf(f);
  }
  *(bf16x8*)(x + e) = o;
}

// ---------------------------------------------------------------- tail: Ms = flat @ T (256 blocks)
__global__ __launch_bounds__(256) void ms_kernel(const float* __restrict__ x6,
                                                 const float* __restrict__ T,
                                                 float* __restrict__ Ms) {
  const int cb = blockIdx.x;
  const int nb = blockIdx.y;
  const int c  = threadIdx.x & 63;
  const int ns = threadIdx.x >> 6;
  __shared__ float fsh[16][256];
  for (int t = threadIdx.x; t < 4096; t += 256) {
    int n = t >> 8, a = t & 255;
    fsh[n][a] = x6[(size_t)(nb * 16 + n) * 256 + a];
  }
  __syncthreads();
  const int col = cb * 64 + c;
  float acc0 = 0.f, acc1 = 0.f, acc2 = 0.f, acc3 = 0.f;
  #pragma unroll 8
  for (int a = 0; a < 256; ++a) {
    float tv = T[(size_t)a * 4096 + col];
    acc0 = fmaf(fsh[ns * 4 + 0][a], tv, acc0);
    acc1 = fmaf(fsh[ns * 4 + 1][a], tv, acc1);
    acc2 = fmaf(fsh[ns * 4 + 2][a], tv, acc2);
    acc3 = fmaf(fsh[ns * 4 + 3][a], tv, acc3);
  }
  const int nbase = nb * 16 + ns * 4;
  Ms[(size_t)(nbase + 0) * 4096 + col] = acc0;
  Ms[(size_t)(nbase + 1) * 4096 + col] = acc1;
  Ms[(size_t)(nbase + 2) * 4096 + col] = acc2;
  Ms[(size_t)(nbase + 3) * 4096 + col] = acc3;
}

// ---------------------------------------------------------------- minibatch discrimination (256 blocks)
__global__ __launch_bounds__(256) void mbd_kernel(const float* __restrict__ Ms,
                                                  float* __restrict__ out) {
  const int b  = blockIdx.x;
  const int ib = blockIdx.y;
  const int tid = threadIdx.x;
  __shared__ float Mb[64][65];
  for (int idx = tid; idx < 4096; idx += 256) {
    const int i = idx >> 6, cc = idx & 63;
    Mb[i][cc] = Ms[(size_t)i * 4096 + b * 64 + cc];
  }
  __syncthreads();
  const int i  = ib * 16 + (tid >> 4);
  const int jg = tid & 15;
  float ssum = 0.f;
  for (int j = jg; j < 64; j += 16) {
    float d = 0.f;
    #pragma unroll
    for (int cc = 0; cc < 64; ++cc) d += fabsf(Mb[i][cc] - Mb[j][cc]);
    ssum += expf(-d);
  }
  ssum += __shfl_xor(ssum, 1, 64);
  ssum += __shfl_xor(ssum, 2, 64);
  ssum += __shfl_xor(ssum, 4, 64);
  ssum += __shfl_xor(ssum, 8, 64);
  if (jg == 0) out[(size_t)i * 320 + 256 + b] = ssum;
}

// ---------------------------------------------------------------- launch
extern "C" void kernel_launch(void* const* d_in, const int* in_sizes, int n_in,
                              void* d_out, int out_size, void* d_ws, size_t ws_size,
                              hipStream_t stream) {
  const float* image = (const float*)d_in[0];
  const float* W[6] = {(const float*)d_in[1], (const float*)d_in[3], (const float*)d_in[5],
                       (const float*)d_in[7], (const float*)d_in[9], (const float*)d_in[11]};
  const float* U[6] = {(const float*)d_in[2], (const float*)d_in[4], (const float*)d_in[6],
                       (const float*)d_in[8], (const float*)d_in[10], (const float*)d_in[12]};
  const float* G[4] = {(const float*)d_in[13], (const float*)d_in[15],
                       (const float*)d_in[17], (const float*)d_in[19]};
  const float* Bb[4] = {(const float*)d_in[14], (const float*)d_in[16],
                        (const float*)d_in[18], (const float*)d_in[20]};
  const float* T = (const float*)d_in[21];
  float* out = (float*)d_out;

  // ---- workspace layout (floats)
  float* f = (float*)d_ws;
  float* inv_sigma = f;                                // 16
  float* part      = f + 1024;                         // 65536
  float* x6        = f + 1024 + 65536 + 1024;          // 16384
  float* Ms        = f + 1024 + 65536 + 1024 + 16384;  // 262144
  float* vbuf      = f + 360448;                       // 49152
  float* pA        = f + 360448 + 49152;               // 256 slots
  float* pB        = pA + 256;                         // 768
  float* rinv      = pB + 768;                         // 16
  float* sbL[4];                                       // per-layer BN scale/bias
  for (int i = 0; i < 4; ++i) sbL[i] = f + 412672 + i * 2048;
  __hip_bfloat16* bfb = (__hip_bfloat16*)(f + 524288);
  const size_t REGION = 16777216 + 2048;
  __hip_bfloat16* region0 = bfb;
  __hip_bfloat16* region1 = region0 + REGION;
  __hip_bfloat16* wf1 = region1 + REGION;
  __hip_bfloat16* wf2 = wf1 + 4096;
  __hip_bfloat16* wf3 = wf2 + 131072;
  __hip_bfloat16* wf4 = wf3 + 524288;
  __hip_bfloat16* wf5 = wf4 + 1048576;
  __hip_bfloat16* wf6 = wf5 + 2097152;
  float* skpart = (float*)(wf6 + 524288);              // 8388608 floats
  float* vpart  = skpart + 8388608;                    // 393216 floats

  __hip_bfloat16* a2col = region0;
  __hip_bfloat16* x1 = region1;
  __hip_bfloat16* x2 = region0;
  __hip_bfloat16* x3 = region1;
  __hip_bfloat16* x4 = region0;
  __hip_bfloat16* x5 = region1;

  zero_pads<<<8, 256, 0, stream>>>(region0, region1);

  SNArgs sa;
  const int outc[6] = {64, 128, 256, 256, 512, 64};
  const int ink[6]  = {48, 1024, 2048, 4096, 4096, 8192};
  for (int l = 0; l < 6; ++l) { sa.w[l] = W[l]; sa.u[l] = U[l]; sa.outc[l] = outc[l]; sa.ink[l] = ink[l]; }

  sn_v<<<dim3(32, 8, 6), 256, 0, stream>>>(sa, vpart);
  sn_v_red<<<dim3(32, 6), 256, 0, stream>>>(sa, vpart, vbuf, pA);
  sn_norm1<<<6, 64, 0, stream>>>(sa, pA, rinv);
  sn_t2<<<dim3(128, 6), 256, 0, stream>>>(sa, vbuf, rinv, pB);
  sn_norm2<<<6, 64, 0, stream>>>(pB, inv_sigma);

  PPArgs pa;
  __hip_bfloat16* wfp_[6] = {wf1, wf2, wf3, wf4, wf5, wf6};
  const int cinr_[6]  = {3, 64, 128, 256, 256, 512};
  const int kpad_[6]  = {64, 1024, 2048, 4096, 4096, 8192};
  const int kreal_[6] = {48, 1024, 2048, 4096, 4096, 8192};
  for (int l = 0; l < 6; ++l) {
    pa.w[l] = W[l]; pa.dst[l] = wfp_[l]; pa.cinr[l] = cinr_[l];
    pa.cout[l] = outc[l]; pa.kpad[l] = kpad_[l]; pa.kreal[l] = kreal_[l];
  }
  prepack_all<<<dim3(8192, 6), 256, 0, stream>>>(pa, inv_sigma);

  im2col_l1<<<8192, 256, 0, stream>>>(image, a2col);

  // L1: [262144 x 64] @ [64 x 64], fused lrelu
  conv_mfma<64, 64, 4, true><<<dim3(2048, 1), 256, 0, stream>>>(a2col, wf1, x1);

  // L2: raw input (lrelu applied by L1), direct bf16 out
  conv_mfma4<64, 128, 64, 32, 1, false, false><<<dim3(512, 1, 1), 256, 0, stream>>>(x1, wf2, nullptr, x2, nullptr);
  bn_stats_a<256><<<dim3(256, 2), 256, 0, stream>>>(x2, part, 65536, 128);
  bn_stats_b<256><<<2, 64, 0, stream>>>(part, G[0], Bb[0], sbL[0], 65536, 128);

  // L3: BN1+lrelu fused on input; split-K Z=2; fused reduce+stats
  conv_mfma4<128, 256, 32, 16, 2, true, true><<<dim3(128, 2, 2), 256, 0, stream>>>(x2, wf3, sbL[0], nullptr, skpart);
  sk_bn_fuse<2, 128><<<dim3(128, 4), 256, 0, stream>>>(skpart, x3, part, 16384, 256);
  bn_stats_b<128><<<4, 64, 0, stream>>>(part, G[1], Bb[1], sbL[1], 16384, 256);

  // L4: BN2+lrelu fused; split-K Z=8; fused reduce+stats
  conv_mfma4<256, 256, 16, 8, 8, true, true><<<dim3(32, 2, 8), 256, 0, stream>>>(x3, wf4, sbL[1], nullptr, skpart);
  sk_bn_fuse<8, 128><<<dim3(128, 4), 256, 0, stream>>>(skpart, x4, part, 4096, 256);
  bn_stats_b<128><<<4, 64, 0, stream>>>(part, G[2], Bb[2], sbL[2], 4096, 256);

  // L5: BN3+lrelu fused; split-K Z=16; fused reduce+stats
  conv_mfma4<256, 512, 8, 4, 16, true, true><<<dim3(8, 4, 16), 256, 0, stream>>>(x4, wf5, sbL[2], nullptr, skpart);
  sk_bn_fuse<16, 32><<<dim3(32, 8), 256, 0, stream>>>(skpart, x5, part, 1024, 512);
  bn_stats_b<32><<<8, 64, 0, stream>>>(part, G[3], Bb[3], sbL[3], 1024, 512);

  // BN4 apply on x5 (tiny: 1 MB), then plain L6
  bn_apply<<<256, 256, 0, stream>>>(x5, sbL[3], 512, 65536);
  conv_l6_mfma<<<8, 256, 0, stream>>>(x5, wf6, x6, out);

  ms_kernel<<<dim3(64, 4), 256, 0, stream>>>(x6, T, Ms);
  mbd_kernel<<<dim3(64, 4), 256, 0, stream>>>(Ms, out);
}

// Round 21
// 357.327 us; speedup vs baseline: 1.2298x; 1.0226x over previous
//
#include <hip/hip_runtime.h>
#include <hip/hip_bf16.h>
#include <math.h>

#define LRELU 0.2f
#define BN_EPS 1e-5f
#define SN_EPS 1e-12f

typedef __attribute__((ext_vector_type(4))) float f32x4;
typedef __attribute__((ext_vector_type(8))) short bf16x8;
typedef __attribute__((ext_vector_type(4))) short bf16x4;

__device__ inline float bf2f(short s) {
  union { unsigned u; float f; } c; c.u = ((unsigned)(unsigned short)s) << 16; return c.f;
}
__device__ inline short f2bf(float f) {
  __hip_bfloat16 h = __float2bfloat16(f); return *(short*)&h;
}

// XCD-aware bijective block swizzle (requires gridDim.x % 8 == 0)
__device__ inline int xcd_swz(int bx, int nwg) {
  int chunk = nwg >> 3;
  return (bx & 7) * chunk + (bx >> 3);
}

// ---------------------------------------------------------------- reductions
__device__ inline float blockReduceSum256(float v, volatile float* red) {
  #pragma unroll
  for (int o = 32; o > 0; o >>= 1) v += __shfl_down(v, o, 64);
  const int tid = threadIdx.x;
  __syncthreads();
  if ((tid & 63) == 0) red[tid >> 6] = v;
  __syncthreads();
  return red[0] + red[1] + red[2] + red[3];
}

// ---------------------------------------------------------------- spectral norm, parallel 5-stage chain
struct SNArgs {
  const float* w[6];
  const float* u[6];
  int outc[6];
  int ink[6];
};

__global__ __launch_bounds__(256) void sn_v(SNArgs args, float* __restrict__ vpart) {
  const int l = blockIdx.z;
  const int in_k = args.ink[l], out_c = args.outc[l];
  const int tid = threadIdx.x;
  const int j = blockIdx.x * 256 + tid;
  if (blockIdx.x * 256 >= in_k) return;
  const int rows = out_c >> 3;
  const int i0 = blockIdx.y * rows;
  __shared__ float uS[64];
  if (tid < rows) uS[tid] = args.u[l][i0 + tid];
  __syncthreads();
  if (j >= in_k) return;
  const float* __restrict__ w = args.w[l] + (size_t)i0 * in_k;
  float t = 0.f;
  for (int i = 0; i < rows; ++i) t = fmaf(w[(size_t)i * in_k + j], uS[i], t);
  vpart[((size_t)(l * 8 + blockIdx.y)) * 8192 + j] = t;
}

__global__ __launch_bounds__(256) void sn_v_red(SNArgs args, const float* __restrict__ vpart,
                                                float* __restrict__ vbuf, float* __restrict__ pA) {
  const int l = blockIdx.y;
  const int in_k = args.ink[l];
  const int tid = threadIdx.x;
  const int j = blockIdx.x * 256 + tid;
  __shared__ float red[4];
  float s = 0.f;
  if (j < in_k) {
    #pragma unroll
    for (int ch = 0; ch < 8; ++ch)
      s += vpart[((size_t)(l * 8 + ch)) * 8192 + j];
    vbuf[l * 8192 + j] = s;
  }
  const float bs = blockReduceSum256((j < in_k) ? s * s : 0.f, red);
  if (tid == 0) pA[l * 32 + blockIdx.x] = bs;
}

__global__ __launch_bounds__(64) void sn_norm1(SNArgs args, const float* __restrict__ pA,
                                               float* __restrict__ rinv) {
  const int l = blockIdx.x;
  if (threadIdx.x != 0) return;
  const int nb = (args.ink[l] + 255) >> 8;
  float s = 0.f;
  for (int b = 0; b < nb; ++b) s += pA[l * 32 + b];
  rinv[l] = 1.f / (sqrtf(s) + SN_EPS);
}

__global__ __launch_bounds__(256) void sn_t2(SNArgs args, const float* __restrict__ vbuf,
                                             const float* __restrict__ rinv,
                                             float* __restrict__ pB) {
  const int l = blockIdx.y;
  const int in_k = args.ink[l], out_c = args.outc[l];
  const int lane = threadIdx.x & 63, wv = threadIdx.x >> 6;
  const int row = blockIdx.x * 4 + wv;
  __shared__ float red[4];
  float sq = 0.f;
  if (row < out_c) {
    const float* __restrict__ wr = args.w[l] + (size_t)row * in_k;
    const float* __restrict__ v = vbuf + l * 8192;
    float a0 = 0.f, a1 = 0.f, a2 = 0.f, a3 = 0.f;
    for (int j = lane * 4; j < in_k; j += 256) {
      f32x4 w4 = *(const f32x4*)(wr + j);
      f32x4 v4 = *(const f32x4*)(v + j);
      a0 = fmaf(w4[0], v4[0], a0);
      a1 = fmaf(w4[1], v4[1], a1);
      a2 = fmaf(w4[2], v4[2], a2);
      a3 = fmaf(w4[3], v4[3], a3);
    }
    float t = (a0 + a1) + (a2 + a3);
    #pragma unroll
    for (int o = 32; o > 0; o >>= 1) t += __shfl_down(t, o, 64);
    if (lane == 0) { t *= rinv[l]; sq = t * t; }
  }
  __syncthreads();
  if (lane == 0) red[wv] = sq;
  __syncthreads();
  if (threadIdx.x == 0) pB[l * 128 + blockIdx.x] = red[0] + red[1] + red[2] + red[3];
}

__global__ __launch_bounds__(64) void sn_norm2(const float* __restrict__ pB,
                                               float* __restrict__ inv_sigma) {
  const int l = blockIdx.x;
  if (threadIdx.x != 0) return;
  float s = 0.f;
  for (int b = 0; b < 128; ++b) s += pB[l * 128 + b];
  const float n2 = sqrtf(s);
  const float sigma = s / (n2 + SN_EPS);
  inv_sigma[l] = 1.f / sigma;
}

// ---------------------------------------------------------------- zero the OOB pad regions
__global__ __launch_bounds__(256) void zero_pads(__hip_bfloat16* r0, __hip_bfloat16* r1) {
  int t = blockIdx.x * 256 + threadIdx.x;
  if (t < 2048) {
    r0[16777216 + t] = __float2bfloat16(0.f);
    r1[16777216 + t] = __float2bfloat16(0.f);
  }
}

// ---------------------------------------------------------------- batched weight prepack (all 6 layers, 1 dispatch)
struct PPArgs {
  const float* w[6];
  __hip_bfloat16* dst[6];
  int cinr[6];
  int cout[6];
  int kpad[6];
  int kreal[6];
};

__global__ __launch_bounds__(256) void prepack_all(PPArgs args, const float* __restrict__ invs) {
  const int l = blockIdx.y;
  int e = blockIdx.x * 256 + threadIdx.x;
  const int total = args.kpad[l] * args.cout[l];
  if (e >= total) return;
  const int CINR = args.cinr[l], COUT = args.cout[l], KREAL = args.kreal[l];
  int j = e & 7, lane = (e >> 3) & 63, frag = e >> 9;
  int nfrags = COUT >> 4;
  int ks = frag / nfrags, nf = frag - ks * nfrags;
  int k = ks * 32 + ((lane >> 4) << 3) + j;
  int co = (nf << 4) + (lane & 15);
  float val = 0.f;
  if (k < KREAL) {
    int khw = k / CINR, ci = k - khw * CINR;
    int kh = khw >> 2, kw = khw & 3;
    val = args.w[l][(((size_t)co * CINR + ci) * 4 + kh) * 4 + kw] * invs[l];
  }
  args.dst[l][e] = __float2bfloat16(val);
}

// ---------------------------------------------------------------- L1 im2col, coalesced 16B writes
__global__ __launch_bounds__(256) void im2col_l1(const float* __restrict__ img,
                                                 __hip_bfloat16* __restrict__ a2) {
  int t = blockIdx.x * 256 + threadIdx.x;      // 2097152
  int c = t & 7;
  int m = t >> 3;
  int n = m >> 12;
  int hw = m & 4095;
  int ho = hw >> 6, wo = hw & 63;
  int ihb = 2 * ho - 1, iwb = 2 * wo - 1;
  const float* __restrict__ ib = img + (size_t)n * 49152;
  short vals[8];
  #pragma unroll
  for (int j = 0; j < 8; ++j) {
    int k = c * 8 + j;
    float val = 0.f;
    if (k < 48) {
      int khw = k / 3;
      int ci = k - khw * 3;
      int kh = khw >> 2, kw = khw & 3;
      int ih = ihb + kh, iw = iwb + kw;
      if (((unsigned)ih < 128u) & ((unsigned)iw < 128u))
        val = ib[ci * 16384 + ih * 128 + iw];
    }
    vals[j] = f2bf(val);
  }
  *(bf16x8*)(a2 + (size_t)m * 64 + c * 8) = *(bf16x8*)vals;
}

// ---------------------------------------------------------------- L1 MFMA GEMM (1x1 over pre-im2col'd A), XCD-swizzled
template<int CIN, int COUT, int MF, bool FUSE>
__global__ __launch_bounds__(256) void conv_mfma(
    const __hip_bfloat16* __restrict__ x,
    const __hip_bfloat16* __restrict__ wf,
    __hip_bfloat16* __restrict__ out)
{
  constexpr int CB = CIN / 32;

  const int bx = xcd_swz(blockIdx.x, gridDim.x);
  const int lane = threadIdx.x & 63;
  const int wid  = threadIdx.x >> 6;
  const int wm = wid >> 1, wn = wid & 1;
  const int mbase = bx * (MF * 32) + wm * (MF * 16);
  const int cobase = blockIdx.y * 64 + wn * 32;

  int offm[MF];
  #pragma unroll
  for (int mf = 0; mf < MF; ++mf) {
    int m = mbase + mf * 16 + (lane & 15);
    offm[mf] = m * CIN;
  }
  const int koff = (lane >> 4) << 3;
  const __hip_bfloat16* wfp = wf + ((size_t)((blockIdx.y * 4 + wn * 2) * 64 + lane)) * 8;

  f32x4 acc[MF][2];
  #pragma unroll
  for (int mf = 0; mf < MF; ++mf) {
    acc[mf][0] = (f32x4){0.f, 0.f, 0.f, 0.f};
    acc[mf][1] = (f32x4){0.f, 0.f, 0.f, 0.f};
  }

  #pragma unroll
  for (int cb = 0; cb < CB; ++cb) {
    bf16x8 a[MF], b[2];
    #pragma unroll
    for (int mf = 0; mf < MF; ++mf) a[mf] = *(const bf16x8*)(x + offm[mf] + koff + cb * 32);
    #pragma unroll
    for (int nf = 0; nf < 2; ++nf)
      b[nf] = *(const bf16x8*)(wfp + (size_t)cb * (COUT * 32) + nf * 512);
    #pragma unroll
    for (int mf = 0; mf < MF; ++mf)
      #pragma unroll
      for (int nf = 0; nf < 2; ++nf)
        acc[mf][nf] = __builtin_amdgcn_mfma_f32_16x16x32_bf16(a[mf], b[nf], acc[mf][nf], 0, 0, 0);
  }

  const int r0 = (lane >> 4) * 4;
  const int cw = cobase + (lane & 15);
  #pragma unroll
  for (int mf = 0; mf < MF; ++mf)
    #pragma unroll
    for (int nf = 0; nf < 2; ++nf)
      #pragma unroll
      for (int r = 0; r < 4; ++r) {
        float v = acc[mf][nf][r];
        if (FUSE) v = (v >= 0.f) ? v : LRELU * v;
        int m = mbase + mf * 16 + r0 + r;
        out[(size_t)m * COUT + (cw + nf * 16)] = __float2bfloat16(v);
      }
}

// ---------------------------------------------------------------- 4x4-fragment implicit-GEMM conv, k4 s2 p1
// XCD-swizzled. BNIN: consumer-side BN+lrelu on A fragments.
// BF16P: split-K partials stored as bf16 (halves partial traffic).
template<int CIN, int COUT, int HIN, int HOUT, int Z, bool SPLITK, bool BNIN, bool BF16P>
__global__ __launch_bounds__(256) void conv_mfma4(
    const __hip_bfloat16* __restrict__ x,
    const __hip_bfloat16* __restrict__ wf,
    const float* __restrict__ sbp,
    __hip_bfloat16* __restrict__ outb, float* __restrict__ outp)
{
  constexpr int WIN = HIN, WO = HOUT;
  constexpr int CB = CIN / 32;
  constexpr int KHW_PER = 16 / Z;
  constexpr int PADOFF = 16777216;
  constexpr int M = 64 * HOUT * WO;

  const int bx = xcd_swz(blockIdx.x, gridDim.x);
  const int lane = threadIdx.x & 63;
  const int wid  = threadIdx.x >> 6;
  const int wm = wid >> 1, wn = wid & 1;
  const int mbase = bx * 128 + wm * 64;
  const int nbase = blockIdx.y * 128 + wn * 64;
  const int khw0 = blockIdx.z * KHW_PER;

  int offm[4], ihb[4], iwb[4];
  #pragma unroll
  for (int mf = 0; mf < 4; ++mf) {
    int m = mbase + mf * 16 + (lane & 15);
    int n = m / (HOUT * WO);
    int hw = m - n * (HOUT * WO);
    int ho = hw / WO, wo = hw - ho * WO;
    ihb[mf] = 2 * ho - 1;
    iwb[mf] = 2 * wo - 1;
    offm[mf] = ((n * HIN + ihb[mf]) * WIN + iwb[mf]) * CIN;
  }
  const int koff = (lane >> 4) << 3;
  const __hip_bfloat16* wfp = wf + ((size_t)((nbase >> 4) * 64 + lane)) * 8;

  f32x4 acc[4][4];
  #pragma unroll
  for (int mf = 0; mf < 4; ++mf)
    #pragma unroll
    for (int nf = 0; nf < 4; ++nf) acc[mf][nf] = (f32x4){0.f, 0.f, 0.f, 0.f};

  #pragma unroll
  for (int cb = 0; cb < CB; ++cb) {
    f32x4 s0, s1, o0, o1;
    if (BNIN) {
      const int cbase = cb * 32 + koff;
      s0 = *(const f32x4*)(sbp + cbase);
      s1 = *(const f32x4*)(sbp + cbase + 4);
      o0 = *(const f32x4*)(sbp + CIN + cbase);
      o1 = *(const f32x4*)(sbp + CIN + cbase + 4);
    }
    #pragma unroll
    for (int ki = 0; ki < KHW_PER; ++ki) {
      const int khw = khw0 + ki;
      const int kh = khw >> 2, kw = khw & 3;
      bf16x8 a[4], b[4];
      bool vm[4];
      #pragma unroll
      for (int mf = 0; mf < 4; ++mf) {
        int ih = ihb[mf] + kh, iw = iwb[mf] + kw;
        vm[mf] = ((unsigned)ih < (unsigned)HIN) & ((unsigned)iw < (unsigned)WIN);
        int off = vm[mf] ? (offm[mf] + (kh * WIN + kw) * CIN + koff + cb * 32)
                         : (PADOFF + koff + cb * 32);
        a[mf] = *(const bf16x8*)(x + off);
      }
      const size_t ks = (size_t)khw * CB + cb;
      #pragma unroll
      for (int nf = 0; nf < 4; ++nf)
        b[nf] = *(const bf16x8*)(wfp + ks * (COUT * 32) + nf * 512);
      if (BNIN) {
        #pragma unroll
        for (int mf = 0; mf < 4; ++mf) {
          bf16x8 t = a[mf];
          #pragma unroll
          for (int j = 0; j < 8; ++j) {
            float fv = bf2f(t[j]);
            float sc = (j < 4) ? s0[j] : s1[j - 4];
            float of = (j < 4) ? o0[j] : o1[j - 4];
            fv = fmaf(fv, sc, of);
            fv = fmaxf(fv, LRELU * fv);
            t[j] = vm[mf] ? f2bf(fv) : (short)0;
          }
          a[mf] = t;
        }
      }
      #pragma unroll
      for (int mf = 0; mf < 4; ++mf)
        #pragma unroll
        for (int nf = 0; nf < 4; ++nf)
          acc[mf][nf] = __builtin_amdgcn_mfma_f32_16x16x32_bf16(a[mf], b[nf], acc[mf][nf], 0, 0, 0);
    }
  }

  const int r0 = (lane >> 4) * 4;
  const int cw = nbase + (lane & 15);
  #pragma unroll
  for (int mf = 0; mf < 4; ++mf)
    #pragma unroll
    for (int nf = 0; nf < 4; ++nf)
      #pragma unroll
      for (int r = 0; r < 4; ++r) {
        const int m = mbase + mf * 16 + r0 + r;
        const int co = cw + nf * 16;
        if (SPLITK) {
          if (BF16P)
            outb[(size_t)blockIdx.z * M * COUT + (size_t)m * COUT + co] = __float2bfloat16(acc[mf][nf][r]);
          else
            outp[(size_t)blockIdx.z * M * COUT + (size_t)m * COUT + co] = acc[mf][nf][r];
        } else {
          outb[(size_t)m * COUT + co] = __float2bfloat16(acc[mf][nf][r]);
        }
      }
}

// ---------------------------------------------------------------- fused: split-K reduce + bf16 write + BN partial stats
template<int Z, int MCHUNKS, bool BF16P>
__global__ __launch_bounds__(256) void sk_bn_fuse(const float* __restrict__ partf,
                                                  const __hip_bfloat16* __restrict__ partb,
                                                  __hip_bfloat16* __restrict__ xo,
                                                  float* __restrict__ statp, int M, int C) {
  const int chunk = blockIdx.x;
  const int c0 = blockIdx.y * 64 + (threadIdx.x & 7) * 8;
  const int mrow = threadIdx.x >> 3;
  const int rows = M / MCHUNKS;
  const size_t MC = (size_t)M * C;
  float s[8], s2[8];
  #pragma unroll
  for (int j = 0; j < 8; ++j) { s[j] = 0.f; s2[j] = 0.f; }
  for (int mi = mrow; mi < rows; mi += 32) {
    const int m = chunk * rows + mi;
    const size_t base = (size_t)m * C + c0;
    float av[8];
    if (BF16P) {
      bf16x8 v0 = *(const bf16x8*)(partb + base);
      #pragma unroll
      for (int j = 0; j < 8; ++j) av[j] = bf2f(v0[j]);
      #pragma unroll
      for (int z = 1; z < Z; ++z) {
        bf16x8 vz = *(const bf16x8*)(partb + (size_t)z * MC + base);
        #pragma unroll
        for (int j = 0; j < 8; ++j) av[j] += bf2f(vz[j]);
      }
    } else {
      f32x4 a = *(const f32x4*)(partf + base);
      f32x4 b = *(const f32x4*)(partf + base + 4);
      #pragma unroll
      for (int z = 1; z < Z; ++z) {
        a += *(const f32x4*)(partf + (size_t)z * MC + base);
        b += *(const f32x4*)(partf + (size_t)z * MC + base + 4);
      }
      #pragma unroll
      for (int j = 0; j < 4; ++j) { av[j] = a[j]; av[4 + j] = b[j]; }
    }
    bf16x8 o;
    #pragma unroll
    for (int j = 0; j < 8; ++j) {
      o[j] = f2bf(av[j]);
      s[j] += av[j];
      s2[j] = fmaf(av[j], av[j], s2[j]);
    }
    *(bf16x8*)(xo + base) = o;
  }
  __shared__ float ls[8][256], ls2[8][256];
  const int t = threadIdx.x;
  #pragma unroll
  for (int j = 0; j < 8; ++j) { ls[j][t] = s[j]; ls2[j][t] = s2[j]; }
  __syncthreads();
  #pragma unroll
  for (int off = 16; off >= 1; off >>= 1) {
    if (mrow < off) {
      #pragma unroll
      for (int j = 0; j < 8; ++j) {
        ls[j][t]  += ls[j][t + off * 8];
        ls2[j][t] += ls2[j][t + off * 8];
      }
    }
    __syncthreads();
  }
  if (t < 8) {
    #pragma unroll
    for (int j = 0; j < 8; ++j) {
      statp[(size_t)chunk * C + c0 + j] = ls[j][t];
      statp[(size_t)(MCHUNKS + chunk) * C + c0 + j] = ls2[j][t];
    }
  }
}

// ---------------------------------------------------------------- L6 MFMA conv (plain); writes flat part of out
__global__ __launch_bounds__(256) void conv_l6_mfma(
    const __hip_bfloat16* __restrict__ x,
    const __hip_bfloat16* __restrict__ wf,
    float* __restrict__ x6, float* __restrict__ out)
{
  constexpr int CIN = 512, COUT = 64, HIN = 4;
  constexpr int CB = CIN / 32;
  constexpr int PADOFF = 16777216;

  const int lane = threadIdx.x & 63;
  const int wid  = threadIdx.x >> 6;
  const int wm = wid >> 1, wn = wid & 1;
  const int mbase = blockIdx.x * 32 + wm * 16;

  int m0 = mbase + (lane & 15);
  int n = m0 >> 2;
  int hw = m0 & 3;
  int ho = hw >> 1, wo = hw & 1;
  int ihb = 2 * ho - 1;
  int iwb = 2 * wo - 1;
  int offm = ((n * HIN + ihb) * HIN + iwb) * CIN;

  const int koff = (lane >> 4) << 3;
  const __hip_bfloat16* wfp = wf + ((size_t)((wn * 2) * 64 + lane)) * 8;

  f32x4 acc[2];
  acc[0] = (f32x4){0.f, 0.f, 0.f, 0.f};
  acc[1] = (f32x4){0.f, 0.f, 0.f, 0.f};

  #pragma unroll
  for (int khw = 0; khw < 16; ++khw) {
    const int kh = khw >> 2, kw = khw & 3;
    const int ih = ihb + kh, iw = iwb + kw;
    const bool v = ((unsigned)ih < (unsigned)HIN) & ((unsigned)iw < (unsigned)HIN);
    const int off = v ? (offm + (kh * HIN + kw) * CIN + koff) : (PADOFF + koff);
    const __hip_bfloat16* ap = x + off;
    #pragma unroll
    for (int cb = 0; cb < CB; ++cb) {
      const int ks = khw * CB + cb;
      bf16x8 a = *(const bf16x8*)(ap + cb * 32);
      bf16x8 b0 = *(const bf16x8*)(wfp + (size_t)ks * (COUT * 32));
      bf16x8 b1 = *(const bf16x8*)(wfp + (size_t)ks * (COUT * 32) + 512);
      acc[0] = __builtin_amdgcn_mfma_f32_16x16x32_bf16(a, b0, acc[0], 0, 0, 0);
      acc[1] = __builtin_amdgcn_mfma_f32_16x16x32_bf16(a, b1, acc[1], 0, 0, 0);
    }
  }

  const int r0 = (lane >> 4) * 4;
  const int cw = wn * 32 + (lane & 15);
  #pragma unroll
  for (int nf = 0; nf < 2; ++nf)
    #pragma unroll
    for (int r = 0; r < 4; ++r) {
      int m = mbase + r0 + r;
      int nn = m >> 2, p = m & 3;
      float v = acc[nf][r];
      x6[(size_t)nn * 256 + (cw + nf * 16) * 4 + p] = v;
      out[(size_t)nn * 320 + (cw + nf * 16) * 4 + p] = v;
    }
}

// ---------------------------------------------------------------- BN stats (direct-output layers), vectorized
template<int MCHUNKS>
__global__ __launch_bounds__(256) void bn_stats_a(const __hip_bfloat16* __restrict__ x,
                                                  float* __restrict__ part, int M, int C) {
  const int chunk = blockIdx.x;
  const int c0 = blockIdx.y * 64 + (threadIdx.x & 7) * 8;
  const int mrow = threadIdx.x >> 3;
  const int rows = M / MCHUNKS;
  float s[8], s2[8];
  #pragma unroll
  for (int j = 0; j < 8; ++j) { s[j] = 0.f; s2[j] = 0.f; }
  for (int mi = mrow; mi < rows; mi += 32) {
    const int m = chunk * rows + mi;
    bf16x8 v = *(const bf16x8*)(x + (size_t)m * C + c0);
    #pragma unroll
    for (int j = 0; j < 8; ++j) {
      float f = bf2f(v[j]);
      s[j] += f;
      s2[j] = fmaf(f, f, s2[j]);
    }
  }
  __shared__ float ls[8][256], ls2[8][256];
  const int t = threadIdx.x;
  #pragma unroll
  for (int j = 0; j < 8; ++j) { ls[j][t] = s[j]; ls2[j][t] = s2[j]; }
  __syncthreads();
  #pragma unroll
  for (int off = 16; off >= 1; off >>= 1) {
    if (mrow < off) {
      #pragma unroll
      for (int j = 0; j < 8; ++j) {
        ls[j][t]  += ls[j][t + off * 8];
        ls2[j][t] += ls2[j][t + off * 8];
      }
    }
    __syncthreads();
  }
  if (t < 8) {
    #pragma unroll
    for (int j = 0; j < 8; ++j) {
      part[(size_t)chunk * C + c0 + j] = ls[j][t];
      part[(size_t)(MCHUNKS + chunk) * C + c0 + j] = ls2[j][t];
    }
  }
}

template<int MCHUNKS>
__global__ __launch_bounds__(64) void bn_stats_b(const float* __restrict__ part,
                                                 const float* __restrict__ g,
                                                 const float* __restrict__ b,
                                                 float* __restrict__ sb, int M, int C) {
  int c = blockIdx.x * 64 + threadIdx.x;
  float s = 0.f, s2 = 0.f;
  for (int ch = 0; ch < MCHUNKS; ++ch) {
    s  += part[(size_t)ch * C + c];
    s2 += part[(size_t)(MCHUNKS + ch) * C + c];
  }
  float invM = 1.f / (float)M;
  float mean = s * invM;
  float var = s2 * invM - mean * mean;
  float scale = g[c] * rsqrtf(var + BN_EPS);
  sb[c] = scale;
  sb[C + c] = b[c] - mean * scale;
}

// ---------------------------------------------------------------- BN apply (only x5 before L6)
__global__ __launch_bounds__(256) void bn_apply(__hip_bfloat16* __restrict__ x,
                                                const float* __restrict__ sb,
                                                int C, int nvec) {
  int idx = blockIdx.x * 256 + threadIdx.x;
  if (idx >= nvec) return;
  size_t e = (size_t)idx * 8;
  int c0 = (int)(e % (size_t)C);
  bf16x8 v = *(bf16x8*)(x + e);
  bf16x8 o;
  #pragma unroll
  for (int j = 0; j < 8; ++j) {
    int c = c0 + j;
    float f = bf2f(v[j]);
    f = fmaf(f, sb[c], sb[C + c]);
    f = (f >= 0.f) ? f : LRELU * f;
    o[j] = f2bf(f);
  }
  *(bf16x8*)(x + e) = o;
}

// ---------------------------------------------------------------- tail: Ms = flat @ T (256 blocks)
__global__ __launch_bounds__(256) void ms_kernel(const float* __restrict__ x6,
                                                 const float* __restrict__ T,
                                                 float* __restrict__ Ms) {
  const int cb = blockIdx.x;
  const int nb = blockIdx.y;
  const int c  = threadIdx.x & 63;
  const int ns = threadIdx.x >> 6;
  __shared__ float fsh[16][256];
  for (int t = threadIdx.x; t < 4096; t += 256) {
    int n = t >> 8, a = t & 255;
    fsh[n][a] = x6[(size_t)(nb * 16 + n) * 256 + a];
  }
  __syncthreads();
  const int col = cb * 64 + c;
  float acc0 = 0.f, acc1 = 0.f, acc2 = 0.f, acc3 = 0.f;
  #pragma unroll 8
  for (int a = 0; a < 256; ++a) {
    float tv = T[(size_t)a * 4096 + col];
    acc0 = fmaf(fsh[ns * 4 + 0][a], tv, acc0);
    acc1 = fmaf(fsh[ns * 4 + 1][a], tv, acc1);
    acc2 = fmaf(fsh[ns * 4 + 2][a], tv, acc2);
    acc3 = fmaf(fsh[ns * 4 + 3][a], tv, acc3);
  }
  const int nbase = nb * 16 + ns * 4;
  Ms[(size_t)(nbase + 0) * 4096 + col] = acc0;
  Ms[(size_t)(nbase + 1) * 4096 + col] = acc1;
  Ms[(size_t)(nbase + 2) * 4096 + col] = acc2;
  Ms[(size_t)(nbase + 3) * 4096 + col] = acc3;
}

// ---------------------------------------------------------------- minibatch discrimination (256 blocks)
__global__ __launch_bounds__(256) void mbd_kernel(const float* __restrict__ Ms,
                                                  float* __restrict__ out) {
  const int b  = blockIdx.x;
  const int ib = blockIdx.y;
  const int tid = threadIdx.x;
  __shared__ float Mb[64][65];
  for (int idx = tid; idx < 4096; idx += 256) {
    const int i = idx >> 6, cc = idx & 63;
    Mb[i][cc] = Ms[(size_t)i * 4096 + b * 64 + cc];
  }
  __syncthreads();
  const int i  = ib * 16 + (tid >> 4);
  const int jg = tid & 15;
  float ssum = 0.f;
  for (int j = jg; j < 64; j += 16) {
    float d = 0.f;
    #pragma unroll
    for (int cc = 0; cc < 64; ++cc) d += fabsf(Mb[i][cc] - Mb[j][cc]);
    ssum += expf(-d);
  }
  ssum += __shfl_xor(ssum, 1, 64);
  ssum += __shfl_xor(ssum, 2, 64);
  ssum += __shfl_xor(ssum, 4, 64);
  ssum += __shfl_xor(ssum, 8, 64);
  if (jg == 0) out[(size_t)i * 320 + 256 + b] = ssum;
}

// ---------------------------------------------------------------- launch
extern "C" void kernel_launch(void* const* d_in, const int* in_sizes, int n_in,
                              void* d_out, int out_size, void* d_ws, size_t ws_size,
                              hipStream_t stream) {
  const float* image = (const float*)d_in[0];
  const float* W[6] = {(const float*)d_in[1], (const float*)d_in[3], (const float*)d_in[5],
                       (const float*)d_in[7], (const float*)d_in[9], (const float*)d_in[11]};
  const float* U[6] = {(const float*)d_in[2], (const float*)d_in[4], (const float*)d_in[6],
                       (const float*)d_in[8], (const float*)d_in[10], (const float*)d_in[12]};
  const float* G[4] = {(const float*)d_in[13], (const float*)d_in[15],
                       (const float*)d_in[17], (const float*)d_in[19]};
  const float* Bb[4] = {(const float*)d_in[14], (const float*)d_in[16],
                        (const float*)d_in[18], (const float*)d_in[20]};
  const float* T = (const float*)d_in[21];
  float* out = (float*)d_out;

  // ---- workspace layout (floats)
  float* f = (float*)d_ws;
  float* inv_sigma = f;                                // 16
  float* part      = f + 1024;                         // 65536
  float* x6        = f + 1024 + 65536 + 1024;          // 16384
  float* Ms        = f + 1024 + 65536 + 1024 + 16384;  // 262144
  float* vbuf      = f + 360448;                       // 49152
  float* pA        = f + 360448 + 49152;               // 256 slots
  float* pB        = pA + 256;                         // 768
  float* rinv      = pB + 768;                         // 16
  float* sbL[4];                                       // per-layer BN scale/bias
  for (int i = 0; i < 4; ++i) sbL[i] = f + 412672 + i * 2048;
  __hip_bfloat16* bfb = (__hip_bfloat16*)(f + 524288);
  const size_t REGION = 16777216 + 2048;
  __hip_bfloat16* region0 = bfb;
  __hip_bfloat16* region1 = region0 + REGION;
  __hip_bfloat16* wf1 = region1 + REGION;
  __hip_bfloat16* wf2 = wf1 + 4096;
  __hip_bfloat16* wf3 = wf2 + 131072;
  __hip_bfloat16* wf4 = wf3 + 524288;
  __hip_bfloat16* wf5 = wf4 + 1048576;
  __hip_bfloat16* wf6 = wf5 + 2097152;
  float* skpart = (float*)(wf6 + 524288);              // 8388608 floats (also used as bf16)
  __hip_bfloat16* skpartb = (__hip_bfloat16*)skpart;
  float* vpart  = skpart + 8388608;                    // 393216 floats

  __hip_bfloat16* a2col = region0;
  __hip_bfloat16* x1 = region1;
  __hip_bfloat16* x2 = region0;
  __hip_bfloat16* x3 = region1;
  __hip_bfloat16* x4 = region0;
  __hip_bfloat16* x5 = region1;

  zero_pads<<<8, 256, 0, stream>>>(region0, region1);

  SNArgs sa;
  const int outc[6] = {64, 128, 256, 256, 512, 64};
  const int ink[6]  = {48, 1024, 2048, 4096, 4096, 8192};
  for (int l = 0; l < 6; ++l) { sa.w[l] = W[l]; sa.u[l] = U[l]; sa.outc[l] = outc[l]; sa.ink[l] = ink[l]; }

  sn_v<<<dim3(32, 8, 6), 256, 0, stream>>>(sa, vpart);
  sn_v_red<<<dim3(32, 6), 256, 0, stream>>>(sa, vpart, vbuf, pA);
  sn_norm1<<<6, 64, 0, stream>>>(sa, pA, rinv);
  sn_t2<<<dim3(128, 6), 256, 0, stream>>>(sa, vbuf, rinv, pB);
  sn_norm2<<<6, 64, 0, stream>>>(pB, inv_sigma);

  PPArgs pa;
  __hip_bfloat16* wfp_[6] = {wf1, wf2, wf3, wf4, wf5, wf6};
  const int cinr_[6]  = {3, 64, 128, 256, 256, 512};
  const int kpad_[6]  = {64, 1024, 2048, 4096, 4096, 8192};
  const int kreal_[6] = {48, 1024, 2048, 4096, 4096, 8192};
  for (int l = 0; l < 6; ++l) {
    pa.w[l] = W[l]; pa.dst[l] = wfp_[l]; pa.cinr[l] = cinr_[l];
    pa.cout[l] = outc[l]; pa.kpad[l] = kpad_[l]; pa.kreal[l] = kreal_[l];
  }
  prepack_all<<<dim3(8192, 6), 256, 0, stream>>>(pa, inv_sigma);

  im2col_l1<<<8192, 256, 0, stream>>>(image, a2col);

  // L1: [262144 x 64] @ [64 x 64], fused lrelu
  conv_mfma<64, 64, 4, true><<<dim3(2048, 1), 256, 0, stream>>>(a2col, wf1, x1);

  // L2: raw input (lrelu applied by L1), direct bf16 out
  conv_mfma4<64, 128, 64, 32, 1, false, false, false><<<dim3(512, 1, 1), 256, 0, stream>>>(x1, wf2, nullptr, x2, nullptr);
  bn_stats_a<256><<<dim3(256, 2), 256, 0, stream>>>(x2, part, 65536, 128);
  bn_stats_b<256><<<2, 64, 0, stream>>>(part, G[0], Bb[0], sbL[0], 65536, 128);

  // L3: BN1+lrelu fused; split-K Z=2 with bf16 partials; fused reduce+stats
  conv_mfma4<128, 256, 32, 16, 2, true, true, true><<<dim3(128, 2, 2), 256, 0, stream>>>(x2, wf3, sbL[0], skpartb, nullptr);
  sk_bn_fuse<2, 128, true><<<dim3(128, 4), 256, 0, stream>>>(nullptr, skpartb, x3, part, 16384, 256);
  bn_stats_b<128><<<4, 64, 0, stream>>>(part, G[1], Bb[1], sbL[1], 16384, 256);

  // L4: BN2+lrelu fused; split-K Z=8 with bf16 partials; fused reduce+stats
  conv_mfma4<256, 256, 16, 8, 8, true, true, true><<<dim3(32, 2, 8), 256, 0, stream>>>(x3, wf4, sbL[1], skpartb, nullptr);
  sk_bn_fuse<8, 128, true><<<dim3(128, 4), 256, 0, stream>>>(nullptr, skpartb, x4, part, 4096, 256);
  bn_stats_b<128><<<4, 64, 0, stream>>>(part, G[2], Bb[2], sbL[2], 4096, 256);

  // L5: BN3+lrelu fused; split-K Z=16 with bf16 partials; fused reduce+stats
  conv_mfma4<256, 512, 8, 4, 16, true, true, true><<<dim3(8, 4, 16), 256, 0, stream>>>(x4, wf5, sbL[2], skpartb, nullptr);
  sk_bn_fuse<16, 32, true><<<dim3(32, 8), 256, 0, stream>>>(nullptr, skpartb, x5, part, 1024, 512);
  bn_stats_b<32><<<8, 64, 0, stream>>>(part, G[3], Bb[3], sbL[3], 1024, 512);

  // BN4 apply on x5 (tiny: 1 MB), then plain L6
  bn_apply<<<256, 256, 0, stream>>>(x5, sbL[3], 512, 65536);
  conv_l6_mfma<<<8, 256, 0, stream>>>(x5, wf6, x6, out);

  ms_kernel<<<dim3(64, 4), 256, 0, stream>>>(x6, T, Ms);
  mbd_kernel<<<dim3(64, 4), 256, 0, stream>>>(Ms, out);
}

// Round 22
// 344.318 us; speedup vs baseline: 1.2762x; 1.0378x over previous
//
#include <hip/hip_runtime.h>
#include <hip/hip_bf16.h>
#include <math.h>

#define LRELU 0.2f
#define BN_EPS 1e-5f
#define SN_EPS 1e-12f

typedef __attribute__((ext_vector_type(4))) float f32x4;
typedef __attribute__((ext_vector_type(8))) short bf16x8;
typedef __attribute__((ext_vector_type(4))) short bf16x4;

__device__ inline float bf2f(short s) {
  union { unsigned u; float f; } c; c.u = ((unsigned)(unsigned short)s) << 16; return c.f;
}
__device__ inline short f2bf(float f) {
  __hip_bfloat16 h = __float2bfloat16(f); return *(short*)&h;
}

// XCD-aware bijective block swizzle (requires gridDim.x % 8 == 0)
__device__ inline int xcd_swz(int bx, int nwg) {
  int chunk = nwg >> 3;
  return (bx & 7) * chunk + (bx >> 3);
}

// ---------------------------------------------------------------- reductions
__device__ inline float blockReduceSum256(float v, volatile float* red) {
  #pragma unroll
  for (int o = 32; o > 0; o >>= 1) v += __shfl_down(v, o, 64);
  const int tid = threadIdx.x;
  __syncthreads();
  if ((tid & 63) == 0) red[tid >> 6] = v;
  __syncthreads();
  return red[0] + red[1] + red[2] + red[3];
}

// ---------------------------------------------------------------- spectral norm, parallel 5-stage chain
struct SNArgs {
  const float* w[6];
  const float* u[6];
  int outc[6];
  int ink[6];
};

__global__ __launch_bounds__(256) void sn_v(SNArgs args, float* __restrict__ vpart) {
  const int l = blockIdx.z;
  const int in_k = args.ink[l], out_c = args.outc[l];
  const int tid = threadIdx.x;
  const int j = blockIdx.x * 256 + tid;
  if (blockIdx.x * 256 >= in_k) return;
  const int rows = out_c >> 3;
  const int i0 = blockIdx.y * rows;
  __shared__ float uS[64];
  if (tid < rows) uS[tid] = args.u[l][i0 + tid];
  __syncthreads();
  if (j >= in_k) return;
  const float* __restrict__ w = args.w[l] + (size_t)i0 * in_k;
  float t = 0.f;
  for (int i = 0; i < rows; ++i) t = fmaf(w[(size_t)i * in_k + j], uS[i], t);
  vpart[((size_t)(l * 8 + blockIdx.y)) * 8192 + j] = t;
}

__global__ __launch_bounds__(256) void sn_v_red(SNArgs args, const float* __restrict__ vpart,
                                                float* __restrict__ vbuf, float* __restrict__ pA) {
  const int l = blockIdx.y;
  const int in_k = args.ink[l];
  const int tid = threadIdx.x;
  const int j = blockIdx.x * 256 + tid;
  __shared__ float red[4];
  float s = 0.f;
  if (j < in_k) {
    #pragma unroll
    for (int ch = 0; ch < 8; ++ch)
      s += vpart[((size_t)(l * 8 + ch)) * 8192 + j];
    vbuf[l * 8192 + j] = s;
  }
  const float bs = blockReduceSum256((j < in_k) ? s * s : 0.f, red);
  if (tid == 0) pA[l * 32 + blockIdx.x] = bs;
}

__global__ __launch_bounds__(64) void sn_norm1(SNArgs args, const float* __restrict__ pA,
                                               float* __restrict__ rinv) {
  const int l = blockIdx.x;
  if (threadIdx.x != 0) return;
  const int nb = (args.ink[l] + 255) >> 8;
  float s = 0.f;
  for (int b = 0; b < nb; ++b) s += pA[l * 32 + b];
  rinv[l] = 1.f / (sqrtf(s) + SN_EPS);
}

__global__ __launch_bounds__(256) void sn_t2(SNArgs args, const float* __restrict__ vbuf,
                                             const float* __restrict__ rinv,
                                             float* __restrict__ pB) {
  const int l = blockIdx.y;
  const int in_k = args.ink[l], out_c = args.outc[l];
  const int lane = threadIdx.x & 63, wv = threadIdx.x >> 6;
  const int row = blockIdx.x * 4 + wv;
  __shared__ float red[4];
  float sq = 0.f;
  if (row < out_c) {
    const float* __restrict__ wr = args.w[l] + (size_t)row * in_k;
    const float* __restrict__ v = vbuf + l * 8192;
    float a0 = 0.f, a1 = 0.f, a2 = 0.f, a3 = 0.f;
    for (int j = lane * 4; j < in_k; j += 256) {
      f32x4 w4 = *(const f32x4*)(wr + j);
      f32x4 v4 = *(const f32x4*)(v + j);
      a0 = fmaf(w4[0], v4[0], a0);
      a1 = fmaf(w4[1], v4[1], a1);
      a2 = fmaf(w4[2], v4[2], a2);
      a3 = fmaf(w4[3], v4[3], a3);
    }
    float t = (a0 + a1) + (a2 + a3);
    #pragma unroll
    for (int o = 32; o > 0; o >>= 1) t += __shfl_down(t, o, 64);
    if (lane == 0) { t *= rinv[l]; sq = t * t; }
  }
  __syncthreads();
  if (lane == 0) red[wv] = sq;
  __syncthreads();
  if (threadIdx.x == 0) pB[l * 128 + blockIdx.x] = red[0] + red[1] + red[2] + red[3];
}

__global__ __launch_bounds__(64) void sn_norm2(const float* __restrict__ pB,
                                               float* __restrict__ inv_sigma) {
  const int l = blockIdx.x;
  if (threadIdx.x != 0) return;
  float s = 0.f;
  for (int b = 0; b < 128; ++b) s += pB[l * 128 + b];
  const float n2 = sqrtf(s);
  const float sigma = s / (n2 + SN_EPS);
  inv_sigma[l] = 1.f / sigma;
}

// ---------------------------------------------------------------- zero the OOB pad regions
__global__ __launch_bounds__(256) void zero_pads(__hip_bfloat16* r0, __hip_bfloat16* r1) {
  int t = blockIdx.x * 256 + threadIdx.x;
  if (t < 2048) {
    r0[16777216 + t] = __float2bfloat16(0.f);
    r1[16777216 + t] = __float2bfloat16(0.f);
  }
}

// ---------------------------------------------------------------- batched weight prepack (all 6 layers, 1 dispatch)
struct PPArgs {
  const float* w[6];
  __hip_bfloat16* dst[6];
  int cinr[6];
  int cout[6];
  int kpad[6];
  int kreal[6];
};

__global__ __launch_bounds__(256) void prepack_all(PPArgs args, const float* __restrict__ invs) {
  const int l = blockIdx.y;
  int e = blockIdx.x * 256 + threadIdx.x;
  const int total = args.kpad[l] * args.cout[l];
  if (e >= total) return;
  const int CINR = args.cinr[l], COUT = args.cout[l], KREAL = args.kreal[l];
  int j = e & 7, lane = (e >> 3) & 63, frag = e >> 9;
  int nfrags = COUT >> 4;
  int ks = frag / nfrags, nf = frag - ks * nfrags;
  int k = ks * 32 + ((lane >> 4) << 3) + j;
  int co = (nf << 4) + (lane & 15);
  float val = 0.f;
  if (k < KREAL) {
    int khw = k / CINR, ci = k - khw * CINR;
    int kh = khw >> 2, kw = khw & 3;
    val = args.w[l][(((size_t)co * CINR + ci) * 4 + kh) * 4 + kw] * invs[l];
  }
  args.dst[l][e] = __float2bfloat16(val);
}

// ---------------------------------------------------------------- L1 im2col, coalesced 16B writes
__global__ __launch_bounds__(256) void im2col_l1(const float* __restrict__ img,
                                                 __hip_bfloat16* __restrict__ a2) {
  int t = blockIdx.x * 256 + threadIdx.x;      // 2097152
  int c = t & 7;
  int m = t >> 3;
  int n = m >> 12;
  int hw = m & 4095;
  int ho = hw >> 6, wo = hw & 63;
  int ihb = 2 * ho - 1, iwb = 2 * wo - 1;
  const float* __restrict__ ib = img + (size_t)n * 49152;
  short vals[8];
  #pragma unroll
  for (int j = 0; j < 8; ++j) {
    int k = c * 8 + j;
    float val = 0.f;
    if (k < 48) {
      int khw = k / 3;
      int ci = k - khw * 3;
      int kh = khw >> 2, kw = khw & 3;
      int ih = ihb + kh, iw = iwb + kw;
      if (((unsigned)ih < 128u) & ((unsigned)iw < 128u))
        val = ib[ci * 16384 + ih * 128 + iw];
    }
    vals[j] = f2bf(val);
  }
  *(bf16x8*)(a2 + (size_t)m * 64 + c * 8) = *(bf16x8*)vals;
}

// ---------------------------------------------------------------- L1 MFMA GEMM (1x1 over pre-im2col'd A), XCD-swizzled
template<int CIN, int COUT, int MF, bool FUSE>
__global__ __launch_bounds__(256) void conv_mfma(
    const __hip_bfloat16* __restrict__ x,
    const __hip_bfloat16* __restrict__ wf,
    __hip_bfloat16* __restrict__ out)
{
  constexpr int CB = CIN / 32;

  const int bx = xcd_swz(blockIdx.x, gridDim.x);
  const int lane = threadIdx.x & 63;
  const int wid  = threadIdx.x >> 6;
  const int wm = wid >> 1, wn = wid & 1;
  const int mbase = bx * (MF * 32) + wm * (MF * 16);
  const int cobase = blockIdx.y * 64 + wn * 32;

  int offm[MF];
  #pragma unroll
  for (int mf = 0; mf < MF; ++mf) {
    int m = mbase + mf * 16 + (lane & 15);
    offm[mf] = m * CIN;
  }
  const int koff = (lane >> 4) << 3;
  const __hip_bfloat16* wfp = wf + ((size_t)((blockIdx.y * 4 + wn * 2) * 64 + lane)) * 8;

  f32x4 acc[MF][2];
  #pragma unroll
  for (int mf = 0; mf < MF; ++mf) {
    acc[mf][0] = (f32x4){0.f, 0.f, 0.f, 0.f};
    acc[mf][1] = (f32x4){0.f, 0.f, 0.f, 0.f};
  }

  #pragma unroll
  for (int cb = 0; cb < CB; ++cb) {
    bf16x8 a[MF], b[2];
    #pragma unroll
    for (int mf = 0; mf < MF; ++mf) a[mf] = *(const bf16x8*)(x + offm[mf] + koff + cb * 32);
    #pragma unroll
    for (int nf = 0; nf < 2; ++nf)
      b[nf] = *(const bf16x8*)(wfp + (size_t)cb * (COUT * 32) + nf * 512);
    #pragma unroll
    for (int mf = 0; mf < MF; ++mf)
      #pragma unroll
      for (int nf = 0; nf < 2; ++nf)
        acc[mf][nf] = __builtin_amdgcn_mfma_f32_16x16x32_bf16(a[mf], b[nf], acc[mf][nf], 0, 0, 0);
  }

  const int r0 = (lane >> 4) * 4;
  const int cw = cobase + (lane & 15);
  #pragma unroll
  for (int mf = 0; mf < MF; ++mf)
    #pragma unroll
    for (int nf = 0; nf < 2; ++nf)
      #pragma unroll
      for (int r = 0; r < 4; ++r) {
        float v = acc[mf][nf][r];
        if (FUSE) v = (v >= 0.f) ? v : LRELU * v;
        int m = mbase + mf * 16 + r0 + r;
        out[(size_t)m * COUT + (cw + nf * 16)] = __float2bfloat16(v);
      }
}

// ---------------------------------------------------------------- LDS-staged 128x128 conv, k4 s2 p1 (reg-staged, 2 barriers/step)
// A and B staged once per block into LDS; fragments via ds_read_b128.
// Next-step global loads issued between barrier-2 and MFMA (latency hidden).
template<int CIN, int COUT, int HIN, int HOUT>
__global__ __launch_bounds__(256) void conv_lds(
    const __hip_bfloat16* __restrict__ x,
    const __hip_bfloat16* __restrict__ wf,
    __hip_bfloat16* __restrict__ outb)
{
  constexpr int WIN = HIN, WO = HOUT;
  constexpr int CB = CIN / 32;
  constexpr int NSTEP = 16 * CB;         // BK=32 steps
  constexpr int PADOFF = 16777216;

  __shared__ __hip_bfloat16 As[128 * 32];   // [row 0..127][32 k], 64B rows
  __shared__ __hip_bfloat16 Bs[4096];       // [8 nfrag][64 lane][8]

  const int bx = xcd_swz(blockIdx.x, gridDim.x);
  const int t = threadIdx.x;
  const int lane = t & 63;
  const int wid = t >> 6;
  const int wm = wid >> 1, wn = wid & 1;
  const int mbase = bx * 128;
  const int nbase = blockIdx.y * 128;

  // staging geometry: thread t owns A rows t/4 and 64+t/4, k-slot t&3
  const int sr0 = t >> 2;
  const int sl  = t & 3;
  int rowbase[2], ihbs[2], iwbs[2];
  #pragma unroll
  for (int i = 0; i < 2; ++i) {
    int m = mbase + sr0 + i * 64;
    int n = m / (HOUT * WO);
    int hw = m - n * (HOUT * WO);
    int ho = hw / WO, wo = hw - ho * WO;
    ihbs[i] = 2 * ho - 1;
    iwbs[i] = 2 * wo - 1;
    rowbase[i] = ((n * HIN + ihbs[i]) * WIN + iwbs[i]) * CIN;
  }
  const size_t bslab0 = (size_t)(nbase >> 4) * 512 + (size_t)t * 8;

  f32x4 acc[4][4];
  #pragma unroll
  for (int mf = 0; mf < 4; ++mf)
    #pragma unroll
    for (int nf = 0; nf < 4; ++nf) acc[mf][nf] = (f32x4){0.f, 0.f, 0.f, 0.f};

  bf16x8 ra0, ra1, rb0, rb1;
  auto load_step = [&](int ks) {
    const int khw = ks / CB, cb = ks - khw * CB;
    const int kh = khw >> 2, kw = khw & 3;
    const int kbyteoff = cb * 32 + sl * 8;
    {
      int ih = ihbs[0] + kh, iw = iwbs[0] + kw;
      bool v = ((unsigned)ih < (unsigned)HIN) & ((unsigned)iw < (unsigned)WIN);
      int off = v ? (rowbase[0] + (kh * WIN + kw) * CIN + kbyteoff) : PADOFF;
      ra0 = *(const bf16x8*)(x + off);
    }
    {
      int ih = ihbs[1] + kh, iw = iwbs[1] + kw;
      bool v = ((unsigned)ih < (unsigned)HIN) & ((unsigned)iw < (unsigned)WIN);
      int off = v ? (rowbase[1] + (kh * WIN + kw) * CIN + kbyteoff) : PADOFF;
      ra1 = *(const bf16x8*)(x + off);
    }
    const size_t bo = (size_t)ks * (COUT * 32) + bslab0;
    rb0 = *(const bf16x8*)(wf + bo);
    rb1 = *(const bf16x8*)(wf + bo + 2048);
  };

  load_step(0);
  for (int ks = 0; ks < NSTEP; ++ks) {
    __syncthreads();                         // prior step's ds_reads complete
    *(bf16x8*)(&As[sr0 * 32 + sl * 8]) = ra0;
    *(bf16x8*)(&As[(sr0 + 64) * 32 + sl * 8]) = ra1;
    *(bf16x8*)(&Bs[t * 8]) = rb0;
    *(bf16x8*)(&Bs[2048 + t * 8]) = rb1;
    __syncthreads();                         // tile visible
    if (ks + 1 < NSTEP) load_step(ks + 1);   // overlap next loads with MFMA
    bf16x8 af[4], bfr[4];
    #pragma unroll
    for (int mf = 0; mf < 4; ++mf) {
      const int ra = wm * 64 + mf * 16 + (lane & 15);
      af[mf] = *(const bf16x8*)(&As[ra * 32 + (lane >> 4) * 8]);
    }
    #pragma unroll
    for (int nf = 0; nf < 4; ++nf)
      bfr[nf] = *(const bf16x8*)(&Bs[(wn * 4 + nf) * 512 + lane * 8]);
    #pragma unroll
    for (int mf = 0; mf < 4; ++mf)
      #pragma unroll
      for (int nf = 0; nf < 4; ++nf)
        acc[mf][nf] = __builtin_amdgcn_mfma_f32_16x16x32_bf16(af[mf], bfr[nf], acc[mf][nf], 0, 0, 0);
  }

  const int r0w = (lane >> 4) * 4;
  const int cw = nbase + wn * 64 + (lane & 15);
  #pragma unroll
  for (int mf = 0; mf < 4; ++mf)
    #pragma unroll
    for (int nf = 0; nf < 4; ++nf)
      #pragma unroll
      for (int r = 0; r < 4; ++r) {
        const int m = mbase + wm * 64 + mf * 16 + r0w + r;
        outb[(size_t)m * COUT + (cw + nf * 16)] = __float2bfloat16(acc[mf][nf][r]);
      }
}

// ---------------------------------------------------------------- 4x4-fragment implicit-GEMM conv, k4 s2 p1 (fragment-direct)
template<int CIN, int COUT, int HIN, int HOUT, int Z, bool SPLITK, bool BNIN, bool BF16P>
__global__ __launch_bounds__(256) void conv_mfma4(
    const __hip_bfloat16* __restrict__ x,
    const __hip_bfloat16* __restrict__ wf,
    const float* __restrict__ sbp,
    __hip_bfloat16* __restrict__ outb, float* __restrict__ outp)
{
  constexpr int WIN = HIN, WO = HOUT;
  constexpr int CB = CIN / 32;
  constexpr int KHW_PER = 16 / Z;
  constexpr int PADOFF = 16777216;
  constexpr int M = 64 * HOUT * WO;

  const int bx = xcd_swz(blockIdx.x, gridDim.x);
  const int lane = threadIdx.x & 63;
  const int wid  = threadIdx.x >> 6;
  const int wm = wid >> 1, wn = wid & 1;
  const int mbase = bx * 128 + wm * 64;
  const int nbase = blockIdx.y * 128 + wn * 64;
  const int khw0 = blockIdx.z * KHW_PER;

  int offm[4], ihb[4], iwb[4];
  #pragma unroll
  for (int mf = 0; mf < 4; ++mf) {
    int m = mbase + mf * 16 + (lane & 15);
    int n = m / (HOUT * WO);
    int hw = m - n * (HOUT * WO);
    int ho = hw / WO, wo = hw - ho * WO;
    ihb[mf] = 2 * ho - 1;
    iwb[mf] = 2 * wo - 1;
    offm[mf] = ((n * HIN + ihb[mf]) * WIN + iwb[mf]) * CIN;
  }
  const int koff = (lane >> 4) << 3;
  const __hip_bfloat16* wfp = wf + ((size_t)((nbase >> 4) * 64 + lane)) * 8;

  f32x4 acc[4][4];
  #pragma unroll
  for (int mf = 0; mf < 4; ++mf)
    #pragma unroll
    for (int nf = 0; nf < 4; ++nf) acc[mf][nf] = (f32x4){0.f, 0.f, 0.f, 0.f};

  #pragma unroll
  for (int cb = 0; cb < CB; ++cb) {
    f32x4 s0, s1, o0, o1;
    if (BNIN) {
      const int cbase = cb * 32 + koff;
      s0 = *(const f32x4*)(sbp + cbase);
      s1 = *(const f32x4*)(sbp + cbase + 4);
      o0 = *(const f32x4*)(sbp + CIN + cbase);
      o1 = *(const f32x4*)(sbp + CIN + cbase + 4);
    }
    #pragma unroll
    for (int ki = 0; ki < KHW_PER; ++ki) {
      const int khw = khw0 + ki;
      const int kh = khw >> 2, kw = khw & 3;
      bf16x8 a[4], b[4];
      bool vm[4];
      #pragma unroll
      for (int mf = 0; mf < 4; ++mf) {
        int ih = ihb[mf] + kh, iw = iwb[mf] + kw;
        vm[mf] = ((unsigned)ih < (unsigned)HIN) & ((unsigned)iw < (unsigned)WIN);
        int off = vm[mf] ? (offm[mf] + (kh * WIN + kw) * CIN + koff + cb * 32)
                         : (PADOFF + koff + cb * 32);
        a[mf] = *(const bf16x8*)(x + off);
      }
      const size_t ks = (size_t)khw * CB + cb;
      #pragma unroll
      for (int nf = 0; nf < 4; ++nf)
        b[nf] = *(const bf16x8*)(wfp + ks * (COUT * 32) + nf * 512);
      if (BNIN) {
        #pragma unroll
        for (int mf = 0; mf < 4; ++mf) {
          bf16x8 tt = a[mf];
          #pragma unroll
          for (int j = 0; j < 8; ++j) {
            float fv = bf2f(tt[j]);
            float sc = (j < 4) ? s0[j] : s1[j - 4];
            float of = (j < 4) ? o0[j] : o1[j - 4];
            fv = fmaf(fv, sc, of);
            fv = fmaxf(fv, LRELU * fv);
            tt[j] = vm[mf] ? f2bf(fv) : (short)0;
          }
          a[mf] = tt;
        }
      }
      #pragma unroll
      for (int mf = 0; mf < 4; ++mf)
        #pragma unroll
        for (int nf = 0; nf < 4; ++nf)
          acc[mf][nf] = __builtin_amdgcn_mfma_f32_16x16x32_bf16(a[mf], b[nf], acc[mf][nf], 0, 0, 0);
    }
  }

  const int r0 = (lane >> 4) * 4;
  const int cw = nbase + (lane & 15);
  #pragma unroll
  for (int mf = 0; mf < 4; ++mf)
    #pragma unroll
    for (int nf = 0; nf < 4; ++nf)
      #pragma unroll
      for (int r = 0; r < 4; ++r) {
        const int m = mbase + mf * 16 + r0 + r;
        const int co = cw + nf * 16;
        if (SPLITK) {
          if (BF16P)
            outb[(size_t)blockIdx.z * M * COUT + (size_t)m * COUT + co] = __float2bfloat16(acc[mf][nf][r]);
          else
            outp[(size_t)blockIdx.z * M * COUT + (size_t)m * COUT + co] = acc[mf][nf][r];
        } else {
          outb[(size_t)m * COUT + co] = __float2bfloat16(acc[mf][nf][r]);
        }
      }
}

// ---------------------------------------------------------------- fused: split-K reduce + bf16 write + BN partial stats
template<int Z, int MCHUNKS, bool BF16P>
__global__ __launch_bounds__(256) void sk_bn_fuse(const float* __restrict__ partf,
                                                  const __hip_bfloat16* __restrict__ partb,
                                                  __hip_bfloat16* __restrict__ xo,
                                                  float* __restrict__ statp, int M, int C) {
  const int chunk = blockIdx.x;
  const int c0 = blockIdx.y * 64 + (threadIdx.x & 7) * 8;
  const int mrow = threadIdx.x >> 3;
  const int rows = M / MCHUNKS;
  const size_t MC = (size_t)M * C;
  float s[8], s2[8];
  #pragma unroll
  for (int j = 0; j < 8; ++j) { s[j] = 0.f; s2[j] = 0.f; }
  for (int mi = mrow; mi < rows; mi += 32) {
    const int m = chunk * rows + mi;
    const size_t base = (size_t)m * C + c0;
    float av[8];
    if (BF16P) {
      bf16x8 v0 = *(const bf16x8*)(partb + base);
      #pragma unroll
      for (int j = 0; j < 8; ++j) av[j] = bf2f(v0[j]);
      #pragma unroll
      for (int z = 1; z < Z; ++z) {
        bf16x8 vz = *(const bf16x8*)(partb + (size_t)z * MC + base);
        #pragma unroll
        for (int j = 0; j < 8; ++j) av[j] += bf2f(vz[j]);
      }
    } else {
      f32x4 a = *(const f32x4*)(partf + base);
      f32x4 b = *(const f32x4*)(partf + base + 4);
      #pragma unroll
      for (int z = 1; z < Z; ++z) {
        a += *(const f32x4*)(partf + (size_t)z * MC + base);
        b += *(const f32x4*)(partf + (size_t)z * MC + base + 4);
      }
      #pragma unroll
      for (int j = 0; j < 4; ++j) { av[j] = a[j]; av[4 + j] = b[j]; }
    }
    bf16x8 o;
    #pragma unroll
    for (int j = 0; j < 8; ++j) {
      o[j] = f2bf(av[j]);
      s[j] += av[j];
      s2[j] = fmaf(av[j], av[j], s2[j]);
    }
    *(bf16x8*)(xo + base) = o;
  }
  __shared__ float ls[8][256], ls2[8][256];
  const int t = threadIdx.x;
  #pragma unroll
  for (int j = 0; j < 8; ++j) { ls[j][t] = s[j]; ls2[j][t] = s2[j]; }
  __syncthreads();
  #pragma unroll
  for (int off = 16; off >= 1; off >>= 1) {
    if (mrow < off) {
      #pragma unroll
      for (int j = 0; j < 8; ++j) {
        ls[j][t]  += ls[j][t + off * 8];
        ls2[j][t] += ls2[j][t + off * 8];
      }
    }
    __syncthreads();
  }
  if (t < 8) {
    #pragma unroll
    for (int j = 0; j < 8; ++j) {
      statp[(size_t)chunk * C + c0 + j] = ls[j][t];
      statp[(size_t)(MCHUNKS + chunk) * C + c0 + j] = ls2[j][t];
    }
  }
}

// ---------------------------------------------------------------- L6 MFMA conv (plain); writes flat part of out
__global__ __launch_bounds__(256) void conv_l6_mfma(
    const __hip_bfloat16* __restrict__ x,
    const __hip_bfloat16* __restrict__ wf,
    float* __restrict__ x6, float* __restrict__ out)
{
  constexpr int CIN = 512, COUT = 64, HIN = 4;
  constexpr int CB = CIN / 32;
  constexpr int PADOFF = 16777216;

  const int lane = threadIdx.x & 63;
  const int wid  = threadIdx.x >> 6;
  const int wm = wid >> 1, wn = wid & 1;
  const int mbase = blockIdx.x * 32 + wm * 16;

  int m0 = mbase + (lane & 15);
  int n = m0 >> 2;
  int hw = m0 & 3;
  int ho = hw >> 1, wo = hw & 1;
  int ihb = 2 * ho - 1;
  int iwb = 2 * wo - 1;
  int offm = ((n * HIN + ihb) * HIN + iwb) * CIN;

  const int koff = (lane >> 4) << 3;
  const __hip_bfloat16* wfp = wf + ((size_t)((wn * 2) * 64 + lane)) * 8;

  f32x4 acc[2];
  acc[0] = (f32x4){0.f, 0.f, 0.f, 0.f};
  acc[1] = (f32x4){0.f, 0.f, 0.f, 0.f};

  #pragma unroll
  for (int khw = 0; khw < 16; ++khw) {
    const int kh = khw >> 2, kw = khw & 3;
    const int ih = ihb + kh, iw = iwb + kw;
    const bool v = ((unsigned)ih < (unsigned)HIN) & ((unsigned)iw < (unsigned)HIN);
    const int off = v ? (offm + (kh * HIN + kw) * CIN + koff) : (PADOFF + koff);
    const __hip_bfloat16* ap = x + off;
    #pragma unroll
    for (int cb = 0; cb < CB; ++cb) {
      const int ks = khw * CB + cb;
      bf16x8 a = *(const bf16x8*)(ap + cb * 32);
      bf16x8 b0 = *(const bf16x8*)(wfp + (size_t)ks * (COUT * 32));
      bf16x8 b1 = *(const bf16x8*)(wfp + (size_t)ks * (COUT * 32) + 512);
      acc[0] = __builtin_amdgcn_mfma_f32_16x16x32_bf16(a, b0, acc[0], 0, 0, 0);
      acc[1] = __builtin_amdgcn_mfma_f32_16x16x32_bf16(a, b1, acc[1], 0, 0, 0);
    }
  }

  const int r0 = (lane >> 4) * 4;
  const int cw = wn * 32 + (lane & 15);
  #pragma unroll
  for (int nf = 0; nf < 2; ++nf)
    #pragma unroll
    for (int r = 0; r < 4; ++r) {
      int m = mbase + r0 + r;
      int nn = m >> 2, p = m & 3;
      float v = acc[nf][r];
      x6[(size_t)nn * 256 + (cw + nf * 16) * 4 + p] = v;
      out[(size_t)nn * 320 + (cw + nf * 16) * 4 + p] = v;
    }
}

// ---------------------------------------------------------------- BN stats (direct-output layers), vectorized
template<int MCHUNKS>
__global__ __launch_bounds__(256) void bn_stats_a(const __hip_bfloat16* __restrict__ x,
                                                  float* __restrict__ part, int M, int C) {
  const int chunk = blockIdx.x;
  const int c0 = blockIdx.y * 64 + (threadIdx.x & 7) * 8;
  const int mrow = threadIdx.x >> 3;
  const int rows = M / MCHUNKS;
  float s[8], s2[8];
  #pragma unroll
  for (int j = 0; j < 8; ++j) { s[j] = 0.f; s2[j] = 0.f; }
  for (int mi = mrow; mi < rows; mi += 32) {
    const int m = chunk * rows + mi;
    bf16x8 v = *(const bf16x8*)(x + (size_t)m * C + c0);
    #pragma unroll
    for (int j = 0; j < 8; ++j) {
      float f = bf2f(v[j]);
      s[j] += f;
      s2[j] = fmaf(f, f, s2[j]);
    }
  }
  __shared__ float ls[8][256], ls2[8][256];
  const int t = threadIdx.x;
  #pragma unroll
  for (int j = 0; j < 8; ++j) { ls[j][t] = s[j]; ls2[j][t] = s2[j]; }
  __syncthreads();
  #pragma unroll
  for (int off = 16; off >= 1; off >>= 1) {
    if (mrow < off) {
      #pragma unroll
      for (int j = 0; j < 8; ++j) {
        ls[j][t]  += ls[j][t + off * 8];
        ls2[j][t] += ls2[j][t + off * 8];
      }
    }
    __syncthreads();
  }
  if (t < 8) {
    #pragma unroll
    for (int j = 0; j < 8; ++j) {
      part[(size_t)chunk * C + c0 + j] = ls[j][t];
      part[(size_t)(MCHUNKS + chunk) * C + c0 + j] = ls2[j][t];
    }
  }
}

template<int MCHUNKS>
__global__ __launch_bounds__(64) void bn_stats_b(const float* __restrict__ part,
                                                 const float* __restrict__ g,
                                                 const float* __restrict__ b,
                                                 float* __restrict__ sb, int M, int C) {
  int c = blockIdx.x * 64 + threadIdx.x;
  float s = 0.f, s2 = 0.f;
  for (int ch = 0; ch < MCHUNKS; ++ch) {
    s  += part[(size_t)ch * C + c];
    s2 += part[(size_t)(MCHUNKS + ch) * C + c];
  }
  float invM = 1.f / (float)M;
  float mean = s * invM;
  float var = s2 * invM - mean * mean;
  float scale = g[c] * rsqrtf(var + BN_EPS);
  sb[c] = scale;
  sb[C + c] = b[c] - mean * scale;
}

// ---------------------------------------------------------------- BN apply (only x5 before L6)
__global__ __launch_bounds__(256) void bn_apply(__hip_bfloat16* __restrict__ x,
                                                const float* __restrict__ sb,
                                                int C, int nvec) {
  int idx = blockIdx.x * 256 + threadIdx.x;
  if (idx >= nvec) return;
  size_t e = (size_t)idx * 8;
  int c0 = (int)(e % (size_t)C);
  bf16x8 v = *(bf16x8*)(x + e);
  bf16x8 o;
  #pragma unroll
  for (int j = 0; j < 8; ++j) {
    int c = c0 + j;
    float f = bf2f(v[j]);
    f = fmaf(f, sb[c], sb[C + c]);
    f = (f >= 0.f) ? f : LRELU * f;
    o[j] = f2bf(f);
  }
  *(bf16x8*)(x + e) = o;
}

// ---------------------------------------------------------------- tail: Ms = flat @ T (256 blocks)
__global__ __launch_bounds__(256) void ms_kernel(const float* __restrict__ x6,
                                                 const float* __restrict__ T,
                                                 float* __restrict__ Ms) {
  const int cb = blockIdx.x;
  const int nb = blockIdx.y;
  const int c  = threadIdx.x & 63;
  const int ns = threadIdx.x >> 6;
  __shared__ float fsh[16][256];
  for (int t = threadIdx.x; t < 4096; t += 256) {
    int n = t >> 8, a = t & 255;
    fsh[n][a] = x6[(size_t)(nb * 16 + n) * 256 + a];
  }
  __syncthreads();
  const int col = cb * 64 + c;
  float acc0 = 0.f, acc1 = 0.f, acc2 = 0.f, acc3 = 0.f;
  #pragma unroll 8
  for (int a = 0; a < 256; ++a) {
    float tv = T[(size_t)a * 4096 + col];
    acc0 = fmaf(fsh[ns * 4 + 0][a], tv, acc0);
    acc1 = fmaf(fsh[ns * 4 + 1][a], tv, acc1);
    acc2 = fmaf(fsh[ns * 4 + 2][a], tv, acc2);
    acc3 = fmaf(fsh[ns * 4 + 3][a], tv, acc3);
  }
  const int nbase = nb * 16 + ns * 4;
  Ms[(size_t)(nbase + 0) * 4096 + col] = acc0;
  Ms[(size_t)(nbase + 1) * 4096 + col] = acc1;
  Ms[(size_t)(nbase + 2) * 4096 + col] = acc2;
  Ms[(size_t)(nbase + 3) * 4096 + col] = acc3;
}

// ---------------------------------------------------------------- minibatch discrimination (256 blocks)
__global__ __launch_bounds__(256) void mbd_kernel(const float* __restrict__ Ms,
                                                  float* __restrict__ out) {
  const int b  = blockIdx.x;
  const int ib = blockIdx.y;
  const int tid = threadIdx.x;
  __shared__ float Mb[64][65];
  for (int idx = tid; idx < 4096; idx += 256) {
    const int i = idx >> 6, cc = idx & 63;
    Mb[i][cc] = Ms[(size_t)i * 4096 + b * 64 + cc];
  }
  __syncthreads();
  const int i  = ib * 16 + (tid >> 4);
  const int jg = tid & 15;
  float ssum = 0.f;
  for (int j = jg; j < 64; j += 16) {
    float d = 0.f;
    #pragma unroll
    for (int cc = 0; cc < 64; ++cc) d += fabsf(Mb[i][cc] - Mb[j][cc]);
    ssum += expf(-d);
  }
  ssum += __shfl_xor(ssum, 1, 64);
  ssum += __shfl_xor(ssum, 2, 64);
  ssum += __shfl_xor(ssum, 4, 64);
  ssum += __shfl_xor(ssum, 8, 64);
  if (jg == 0) out[(size_t)i * 320 + 256 + b] = ssum;
}

// ---------------------------------------------------------------- launch
extern "C" void kernel_launch(void* const* d_in, const int* in_sizes, int n_in,
                              void* d_out, int out_size, void* d_ws, size_t ws_size,
                              hipStream_t stream) {
  const float* image = (const float*)d_in[0];
  const float* W[6] = {(const float*)d_in[1], (const float*)d_in[3], (const float*)d_in[5],
                       (const float*)d_in[7], (const float*)d_in[9], (const float*)d_in[11]};
  const float* U[6] = {(const float*)d_in[2], (const float*)d_in[4], (const float*)d_in[6],
                       (const float*)d_in[8], (const float*)d_in[10], (const float*)d_in[12]};
  const float* G[4] = {(const float*)d_in[13], (const float*)d_in[15],
                       (const float*)d_in[17], (const float*)d_in[19]};
  const float* Bb[4] = {(const float*)d_in[14], (const float*)d_in[16],
                        (const float*)d_in[18], (const float*)d_in[20]};
  const float* T = (const float*)d_in[21];
  float* out = (float*)d_out;

  // ---- workspace layout (floats)
  float* f = (float*)d_ws;
  float* inv_sigma = f;                                // 16
  float* part      = f + 1024;                         // 65536
  float* x6        = f + 1024 + 65536 + 1024;          // 16384
  float* Ms        = f + 1024 + 65536 + 1024 + 16384;  // 262144
  float* vbuf      = f + 360448;                       // 49152
  float* pA        = f + 360448 + 49152;               // 256 slots
  float* pB        = pA + 256;                         // 768
  float* rinv      = pB + 768;                         // 16
  float* sbL[4];                                       // per-layer BN scale/bias
  for (int i = 0; i < 4; ++i) sbL[i] = f + 412672 + i * 2048;
  __hip_bfloat16* bfb = (__hip_bfloat16*)(f + 524288);
  const size_t REGION = 16777216 + 2048;
  __hip_bfloat16* region0 = bfb;
  __hip_bfloat16* region1 = region0 + REGION;
  __hip_bfloat16* wf1 = region1 + REGION;
  __hip_bfloat16* wf2 = wf1 + 4096;
  __hip_bfloat16* wf3 = wf2 + 131072;
  __hip_bfloat16* wf4 = wf3 + 524288;
  __hip_bfloat16* wf5 = wf4 + 1048576;
  __hip_bfloat16* wf6 = wf5 + 2097152;
  float* skpart = (float*)(wf6 + 524288);              // 8388608 floats (also used as bf16)
  __hip_bfloat16* skpartb = (__hip_bfloat16*)skpart;
  float* vpart  = skpart + 8388608;                    // 393216 floats

  __hip_bfloat16* a2col = region0;
  __hip_bfloat16* x1 = region1;
  __hip_bfloat16* x2 = region0;
  __hip_bfloat16* x3 = region1;
  __hip_bfloat16* x4 = region0;
  __hip_bfloat16* x5 = region1;

  zero_pads<<<8, 256, 0, stream>>>(region0, region1);

  SNArgs sa;
  const int outc[6] = {64, 128, 256, 256, 512, 64};
  const int ink[6]  = {48, 1024, 2048, 4096, 4096, 8192};
  for (int l = 0; l < 6; ++l) { sa.w[l] = W[l]; sa.u[l] = U[l]; sa.outc[l] = outc[l]; sa.ink[l] = ink[l]; }

  sn_v<<<dim3(32, 8, 6), 256, 0, stream>>>(sa, vpart);
  sn_v_red<<<dim3(32, 6), 256, 0, stream>>>(sa, vpart, vbuf, pA);
  sn_norm1<<<6, 64, 0, stream>>>(sa, pA, rinv);
  sn_t2<<<dim3(128, 6), 256, 0, stream>>>(sa, vbuf, rinv, pB);
  sn_norm2<<<6, 64, 0, stream>>>(pB, inv_sigma);

  PPArgs pa;
  __hip_bfloat16* wfp_[6] = {wf1, wf2, wf3, wf4, wf5, wf6};
  const int cinr_[6]  = {3, 64, 128, 256, 256, 512};
  const int kpad_[6]  = {64, 1024, 2048, 4096, 4096, 8192};
  const int kreal_[6] = {48, 1024, 2048, 4096, 4096, 8192};
  for (int l = 0; l < 6; ++l) {
    pa.w[l] = W[l]; pa.dst[l] = wfp_[l]; pa.cinr[l] = cinr_[l];
    pa.cout[l] = outc[l]; pa.kpad[l] = kpad_[l]; pa.kreal[l] = kreal_[l];
  }
  prepack_all<<<dim3(8192, 6), 256, 0, stream>>>(pa, inv_sigma);

  im2col_l1<<<8192, 256, 0, stream>>>(image, a2col);

  // L1: [262144 x 64] @ [64 x 64], fused lrelu
  conv_mfma<64, 64, 4, true><<<dim3(2048, 1), 256, 0, stream>>>(a2col, wf1, x1);

  // L2: LDS-staged 128x128 tile (NEW), raw input, direct bf16 out
  conv_lds<64, 128, 64, 32><<<dim3(512, 1, 1), 256, 0, stream>>>(x1, wf2, x2);
  bn_stats_a<256><<<dim3(256, 2), 256, 0, stream>>>(x2, part, 65536, 128);
  bn_stats_b<256><<<2, 64, 0, stream>>>(part, G[0], Bb[0], sbL[0], 65536, 128);

  // L3: BN1+lrelu fused; split-K Z=2 with bf16 partials; fused reduce+stats
  conv_mfma4<128, 256, 32, 16, 2, true, true, true><<<dim3(128, 2, 2), 256, 0, stream>>>(x2, wf3, sbL[0], skpartb, nullptr);
  sk_bn_fuse<2, 128, true><<<dim3(128, 4), 256, 0, stream>>>(nullptr, skpartb, x3, part, 16384, 256);
  bn_stats_b<128><<<4, 64, 0, stream>>>(part, G[1], Bb[1], sbL[1], 16384, 256);

  // L4: BN2+lrelu fused; split-K Z=8 with bf16 partials; fused reduce+stats
  conv_mfma4<256, 256, 16, 8, 8, true, true, true><<<dim3(32, 2, 8), 256, 0, stream>>>(x3, wf4, sbL[1], skpartb, nullptr);
  sk_bn_fuse<8, 128, true><<<dim3(128, 4), 256, 0, stream>>>(nullptr, skpartb, x4, part, 4096, 256);
  bn_stats_b<128><<<4, 64, 0, stream>>>(part, G[2], Bb[2], sbL[2], 4096, 256);

  // L5: BN3+lrelu fused; split-K Z=16 with bf16 partials; fused reduce+stats
  conv_mfma4<256, 512, 8, 4, 16, true, true, true><<<dim3(8, 4, 16), 256, 0, stream>>>(x4, wf5, sbL[2], skpartb, nullptr);
  sk_bn_fuse<16, 32, true><<<dim3(32, 8), 256, 0, stream>>>(nullptr, skpartb, x5, part, 1024, 512);
  bn_stats_b<32><<<8, 64, 0, stream>>>(part, G[3], Bb[3], sbL[3], 1024, 512);

  // BN4 apply on x5 (tiny: 1 MB), then plain L6
  bn_apply<<<256, 256, 0, stream>>>(x5, sbL[3], 512, 65536);
  conv_l6_mfma<<<8, 256, 0, stream>>>(x5, wf6, x6, out);

  ms_kernel<<<dim3(64, 4), 256, 0, stream>>>(x6, T, Ms);
  mbd_kernel<<<dim3(64, 4), 256, 0, stream>>>(Ms, out);
}

// Round 23
// 335.507 us; speedup vs baseline: 1.3097x; 1.0263x over previous
//
#include <hip/hip_runtime.h>
#include <hip/hip_bf16.h>
#include <math.h>

#define LRELU 0.2f
#define BN_EPS 1e-5f
#define SN_EPS 1e-12f

typedef __attribute__((ext_vector_type(4))) float f32x4;
typedef __attribute__((ext_vector_type(8))) short bf16x8;
typedef __attribute__((ext_vector_type(4))) short bf16x4;

__device__ inline float bf2f(short s) {
  union { unsigned u; float f; } c; c.u = ((unsigned)(unsigned short)s) << 16; return c.f;
}
__device__ inline short f2bf(float f) {
  __hip_bfloat16 h = __float2bfloat16(f); return *(short*)&h;
}

// XCD-aware bijective block swizzle (requires gridDim.x % 8 == 0)
__device__ inline int xcd_swz(int bx, int nwg) {
  int chunk = nwg >> 3;
  return (bx & 7) * chunk + (bx >> 3);
}

// ---------------------------------------------------------------- reductions
__device__ inline float blockReduceSum256(float v, volatile float* red) {
  #pragma unroll
  for (int o = 32; o > 0; o >>= 1) v += __shfl_down(v, o, 64);
  const int tid = threadIdx.x;
  __syncthreads();
  if ((tid & 63) == 0) red[tid >> 6] = v;
  __syncthreads();
  return red[0] + red[1] + red[2] + red[3];
}

// ---------------------------------------------------------------- spectral norm, parallel 5-stage chain
struct SNArgs {
  const float* w[6];
  const float* u[6];
  int outc[6];
  int ink[6];
};

__global__ __launch_bounds__(256) void sn_v(SNArgs args, float* __restrict__ vpart) {
  const int l = blockIdx.z;
  const int in_k = args.ink[l], out_c = args.outc[l];
  const int tid = threadIdx.x;
  const int j = blockIdx.x * 256 + tid;
  if (blockIdx.x * 256 >= in_k) return;
  const int rows = out_c >> 3;
  const int i0 = blockIdx.y * rows;
  __shared__ float uS[64];
  if (tid < rows) uS[tid] = args.u[l][i0 + tid];
  __syncthreads();
  if (j >= in_k) return;
  const float* __restrict__ w = args.w[l] + (size_t)i0 * in_k;
  float t = 0.f;
  for (int i = 0; i < rows; ++i) t = fmaf(w[(size_t)i * in_k + j], uS[i], t);
  vpart[((size_t)(l * 8 + blockIdx.y)) * 8192 + j] = t;
}

__global__ __launch_bounds__(256) void sn_v_red(SNArgs args, const float* __restrict__ vpart,
                                                float* __restrict__ vbuf, float* __restrict__ pA) {
  const int l = blockIdx.y;
  const int in_k = args.ink[l];
  const int tid = threadIdx.x;
  const int j = blockIdx.x * 256 + tid;
  __shared__ float red[4];
  float s = 0.f;
  if (j < in_k) {
    #pragma unroll
    for (int ch = 0; ch < 8; ++ch)
      s += vpart[((size_t)(l * 8 + ch)) * 8192 + j];
    vbuf[l * 8192 + j] = s;
  }
  const float bs = blockReduceSum256((j < in_k) ? s * s : 0.f, red);
  if (tid == 0) pA[l * 32 + blockIdx.x] = bs;
}

__global__ __launch_bounds__(64) void sn_norm1(SNArgs args, const float* __restrict__ pA,
                                               float* __restrict__ rinv) {
  const int l = blockIdx.x;
  if (threadIdx.x != 0) return;
  const int nb = (args.ink[l] + 255) >> 8;
  float s = 0.f;
  for (int b = 0; b < nb; ++b) s += pA[l * 32 + b];
  rinv[l] = 1.f / (sqrtf(s) + SN_EPS);
}

__global__ __launch_bounds__(256) void sn_t2(SNArgs args, const float* __restrict__ vbuf,
                                             const float* __restrict__ rinv,
                                             float* __restrict__ pB) {
  const int l = blockIdx.y;
  const int in_k = args.ink[l], out_c = args.outc[l];
  const int lane = threadIdx.x & 63, wv = threadIdx.x >> 6;
  const int row = blockIdx.x * 4 + wv;
  __shared__ float red[4];
  float sq = 0.f;
  if (row < out_c) {
    const float* __restrict__ wr = args.w[l] + (size_t)row * in_k;
    const float* __restrict__ v = vbuf + l * 8192;
    float a0 = 0.f, a1 = 0.f, a2 = 0.f, a3 = 0.f;
    for (int j = lane * 4; j < in_k; j += 256) {
      f32x4 w4 = *(const f32x4*)(wr + j);
      f32x4 v4 = *(const f32x4*)(v + j);
      a0 = fmaf(w4[0], v4[0], a0);
      a1 = fmaf(w4[1], v4[1], a1);
      a2 = fmaf(w4[2], v4[2], a2);
      a3 = fmaf(w4[3], v4[3], a3);
    }
    float t = (a0 + a1) + (a2 + a3);
    #pragma unroll
    for (int o = 32; o > 0; o >>= 1) t += __shfl_down(t, o, 64);
    if (lane == 0) { t *= rinv[l]; sq = t * t; }
  }
  __syncthreads();
  if (lane == 0) red[wv] = sq;
  __syncthreads();
  if (threadIdx.x == 0) pB[l * 128 + blockIdx.x] = red[0] + red[1] + red[2] + red[3];
}

__global__ __launch_bounds__(64) void sn_norm2(const float* __restrict__ pB,
                                               float* __restrict__ inv_sigma) {
  const int l = blockIdx.x;
  if (threadIdx.x != 0) return;
  float s = 0.f;
  for (int b = 0; b < 128; ++b) s += pB[l * 128 + b];
  const float n2 = sqrtf(s);
  const float sigma = s / (n2 + SN_EPS);
  inv_sigma[l] = 1.f / sigma;
}

// ---------------------------------------------------------------- zero the OOB pad regions
__global__ __launch_bounds__(256) void zero_pads(__hip_bfloat16* r0, __hip_bfloat16* r1) {
  int t = blockIdx.x * 256 + threadIdx.x;
  if (t < 2048) {
    r0[16777216 + t] = __float2bfloat16(0.f);
    r1[16777216 + t] = __float2bfloat16(0.f);
  }
}

// ---------------------------------------------------------------- batched weight prepack (all 6 layers, 1 dispatch)
struct PPArgs {
  const float* w[6];
  __hip_bfloat16* dst[6];
  int cinr[6];
  int cout[6];
  int kpad[6];
  int kreal[6];
};

__global__ __launch_bounds__(256) void prepack_all(PPArgs args, const float* __restrict__ invs) {
  const int l = blockIdx.y;
  int e = blockIdx.x * 256 + threadIdx.x;
  const int total = args.kpad[l] * args.cout[l];
  if (e >= total) return;
  const int CINR = args.cinr[l], COUT = args.cout[l], KREAL = args.kreal[l];
  int j = e & 7, lane = (e >> 3) & 63, frag = e >> 9;
  int nfrags = COUT >> 4;
  int ks = frag / nfrags, nf = frag - ks * nfrags;
  int k = ks * 32 + ((lane >> 4) << 3) + j;
  int co = (nf << 4) + (lane & 15);
  float val = 0.f;
  if (k < KREAL) {
    int khw = k / CINR, ci = k - khw * CINR;
    int kh = khw >> 2, kw = khw & 3;
    val = args.w[l][(((size_t)co * CINR + ci) * 4 + kh) * 4 + kw] * invs[l];
  }
  args.dst[l][e] = __float2bfloat16(val);
}

// ---------------------------------------------------------------- L1 im2col, coalesced 16B writes
__global__ __launch_bounds__(256) void im2col_l1(const float* __restrict__ img,
                                                 __hip_bfloat16* __restrict__ a2) {
  int t = blockIdx.x * 256 + threadIdx.x;      // 2097152
  int c = t & 7;
  int m = t >> 3;
  int n = m >> 12;
  int hw = m & 4095;
  int ho = hw >> 6, wo = hw & 63;
  int ihb = 2 * ho - 1, iwb = 2 * wo - 1;
  const float* __restrict__ ib = img + (size_t)n * 49152;
  short vals[8];
  #pragma unroll
  for (int j = 0; j < 8; ++j) {
    int k = c * 8 + j;
    float val = 0.f;
    if (k < 48) {
      int khw = k / 3;
      int ci = k - khw * 3;
      int kh = khw >> 2, kw = khw & 3;
      int ih = ihb + kh, iw = iwb + kw;
      if (((unsigned)ih < 128u) & ((unsigned)iw < 128u))
        val = ib[ci * 16384 + ih * 128 + iw];
    }
    vals[j] = f2bf(val);
  }
  *(bf16x8*)(a2 + (size_t)m * 64 + c * 8) = *(bf16x8*)vals;
}

// ---------------------------------------------------------------- L1 MFMA GEMM (1x1 over pre-im2col'd A), XCD-swizzled
template<int CIN, int COUT, int MF, bool FUSE>
__global__ __launch_bounds__(256) void conv_mfma(
    const __hip_bfloat16* __restrict__ x,
    const __hip_bfloat16* __restrict__ wf,
    __hip_bfloat16* __restrict__ out)
{
  constexpr int CB = CIN / 32;

  const int bx = xcd_swz(blockIdx.x, gridDim.x);
  const int lane = threadIdx.x & 63;
  const int wid  = threadIdx.x >> 6;
  const int wm = wid >> 1, wn = wid & 1;
  const int mbase = bx * (MF * 32) + wm * (MF * 16);
  const int cobase = blockIdx.y * 64 + wn * 32;

  int offm[MF];
  #pragma unroll
  for (int mf = 0; mf < MF; ++mf) {
    int m = mbase + mf * 16 + (lane & 15);
    offm[mf] = m * CIN;
  }
  const int koff = (lane >> 4) << 3;
  const __hip_bfloat16* wfp = wf + ((size_t)((blockIdx.y * 4 + wn * 2) * 64 + lane)) * 8;

  f32x4 acc[MF][2];
  #pragma unroll
  for (int mf = 0; mf < MF; ++mf) {
    acc[mf][0] = (f32x4){0.f, 0.f, 0.f, 0.f};
    acc[mf][1] = (f32x4){0.f, 0.f, 0.f, 0.f};
  }

  #pragma unroll
  for (int cb = 0; cb < CB; ++cb) {
    bf16x8 a[MF], b[2];
    #pragma unroll
    for (int mf = 0; mf < MF; ++mf) a[mf] = *(const bf16x8*)(x + offm[mf] + koff + cb * 32);
    #pragma unroll
    for (int nf = 0; nf < 2; ++nf)
      b[nf] = *(const bf16x8*)(wfp + (size_t)cb * (COUT * 32) + nf * 512);
    #pragma unroll
    for (int mf = 0; mf < MF; ++mf)
      #pragma unroll
      for (int nf = 0; nf < 2; ++nf)
        acc[mf][nf] = __builtin_amdgcn_mfma_f32_16x16x32_bf16(a[mf], b[nf], acc[mf][nf], 0, 0, 0);
  }

  const int r0 = (lane >> 4) * 4;
  const int cw = cobase + (lane & 15);
  #pragma unroll
  for (int mf = 0; mf < MF; ++mf)
    #pragma unroll
    for (int nf = 0; nf < 2; ++nf)
      #pragma unroll
      for (int r = 0; r < 4; ++r) {
        float v = acc[mf][nf][r];
        if (FUSE) v = (v >= 0.f) ? v : LRELU * v;
        int m = mbase + mf * 16 + r0 + r;
        out[(size_t)m * COUT + (cw + nf * 16)] = __float2bfloat16(v);
      }
}

// ---------------------------------------------------------------- LDS-staged 128x128 conv, k4 s2 p1 (reg-staged, 2 barriers/step)
// A and B staged once per block; optional BN+lrelu at stage time (BNIN);
// optional split-K over khw with bf16 partials (SPLITK).
template<int CIN, int COUT, int HIN, int HOUT, int Z, bool SPLITK, bool BNIN>
__global__ __launch_bounds__(256) void conv_lds(
    const __hip_bfloat16* __restrict__ x,
    const __hip_bfloat16* __restrict__ wf,
    const float* __restrict__ sbp,
    __hip_bfloat16* __restrict__ outb)
{
  constexpr int WIN = HIN, WO = HOUT;
  constexpr int CB = CIN / 32;
  constexpr int KHW_PER = 16 / Z;
  constexpr int NSTEP = KHW_PER * CB;
  constexpr int PADOFF = 16777216;
  constexpr int M = 64 * HOUT * WO;

  __shared__ __hip_bfloat16 As[128 * 32];   // [row][32 k]
  __shared__ __hip_bfloat16 Bs[4096];       // [8 nfrag][64 lane][8]

  const int bx = xcd_swz(blockIdx.x, gridDim.x);
  const int t = threadIdx.x;
  const int lane = t & 63;
  const int wid = t >> 6;
  const int wm = wid >> 1, wn = wid & 1;
  const int mbase = bx * 128;
  const int nbase = blockIdx.y * 128;
  const int khw0 = blockIdx.z * KHW_PER;

  const int sr0 = t >> 2;
  const int sl  = t & 3;
  int rowbase[2], ihbs[2], iwbs[2];
  #pragma unroll
  for (int i = 0; i < 2; ++i) {
    int m = mbase + sr0 + i * 64;
    int n = m / (HOUT * WO);
    int hw = m - n * (HOUT * WO);
    int ho = hw / WO, wo = hw - ho * WO;
    ihbs[i] = 2 * ho - 1;
    iwbs[i] = 2 * wo - 1;
    rowbase[i] = ((n * HIN + ihbs[i]) * WIN + iwbs[i]) * CIN;
  }
  const size_t bslab0 = (size_t)(nbase >> 4) * 512 + (size_t)t * 8;

  f32x4 acc[4][4];
  #pragma unroll
  for (int mf = 0; mf < 4; ++mf)
    #pragma unroll
    for (int nf = 0; nf < 4; ++nf) acc[mf][nf] = (f32x4){0.f, 0.f, 0.f, 0.f};

  bf16x8 ra0, ra1, rb0, rb1;
  f32x4 sc0, sc1, of0, of1;
  bool v0 = true, v1 = true;
  auto load_step = [&](int ks) {
    const int khw = khw0 + ks / CB;
    const int cb = ks % CB;
    const int kh = khw >> 2, kw = khw & 3;
    const int kbyteoff = cb * 32 + sl * 8;
    {
      int ih = ihbs[0] + kh, iw = iwbs[0] + kw;
      v0 = ((unsigned)ih < (unsigned)HIN) & ((unsigned)iw < (unsigned)WIN);
      int off = v0 ? (rowbase[0] + (kh * WIN + kw) * CIN + kbyteoff) : PADOFF;
      ra0 = *(const bf16x8*)(x + off);
    }
    {
      int ih = ihbs[1] + kh, iw = iwbs[1] + kw;
      v1 = ((unsigned)ih < (unsigned)HIN) & ((unsigned)iw < (unsigned)WIN);
      int off = v1 ? (rowbase[1] + (kh * WIN + kw) * CIN + kbyteoff) : PADOFF;
      ra1 = *(const bf16x8*)(x + off);
    }
    const size_t kg = (size_t)khw * CB + cb;
    const size_t bo = kg * (COUT * 32) + bslab0;
    rb0 = *(const bf16x8*)(wf + bo);
    rb1 = *(const bf16x8*)(wf + bo + 2048);
    if (BNIN) {
      const int cbv = cb * 32 + sl * 8;
      sc0 = *(const f32x4*)(sbp + cbv);
      sc1 = *(const f32x4*)(sbp + cbv + 4);
      of0 = *(const f32x4*)(sbp + CIN + cbv);
      of1 = *(const f32x4*)(sbp + CIN + cbv + 4);
    }
  };

  load_step(0);
  for (int ks = 0; ks < NSTEP; ++ks) {
    __syncthreads();                         // prior step's ds_reads complete
    bf16x8 wa0 = ra0, wa1 = ra1;
    if (BNIN) {
      #pragma unroll
      for (int j = 0; j < 8; ++j) {
        float sc = (j < 4) ? sc0[j] : sc1[j - 4];
        float of = (j < 4) ? of0[j] : of1[j - 4];
        float f0 = fmaf(bf2f(wa0[j]), sc, of);
        f0 = fmaxf(f0, LRELU * f0);
        wa0[j] = v0 ? f2bf(f0) : (short)0;
        float f1 = fmaf(bf2f(wa1[j]), sc, of);
        f1 = fmaxf(f1, LRELU * f1);
        wa1[j] = v1 ? f2bf(f1) : (short)0;
      }
    }
    *(bf16x8*)(&As[sr0 * 32 + sl * 8]) = wa0;
    *(bf16x8*)(&As[(sr0 + 64) * 32 + sl * 8]) = wa1;
    *(bf16x8*)(&Bs[t * 8]) = rb0;
    *(bf16x8*)(&Bs[2048 + t * 8]) = rb1;
    __syncthreads();                         // tile visible
    if (ks + 1 < NSTEP) load_step(ks + 1);   // overlap next loads with MFMA
    bf16x8 af[4], bfr[4];
    #pragma unroll
    for (int mf = 0; mf < 4; ++mf) {
      const int ra = wm * 64 + mf * 16 + (lane & 15);
      af[mf] = *(const bf16x8*)(&As[ra * 32 + (lane >> 4) * 8]);
    }
    #pragma unroll
    for (int nf = 0; nf < 4; ++nf)
      bfr[nf] = *(const bf16x8*)(&Bs[(wn * 4 + nf) * 512 + lane * 8]);
    #pragma unroll
    for (int mf = 0; mf < 4; ++mf)
      #pragma unroll
      for (int nf = 0; nf < 4; ++nf)
        acc[mf][nf] = __builtin_amdgcn_mfma_f32_16x16x32_bf16(af[mf], bfr[nf], acc[mf][nf], 0, 0, 0);
  }

  const int r0w = (lane >> 4) * 4;
  const int cw = nbase + wn * 64 + (lane & 15);
  #pragma unroll
  for (int mf = 0; mf < 4; ++mf)
    #pragma unroll
    for (int nf = 0; nf < 4; ++nf)
      #pragma unroll
      for (int r = 0; r < 4; ++r) {
        const int m = mbase + wm * 64 + mf * 16 + r0w + r;
        const int co = cw + nf * 16;
        if (SPLITK)
          outb[(size_t)blockIdx.z * M * COUT + (size_t)m * COUT + co] = __float2bfloat16(acc[mf][nf][r]);
        else
          outb[(size_t)m * COUT + co] = __float2bfloat16(acc[mf][nf][r]);
      }
}

// ---------------------------------------------------------------- 4x4-fragment implicit-GEMM conv (L5)
template<int CIN, int COUT, int HIN, int HOUT, int Z, bool SPLITK, bool BNIN, bool BF16P>
__global__ __launch_bounds__(256) void conv_mfma4(
    const __hip_bfloat16* __restrict__ x,
    const __hip_bfloat16* __restrict__ wf,
    const float* __restrict__ sbp,
    __hip_bfloat16* __restrict__ outb, float* __restrict__ outp)
{
  constexpr int WIN = HIN, WO = HOUT;
  constexpr int CB = CIN / 32;
  constexpr int KHW_PER = 16 / Z;
  constexpr int PADOFF = 16777216;
  constexpr int M = 64 * HOUT * WO;

  const int bx = xcd_swz(blockIdx.x, gridDim.x);
  const int lane = threadIdx.x & 63;
  const int wid  = threadIdx.x >> 6;
  const int wm = wid >> 1, wn = wid & 1;
  const int mbase = bx * 128 + wm * 64;
  const int nbase = blockIdx.y * 128 + wn * 64;
  const int khw0 = blockIdx.z * KHW_PER;

  int offm[4], ihb[4], iwb[4];
  #pragma unroll
  for (int mf = 0; mf < 4; ++mf) {
    int m = mbase + mf * 16 + (lane & 15);
    int n = m / (HOUT * WO);
    int hw = m - n * (HOUT * WO);
    int ho = hw / WO, wo = hw - ho * WO;
    ihb[mf] = 2 * ho - 1;
    iwb[mf] = 2 * wo - 1;
    offm[mf] = ((n * HIN + ihb[mf]) * WIN + iwb[mf]) * CIN;
  }
  const int koff = (lane >> 4) << 3;
  const __hip_bfloat16* wfp = wf + ((size_t)((nbase >> 4) * 64 + lane)) * 8;

  f32x4 acc[4][4];
  #pragma unroll
  for (int mf = 0; mf < 4; ++mf)
    #pragma unroll
    for (int nf = 0; nf < 4; ++nf) acc[mf][nf] = (f32x4){0.f, 0.f, 0.f, 0.f};

  #pragma unroll
  for (int cb = 0; cb < CB; ++cb) {
    f32x4 s0, s1, o0, o1;
    if (BNIN) {
      const int cbase = cb * 32 + koff;
      s0 = *(const f32x4*)(sbp + cbase);
      s1 = *(const f32x4*)(sbp + cbase + 4);
      o0 = *(const f32x4*)(sbp + CIN + cbase);
      o1 = *(const f32x4*)(sbp + CIN + cbase + 4);
    }
    #pragma unroll
    for (int ki = 0; ki < KHW_PER; ++ki) {
      const int khw = khw0 + ki;
      const int kh = khw >> 2, kw = khw & 3;
      bf16x8 a[4], b[4];
      bool vm[4];
      #pragma unroll
      for (int mf = 0; mf < 4; ++mf) {
        int ih = ihb[mf] + kh, iw = iwb[mf] + kw;
        vm[mf] = ((unsigned)ih < (unsigned)HIN) & ((unsigned)iw < (unsigned)WIN);
        int off = vm[mf] ? (offm[mf] + (kh * WIN + kw) * CIN + koff + cb * 32)
                         : (PADOFF + koff + cb * 32);
        a[mf] = *(const bf16x8*)(x + off);
      }
      const size_t ks = (size_t)khw * CB + cb;
      #pragma unroll
      for (int nf = 0; nf < 4; ++nf)
        b[nf] = *(const bf16x8*)(wfp + ks * (COUT * 32) + nf * 512);
      if (BNIN) {
        #pragma unroll
        for (int mf = 0; mf < 4; ++mf) {
          bf16x8 tt = a[mf];
          #pragma unroll
          for (int j = 0; j < 8; ++j) {
            float fv = bf2f(tt[j]);
            float sc = (j < 4) ? s0[j] : s1[j - 4];
            float of = (j < 4) ? o0[j] : o1[j - 4];
            fv = fmaf(fv, sc, of);
            fv = fmaxf(fv, LRELU * fv);
            tt[j] = vm[mf] ? f2bf(fv) : (short)0;
          }
          a[mf] = tt;
        }
      }
      #pragma unroll
      for (int mf = 0; mf < 4; ++mf)
        #pragma unroll
        for (int nf = 0; nf < 4; ++nf)
          acc[mf][nf] = __builtin_amdgcn_mfma_f32_16x16x32_bf16(a[mf], b[nf], acc[mf][nf], 0, 0, 0);
    }
  }

  const int r0 = (lane >> 4) * 4;
  const int cw = nbase + (lane & 15);
  #pragma unroll
  for (int mf = 0; mf < 4; ++mf)
    #pragma unroll
    for (int nf = 0; nf < 4; ++nf)
      #pragma unroll
      for (int r = 0; r < 4; ++r) {
        const int m = mbase + mf * 16 + r0 + r;
        const int co = cw + nf * 16;
        if (SPLITK) {
          if (BF16P)
            outb[(size_t)blockIdx.z * M * COUT + (size_t)m * COUT + co] = __float2bfloat16(acc[mf][nf][r]);
          else
            outp[(size_t)blockIdx.z * M * COUT + (size_t)m * COUT + co] = acc[mf][nf][r];
        } else {
          outb[(size_t)m * COUT + co] = __float2bfloat16(acc[mf][nf][r]);
        }
      }
}

// ---------------------------------------------------------------- fused: split-K reduce + bf16 write + BN partial stats
template<int Z, int MCHUNKS, bool BF16P>
__global__ __launch_bounds__(256) void sk_bn_fuse(const float* __restrict__ partf,
                                                  const __hip_bfloat16* __restrict__ partb,
                                                  __hip_bfloat16* __restrict__ xo,
                                                  float* __restrict__ statp, int M, int C) {
  const int chunk = blockIdx.x;
  const int c0 = blockIdx.y * 64 + (threadIdx.x & 7) * 8;
  const int mrow = threadIdx.x >> 3;
  const int rows = M / MCHUNKS;
  const size_t MC = (size_t)M * C;
  float s[8], s2[8];
  #pragma unroll
  for (int j = 0; j < 8; ++j) { s[j] = 0.f; s2[j] = 0.f; }
  for (int mi = mrow; mi < rows; mi += 32) {
    const int m = chunk * rows + mi;
    const size_t base = (size_t)m * C + c0;
    float av[8];
    if (BF16P) {
      bf16x8 v0 = *(const bf16x8*)(partb + base);
      #pragma unroll
      for (int j = 0; j < 8; ++j) av[j] = bf2f(v0[j]);
      #pragma unroll
      for (int z = 1; z < Z; ++z) {
        bf16x8 vz = *(const bf16x8*)(partb + (size_t)z * MC + base);
        #pragma unroll
        for (int j = 0; j < 8; ++j) av[j] += bf2f(vz[j]);
      }
    } else {
      f32x4 a = *(const f32x4*)(partf + base);
      f32x4 b = *(const f32x4*)(partf + base + 4);
      #pragma unroll
      for (int z = 1; z < Z; ++z) {
        a += *(const f32x4*)(partf + (size_t)z * MC + base);
        b += *(const f32x4*)(partf + (size_t)z * MC + base + 4);
      }
      #pragma unroll
      for (int j = 0; j < 4; ++j) { av[j] = a[j]; av[4 + j] = b[j]; }
    }
    bf16x8 o;
    #pragma unroll
    for (int j = 0; j < 8; ++j) {
      o[j] = f2bf(av[j]);
      s[j] += av[j];
      s2[j] = fmaf(av[j], av[j], s2[j]);
    }
    *(bf16x8*)(xo + base) = o;
  }
  __shared__ float ls[8][256], ls2[8][256];
  const int t = threadIdx.x;
  #pragma unroll
  for (int j = 0; j < 8; ++j) { ls[j][t] = s[j]; ls2[j][t] = s2[j]; }
  __syncthreads();
  #pragma unroll
  for (int off = 16; off >= 1; off >>= 1) {
    if (mrow < off) {
      #pragma unroll
      for (int j = 0; j < 8; ++j) {
        ls[j][t]  += ls[j][t + off * 8];
        ls2[j][t] += ls2[j][t + off * 8];
      }
    }
    __syncthreads();
  }
  if (t < 8) {
    #pragma unroll
    for (int j = 0; j < 8; ++j) {
      statp[(size_t)chunk * C + c0 + j] = ls[j][t];
      statp[(size_t)(MCHUNKS + chunk) * C + c0 + j] = ls2[j][t];
    }
  }
}

// ---------------------------------------------------------------- L6 MFMA conv (plain); writes flat part of out
__global__ __launch_bounds__(256) void conv_l6_mfma(
    const __hip_bfloat16* __restrict__ x,
    const __hip_bfloat16* __restrict__ wf,
    float* __restrict__ x6, float* __restrict__ out)
{
  constexpr int CIN = 512, COUT = 64, HIN = 4;
  constexpr int CB = CIN / 32;
  constexpr int PADOFF = 16777216;

  const int lane = threadIdx.x & 63;
  const int wid  = threadIdx.x >> 6;
  const int wm = wid >> 1, wn = wid & 1;
  const int mbase = blockIdx.x * 32 + wm * 16;

  int m0 = mbase + (lane & 15);
  int n = m0 >> 2;
  int hw = m0 & 3;
  int ho = hw >> 1, wo = hw & 1;
  int ihb = 2 * ho - 1;
  int iwb = 2 * wo - 1;
  int offm = ((n * HIN + ihb) * HIN + iwb) * CIN;

  const int koff = (lane >> 4) << 3;
  const __hip_bfloat16* wfp = wf + ((size_t)((wn * 2) * 64 + lane)) * 8;

  f32x4 acc[2];
  acc[0] = (f32x4){0.f, 0.f, 0.f, 0.f};
  acc[1] = (f32x4){0.f, 0.f, 0.f, 0.f};

  #pragma unroll
  for (int khw = 0; khw < 16; ++khw) {
    const int kh = khw >> 2, kw = khw & 3;
    const int ih = ihb + kh, iw = iwb + kw;
    const bool v = ((unsigned)ih < (unsigned)HIN) & ((unsigned)iw < (unsigned)HIN);
    const int off = v ? (offm + (kh * HIN + kw) * CIN + koff) : (PADOFF + koff);
    const __hip_bfloat16* ap = x + off;
    #pragma unroll
    for (int cb = 0; cb < CB; ++cb) {
      const int ks = khw * CB + cb;
      bf16x8 a = *(const bf16x8*)(ap + cb * 32);
      bf16x8 b0 = *(const bf16x8*)(wfp + (size_t)ks * (COUT * 32));
      bf16x8 b1 = *(const bf16x8*)(wfp + (size_t)ks * (COUT * 32) + 512);
      acc[0] = __builtin_amdgcn_mfma_f32_16x16x32_bf16(a, b0, acc[0], 0, 0, 0);
      acc[1] = __builtin_amdgcn_mfma_f32_16x16x32_bf16(a, b1, acc[1], 0, 0, 0);
    }
  }

  const int r0 = (lane >> 4) * 4;
  const int cw = wn * 32 + (lane & 15);
  #pragma unroll
  for (int nf = 0; nf < 2; ++nf)
    #pragma unroll
    for (int r = 0; r < 4; ++r) {
      int m = mbase + r0 + r;
      int nn = m >> 2, p = m & 3;
      float v = acc[nf][r];
      x6[(size_t)nn * 256 + (cw + nf * 16) * 4 + p] = v;
      out[(size_t)nn * 320 + (cw + nf * 16) * 4 + p] = v;
    }
}

// ---------------------------------------------------------------- BN stats (direct-output layers), vectorized
template<int MCHUNKS>
__global__ __launch_bounds__(256) void bn_stats_a(const __hip_bfloat16* __restrict__ x,
                                                  float* __restrict__ part, int M, int C) {
  const int chunk = blockIdx.x;
  const int c0 = blockIdx.y * 64 + (threadIdx.x & 7) * 8;
  const int mrow = threadIdx.x >> 3;
  const int rows = M / MCHUNKS;
  float s[8], s2[8];
  #pragma unroll
  for (int j = 0; j < 8; ++j) { s[j] = 0.f; s2[j] = 0.f; }
  for (int mi = mrow; mi < rows; mi += 32) {
    const int m = chunk * rows + mi;
    bf16x8 v = *(const bf16x8*)(x + (size_t)m * C + c0);
    #pragma unroll
    for (int j = 0; j < 8; ++j) {
      float f = bf2f(v[j]);
      s[j] += f;
      s2[j] = fmaf(f, f, s2[j]);
    }
  }
  __shared__ float ls[8][256], ls2[8][256];
  const int t = threadIdx.x;
  #pragma unroll
  for (int j = 0; j < 8; ++j) { ls[j][t] = s[j]; ls2[j][t] = s2[j]; }
  __syncthreads();
  #pragma unroll
  for (int off = 16; off >= 1; off >>= 1) {
    if (mrow < off) {
      #pragma unroll
      for (int j = 0; j < 8; ++j) {
        ls[j][t]  += ls[j][t + off * 8];
        ls2[j][t] += ls2[j][t + off * 8];
      }
    }
    __syncthreads();
  }
  if (t < 8) {
    #pragma unroll
    for (int j = 0; j < 8; ++j) {
      part[(size_t)chunk * C + c0 + j] = ls[j][t];
      part[(size_t)(MCHUNKS + chunk) * C + c0 + j] = ls2[j][t];
    }
  }
}

template<int MCHUNKS>
__global__ __launch_bounds__(64) void bn_stats_b(const float* __restrict__ part,
                                                 const float* __restrict__ g,
                                                 const float* __restrict__ b,
                                                 float* __restrict__ sb, int M, int C) {
  int c = blockIdx.x * 64 + threadIdx.x;
  float s = 0.f, s2 = 0.f;
  for (int ch = 0; ch < MCHUNKS; ++ch) {
    s  += part[(size_t)ch * C + c];
    s2 += part[(size_t)(MCHUNKS + ch) * C + c];
  }
  float invM = 1.f / (float)M;
  float mean = s * invM;
  float var = s2 * invM - mean * mean;
  float scale = g[c] * rsqrtf(var + BN_EPS);
  sb[c] = scale;
  sb[C + c] = b[c] - mean * scale;
}

// ---------------------------------------------------------------- BN apply (only x5 before L6)
__global__ __launch_bounds__(256) void bn_apply(__hip_bfloat16* __restrict__ x,
                                                const float* __restrict__ sb,
                                                int C, int nvec) {
  int idx = blockIdx.x * 256 + threadIdx.x;
  if (idx >= nvec) return;
  size_t e = (size_t)idx * 8;
  int c0 = (int)(e % (size_t)C);
  bf16x8 v = *(bf16x8*)(x + e);
  bf16x8 o;
  #pragma unroll
  for (int j = 0; j < 8; ++j) {
    int c = c0 + j;
    float f = bf2f(v[j]);
    f = fmaf(f, sb[c], sb[C + c]);
    f = (f >= 0.f) ? f : LRELU * f;
    o[j] = f2bf(f);
  }
  *(bf16x8*)(x + e) = o;
}

// ---------------------------------------------------------------- tail: Ms = flat @ T (256 blocks)
__global__ __launch_bounds__(256) void ms_kernel(const float* __restrict__ x6,
                                                 const float* __restrict__ T,
                                                 float* __restrict__ Ms) {
  const int cb = blockIdx.x;
  const int nb = blockIdx.y;
  const int c  = threadIdx.x & 63;
  const int ns = threadIdx.x >> 6;
  __shared__ float fsh[16][256];
  for (int t = threadIdx.x; t < 4096; t += 256) {
    int n = t >> 8, a = t & 255;
    fsh[n][a] = x6[(size_t)(nb * 16 + n) * 256 + a];
  }
  __syncthreads();
  const int col = cb * 64 + c;
  float acc0 = 0.f, acc1 = 0.f, acc2 = 0.f, acc3 = 0.f;
  #pragma unroll 8
  for (int a = 0; a < 256; ++a) {
    float tv = T[(size_t)a * 4096 + col];
    acc0 = fmaf(fsh[ns * 4 + 0][a], tv, acc0);
    acc1 = fmaf(fsh[ns * 4 + 1][a], tv, acc1);
    acc2 = fmaf(fsh[ns * 4 + 2][a], tv, acc2);
    acc3 = fmaf(fsh[ns * 4 + 3][a], tv, acc3);
  }
  const int nbase = nb * 16 + ns * 4;
  Ms[(size_t)(nbase + 0) * 4096 + col] = acc0;
  Ms[(size_t)(nbase + 1) * 4096 + col] = acc1;
  Ms[(size_t)(nbase + 2) * 4096 + col] = acc2;
  Ms[(size_t)(nbase + 3) * 4096 + col] = acc3;
}

// ---------------------------------------------------------------- minibatch discrimination (256 blocks)
__global__ __launch_bounds__(256) void mbd_kernel(const float* __restrict__ Ms,
                                                  float* __restrict__ out) {
  const int b  = blockIdx.x;
  const int ib = blockIdx.y;
  const int tid = threadIdx.x;
  __shared__ float Mb[64][65];
  for (int idx = tid; idx < 4096; idx += 256) {
    const int i = idx >> 6, cc = idx & 63;
    Mb[i][cc] = Ms[(size_t)i * 4096 + b * 64 + cc];
  }
  __syncthreads();
  const int i  = ib * 16 + (tid >> 4);
  const int jg = tid & 15;
  float ssum = 0.f;
  for (int j = jg; j < 64; j += 16) {
    float d = 0.f;
    #pragma unroll
    for (int cc = 0; cc < 64; ++cc) d += fabsf(Mb[i][cc] - Mb[j][cc]);
    ssum += expf(-d);
  }
  ssum += __shfl_xor(ssum, 1, 64);
  ssum += __shfl_xor(ssum, 2, 64);
  ssum += __shfl_xor(ssum, 4, 64);
  ssum += __shfl_xor(ssum, 8, 64);
  if (jg == 0) out[(size_t)i * 320 + 256 + b] = ssum;
}

// ---------------------------------------------------------------- launch
extern "C" void kernel_launch(void* const* d_in, const int* in_sizes, int n_in,
                              void* d_out, int out_size, void* d_ws, size_t ws_size,
                              hipStream_t stream) {
  const float* image = (const float*)d_in[0];
  const float* W[6] = {(const float*)d_in[1], (const float*)d_in[3], (const float*)d_in[5],
                       (const float*)d_in[7], (const float*)d_in[9], (const float*)d_in[11]};
  const float* U[6] = {(const float*)d_in[2], (const float*)d_in[4], (const float*)d_in[6],
                       (const float*)d_in[8], (const float*)d_in[10], (const float*)d_in[12]};
  const float* G[4] = {(const float*)d_in[13], (const float*)d_in[15],
                       (const float*)d_in[17], (const float*)d_in[19]};
  const float* Bb[4] = {(const float*)d_in[14], (const float*)d_in[16],
                        (const float*)d_in[18], (const float*)d_in[20]};
  const float* T = (const float*)d_in[21];
  float* out = (float*)d_out;

  // ---- workspace layout (floats)
  float* f = (float*)d_ws;
  float* inv_sigma = f;                                // 16
  float* part      = f + 1024;                         // 65536
  float* x6        = f + 1024 + 65536 + 1024;          // 16384
  float* Ms        = f + 1024 + 65536 + 1024 + 16384;  // 262144
  float* vbuf      = f + 360448;                       // 49152
  float* pA        = f + 360448 + 49152;               // 256 slots
  float* pB        = pA + 256;                         // 768
  float* rinv      = pB + 768;                         // 16
  float* sbL[4];                                       // per-layer BN scale/bias
  for (int i = 0; i < 4; ++i) sbL[i] = f + 412672 + i * 2048;
  __hip_bfloat16* bfb = (__hip_bfloat16*)(f + 524288);
  const size_t REGION = 16777216 + 2048;
  __hip_bfloat16* region0 = bfb;
  __hip_bfloat16* region1 = region0 + REGION;
  __hip_bfloat16* wf1 = region1 + REGION;
  __hip_bfloat16* wf2 = wf1 + 4096;
  __hip_bfloat16* wf3 = wf2 + 131072;
  __hip_bfloat16* wf4 = wf3 + 524288;
  __hip_bfloat16* wf5 = wf4 + 1048576;
  __hip_bfloat16* wf6 = wf5 + 2097152;
  float* skpart = (float*)(wf6 + 524288);              // 8388608 floats (also used as bf16)
  __hip_bfloat16* skpartb = (__hip_bfloat16*)skpart;
  float* vpart  = skpart + 8388608;                    // 393216 floats

  __hip_bfloat16* a2col = region0;
  __hip_bfloat16* x1 = region1;
  __hip_bfloat16* x2 = region0;
  __hip_bfloat16* x3 = region1;
  __hip_bfloat16* x4 = region0;
  __hip_bfloat16* x5 = region1;

  zero_pads<<<8, 256, 0, stream>>>(region0, region1);

  SNArgs sa;
  const int outc[6] = {64, 128, 256, 256, 512, 64};
  const int ink[6]  = {48, 1024, 2048, 4096, 4096, 8192};
  for (int l = 0; l < 6; ++l) { sa.w[l] = W[l]; sa.u[l] = U[l]; sa.outc[l] = outc[l]; sa.ink[l] = ink[l]; }

  sn_v<<<dim3(32, 8, 6), 256, 0, stream>>>(sa, vpart);
  sn_v_red<<<dim3(32, 6), 256, 0, stream>>>(sa, vpart, vbuf, pA);
  sn_norm1<<<6, 64, 0, stream>>>(sa, pA, rinv);
  sn_t2<<<dim3(128, 6), 256, 0, stream>>>(sa, vbuf, rinv, pB);
  sn_norm2<<<6, 64, 0, stream>>>(pB, inv_sigma);

  PPArgs pa;
  __hip_bfloat16* wfp_[6] = {wf1, wf2, wf3, wf4, wf5, wf6};
  const int cinr_[6]  = {3, 64, 128, 256, 256, 512};
  const int kpad_[6]  = {64, 1024, 2048, 4096, 4096, 8192};
  const int kreal_[6] = {48, 1024, 2048, 4096, 4096, 8192};
  for (int l = 0; l < 6; ++l) {
    pa.w[l] = W[l]; pa.dst[l] = wfp_[l]; pa.cinr[l] = cinr_[l];
    pa.cout[l] = outc[l]; pa.kpad[l] = kpad_[l]; pa.kreal[l] = kreal_[l];
  }
  prepack_all<<<dim3(8192, 6), 256, 0, stream>>>(pa, inv_sigma);

  im2col_l1<<<8192, 256, 0, stream>>>(image, a2col);

  // L1: [262144 x 64] @ [64 x 64], fused lrelu
  conv_mfma<64, 64, 4, true><<<dim3(2048, 1), 256, 0, stream>>>(a2col, wf1, x1);

  // L2: LDS-staged, raw input, direct bf16 out
  conv_lds<64, 128, 64, 32, 1, false, false><<<dim3(512, 1, 1), 256, 0, stream>>>(x1, wf2, nullptr, x2);
  bn_stats_a<256><<<dim3(256, 2), 256, 0, stream>>>(x2, part, 65536, 128);
  bn_stats_b<256><<<2, 64, 0, stream>>>(part, G[0], Bb[0], sbL[0], 65536, 128);

  // L3: LDS-staged, BN1+lrelu at stage, split-K Z=2 (bf16 partials); fused reduce+stats
  conv_lds<128, 256, 32, 16, 2, true, true><<<dim3(128, 2, 2), 256, 0, stream>>>(x2, wf3, sbL[0], skpartb);
  sk_bn_fuse<2, 128, true><<<dim3(128, 4), 256, 0, stream>>>(nullptr, skpartb, x3, part, 16384, 256);
  bn_stats_b<128><<<4, 64, 0, stream>>>(part, G[1], Bb[1], sbL[1], 16384, 256);

  // L4: LDS-staged, BN2+lrelu at stage, split-K Z=8 (bf16 partials); fused reduce+stats
  conv_lds<256, 256, 16, 8, 8, true, true><<<dim3(32, 2, 8), 256, 0, stream>>>(x3, wf4, sbL[1], skpartb);
  sk_bn_fuse<8, 128, true><<<dim3(128, 4), 256, 0, stream>>>(nullptr, skpartb, x4, part, 4096, 256);
  bn_stats_b<128><<<4, 64, 0, stream>>>(part, G[2], Bb[2], sbL[2], 4096, 256);

  // L5: fragment-direct, BN3+lrelu fused; split-K Z=16 (bf16 partials); fused reduce+stats
  conv_mfma4<256, 512, 8, 4, 16, true, true, true><<<dim3(8, 4, 16), 256, 0, stream>>>(x4, wf5, sbL[2], skpartb, nullptr);
  sk_bn_fuse<16, 32, true><<<dim3(32, 8), 256, 0, stream>>>(nullptr, skpartb, x5, part, 1024, 512);
  bn_stats_b<32><<<8, 64, 0, stream>>>(part, G[3], Bb[3], sbL[3], 1024, 512);

  // BN4 apply on x5 (tiny: 1 MB), then plain L6
  bn_apply<<<256, 256, 0, stream>>>(x5, sbL[3], 512, 65536);
  conv_l6_mfma<<<8, 256, 0, stream>>>(x5, wf6, x6, out);

  ms_kernel<<<dim3(64, 4), 256, 0, stream>>>(x6, T, Ms);
  mbd_kernel<<<dim3(64, 4), 256, 0, stream>>>(Ms, out);
}

// Round 24
// 333.745 us; speedup vs baseline: 1.3166x; 1.0053x over previous
//
#include <hip/hip_runtime.h>
#include <hip/hip_bf16.h>
#include <math.h>

#define LRELU 0.2f
#define BN_EPS 1e-5f
#define SN_EPS 1e-12f

typedef __attribute__((ext_vector_type(4))) float f32x4;
typedef __attribute__((ext_vector_type(8))) short bf16x8;
typedef __attribute__((ext_vector_type(4))) short bf16x4;

__device__ inline float bf2f(short s) {
  union { unsigned u; float f; } c; c.u = ((unsigned)(unsigned short)s) << 16; return c.f;
}
__device__ inline short f2bf(float f) {
  __hip_bfloat16 h = __float2bfloat16(f); return *(short*)&h;
}

// XCD-aware bijective block swizzle (requires gridDim.x % 8 == 0)
__device__ inline int xcd_swz(int bx, int nwg) {
  int chunk = nwg >> 3;
  return (bx & 7) * chunk + (bx >> 3);
}

// ---------------------------------------------------------------- reductions
__device__ inline float blockReduceSum256(float v, volatile float* red) {
  #pragma unroll
  for (int o = 32; o > 0; o >>= 1) v += __shfl_down(v, o, 64);
  const int tid = threadIdx.x;
  __syncthreads();
  if ((tid & 63) == 0) red[tid >> 6] = v;
  __syncthreads();
  return red[0] + red[1] + red[2] + red[3];
}

// ---------------------------------------------------------------- spectral norm, parallel 5-stage chain
struct SNArgs {
  const float* w[6];
  const float* u[6];
  int outc[6];
  int ink[6];
};

__global__ __launch_bounds__(256) void sn_v(SNArgs args, float* __restrict__ vpart) {
  const int l = blockIdx.z;
  const int in_k = args.ink[l], out_c = args.outc[l];
  const int tid = threadIdx.x;
  const int j = blockIdx.x * 256 + tid;
  if (blockIdx.x * 256 >= in_k) return;
  const int rows = out_c >> 3;
  const int i0 = blockIdx.y * rows;
  __shared__ float uS[64];
  if (tid < rows) uS[tid] = args.u[l][i0 + tid];
  __syncthreads();
  if (j >= in_k) return;
  const float* __restrict__ w = args.w[l] + (size_t)i0 * in_k;
  float t = 0.f;
  for (int i = 0; i < rows; ++i) t = fmaf(w[(size_t)i * in_k + j], uS[i], t);
  vpart[((size_t)(l * 8 + blockIdx.y)) * 8192 + j] = t;
}

__global__ __launch_bounds__(256) void sn_v_red(SNArgs args, const float* __restrict__ vpart,
                                                float* __restrict__ vbuf, float* __restrict__ pA) {
  const int l = blockIdx.y;
  const int in_k = args.ink[l];
  const int tid = threadIdx.x;
  const int j = blockIdx.x * 256 + tid;
  __shared__ float red[4];
  float s = 0.f;
  if (j < in_k) {
    #pragma unroll
    for (int ch = 0; ch < 8; ++ch)
      s += vpart[((size_t)(l * 8 + ch)) * 8192 + j];
    vbuf[l * 8192 + j] = s;
  }
  const float bs = blockReduceSum256((j < in_k) ? s * s : 0.f, red);
  if (tid == 0) pA[l * 32 + blockIdx.x] = bs;
}

__global__ __launch_bounds__(64) void sn_norm1(SNArgs args, const float* __restrict__ pA,
                                               float* __restrict__ rinv) {
  const int l = blockIdx.x;
  if (threadIdx.x != 0) return;
  const int nb = (args.ink[l] + 255) >> 8;
  float s = 0.f;
  for (int b = 0; b < nb; ++b) s += pA[l * 32 + b];
  rinv[l] = 1.f / (sqrtf(s) + SN_EPS);
}

__global__ __launch_bounds__(256) void sn_t2(SNArgs args, const float* __restrict__ vbuf,
                                             const float* __restrict__ rinv,
                                             float* __restrict__ pB) {
  const int l = blockIdx.y;
  const int in_k = args.ink[l], out_c = args.outc[l];
  const int lane = threadIdx.x & 63, wv = threadIdx.x >> 6;
  const int row = blockIdx.x * 4 + wv;
  __shared__ float red[4];
  float sq = 0.f;
  if (row < out_c) {
    const float* __restrict__ wr = args.w[l] + (size_t)row * in_k;
    const float* __restrict__ v = vbuf + l * 8192;
    float a0 = 0.f, a1 = 0.f, a2 = 0.f, a3 = 0.f;
    for (int j = lane * 4; j < in_k; j += 256) {
      f32x4 w4 = *(const f32x4*)(wr + j);
      f32x4 v4 = *(const f32x4*)(v + j);
      a0 = fmaf(w4[0], v4[0], a0);
      a1 = fmaf(w4[1], v4[1], a1);
      a2 = fmaf(w4[2], v4[2], a2);
      a3 = fmaf(w4[3], v4[3], a3);
    }
    float t = (a0 + a1) + (a2 + a3);
    #pragma unroll
    for (int o = 32; o > 0; o >>= 1) t += __shfl_down(t, o, 64);
    if (lane == 0) { t *= rinv[l]; sq = t * t; }
  }
  __syncthreads();
  if (lane == 0) red[wv] = sq;
  __syncthreads();
  if (threadIdx.x == 0) pB[l * 128 + blockIdx.x] = red[0] + red[1] + red[2] + red[3];
}

__global__ __launch_bounds__(64) void sn_norm2(const float* __restrict__ pB,
                                               float* __restrict__ inv_sigma) {
  const int l = blockIdx.x;
  if (threadIdx.x != 0) return;
  float s = 0.f;
  for (int b = 0; b < 128; ++b) s += pB[l * 128 + b];
  const float n2 = sqrtf(s);
  const float sigma = s / (n2 + SN_EPS);
  inv_sigma[l] = 1.f / sigma;
}

// ---------------------------------------------------------------- zero the OOB pad regions
__global__ __launch_bounds__(256) void zero_pads(__hip_bfloat16* r0, __hip_bfloat16* r1) {
  int t = blockIdx.x * 256 + threadIdx.x;
  if (t < 2048) {
    r0[16777216 + t] = __float2bfloat16(0.f);
    r1[16777216 + t] = __float2bfloat16(0.f);
  }
}

// ---------------------------------------------------------------- batched weight prepack (all 6 layers, 1 dispatch)
struct PPArgs {
  const float* w[6];
  __hip_bfloat16* dst[6];
  int cinr[6];
  int cout[6];
  int kpad[6];
  int kreal[6];
};

__global__ __launch_bounds__(256) void prepack_all(PPArgs args, const float* __restrict__ invs) {
  const int l = blockIdx.y;
  int e = blockIdx.x * 256 + threadIdx.x;
  const int total = args.kpad[l] * args.cout[l];
  if (e >= total) return;
  const int CINR = args.cinr[l], COUT = args.cout[l], KREAL = args.kreal[l];
  int j = e & 7, lane = (e >> 3) & 63, frag = e >> 9;
  int nfrags = COUT >> 4;
  int ks = frag / nfrags, nf = frag - ks * nfrags;
  int k = ks * 32 + ((lane >> 4) << 3) + j;
  int co = (nf << 4) + (lane & 15);
  float val = 0.f;
  if (k < KREAL) {
    int khw = k / CINR, ci = k - khw * CINR;
    int kh = khw >> 2, kw = khw & 3;
    val = args.w[l][(((size_t)co * CINR + ci) * 4 + kh) * 4 + kw] * invs[l];
  }
  args.dst[l][e] = __float2bfloat16(val);
}

// ---------------------------------------------------------------- L1 im2col, coalesced 16B writes
__global__ __launch_bounds__(256) void im2col_l1(const float* __restrict__ img,
                                                 __hip_bfloat16* __restrict__ a2) {
  int t = blockIdx.x * 256 + threadIdx.x;      // 2097152
  int c = t & 7;
  int m = t >> 3;
  int n = m >> 12;
  int hw = m & 4095;
  int ho = hw >> 6, wo = hw & 63;
  int ihb = 2 * ho - 1, iwb = 2 * wo - 1;
  const float* __restrict__ ib = img + (size_t)n * 49152;
  short vals[8];
  #pragma unroll
  for (int j = 0; j < 8; ++j) {
    int k = c * 8 + j;
    float val = 0.f;
    if (k < 48) {
      int khw = k / 3;
      int ci = k - khw * 3;
      int kh = khw >> 2, kw = khw & 3;
      int ih = ihb + kh, iw = iwb + kw;
      if (((unsigned)ih < 128u) & ((unsigned)iw < 128u))
        val = ib[ci * 16384 + ih * 128 + iw];
    }
    vals[j] = f2bf(val);
  }
  *(bf16x8*)(a2 + (size_t)m * 64 + c * 8) = *(bf16x8*)vals;
}

// ---------------------------------------------------------------- L1 MFMA GEMM (1x1 over pre-im2col'd A), XCD-swizzled
template<int CIN, int COUT, int MF, bool FUSE>
__global__ __launch_bounds__(256) void conv_mfma(
    const __hip_bfloat16* __restrict__ x,
    const __hip_bfloat16* __restrict__ wf,
    __hip_bfloat16* __restrict__ out)
{
  constexpr int CB = CIN / 32;

  const int bx = xcd_swz(blockIdx.x, gridDim.x);
  const int lane = threadIdx.x & 63;
  const int wid  = threadIdx.x >> 6;
  const int wm = wid >> 1, wn = wid & 1;
  const int mbase = bx * (MF * 32) + wm * (MF * 16);
  const int cobase = blockIdx.y * 64 + wn * 32;

  int offm[MF];
  #pragma unroll
  for (int mf = 0; mf < MF; ++mf) {
    int m = mbase + mf * 16 + (lane & 15);
    offm[mf] = m * CIN;
  }
  const int koff = (lane >> 4) << 3;
  const __hip_bfloat16* wfp = wf + ((size_t)((blockIdx.y * 4 + wn * 2) * 64 + lane)) * 8;

  f32x4 acc[MF][2];
  #pragma unroll
  for (int mf = 0; mf < MF; ++mf) {
    acc[mf][0] = (f32x4){0.f, 0.f, 0.f, 0.f};
    acc[mf][1] = (f32x4){0.f, 0.f, 0.f, 0.f};
  }

  #pragma unroll
  for (int cb = 0; cb < CB; ++cb) {
    bf16x8 a[MF], b[2];
    #pragma unroll
    for (int mf = 0; mf < MF; ++mf) a[mf] = *(const bf16x8*)(x + offm[mf] + koff + cb * 32);
    #pragma unroll
    for (int nf = 0; nf < 2; ++nf)
      b[nf] = *(const bf16x8*)(wfp + (size_t)cb * (COUT * 32) + nf * 512);
    #pragma unroll
    for (int mf = 0; mf < MF; ++mf)
      #pragma unroll
      for (int nf = 0; nf < 2; ++nf)
        acc[mf][nf] = __builtin_amdgcn_mfma_f32_16x16x32_bf16(a[mf], b[nf], acc[mf][nf], 0, 0, 0);
  }

  const int r0 = (lane >> 4) * 4;
  const int cw = cobase + (lane & 15);
  #pragma unroll
  for (int mf = 0; mf < MF; ++mf)
    #pragma unroll
    for (int nf = 0; nf < 2; ++nf)
      #pragma unroll
      for (int r = 0; r < 4; ++r) {
        float v = acc[mf][nf][r];
        if (FUSE) v = (v >= 0.f) ? v : LRELU * v;
        int m = mbase + mf * 16 + r0 + r;
        out[(size_t)m * COUT + (cw + nf * 16)] = __float2bfloat16(v);
      }
}

// ---------------------------------------------------------------- LDS-staged 128x128 conv, k4 s2 p1
// XOR-swizzled As (chunk ^= row&3, both write and read) -> conflict-free b128.
template<int CIN, int COUT, int HIN, int HOUT, int Z, bool SPLITK, bool BNIN>
__global__ __launch_bounds__(256) void conv_lds(
    const __hip_bfloat16* __restrict__ x,
    const __hip_bfloat16* __restrict__ wf,
    const float* __restrict__ sbp,
    __hip_bfloat16* __restrict__ outb)
{
  constexpr int WIN = HIN, WO = HOUT;
  constexpr int CB = CIN / 32;
  constexpr int KHW_PER = 16 / Z;
  constexpr int NSTEP = KHW_PER * CB;
  constexpr int PADOFF = 16777216;
  constexpr int M = 64 * HOUT * WO;

  __shared__ __hip_bfloat16 As[128 * 32];   // [row][4 chunks of 8], chunk XOR-swizzled
  __shared__ __hip_bfloat16 Bs[4096];       // [8 nfrag][64 lane][8]

  const int bx = xcd_swz(blockIdx.x, gridDim.x);
  const int t = threadIdx.x;
  const int lane = t & 63;
  const int wid = t >> 6;
  const int wm = wid >> 1, wn = wid & 1;
  const int mbase = bx * 128;
  const int nbase = blockIdx.y * 128;
  const int khw0 = blockIdx.z * KHW_PER;

  const int sr0 = t >> 2;
  const int sl  = t & 3;
  const int wchunk = sl ^ (sr0 & 3);        // swizzled store chunk (same for row sr0 and sr0+64)
  int rowbase[2], ihbs[2], iwbs[2];
  #pragma unroll
  for (int i = 0; i < 2; ++i) {
    int m = mbase + sr0 + i * 64;
    int n = m / (HOUT * WO);
    int hw = m - n * (HOUT * WO);
    int ho = hw / WO, wo = hw - ho * WO;
    ihbs[i] = 2 * ho - 1;
    iwbs[i] = 2 * wo - 1;
    rowbase[i] = ((n * HIN + ihbs[i]) * WIN + iwbs[i]) * CIN;
  }
  const size_t bslab0 = (size_t)(nbase >> 4) * 512 + (size_t)t * 8;

  f32x4 acc[4][4];
  #pragma unroll
  for (int mf = 0; mf < 4; ++mf)
    #pragma unroll
    for (int nf = 0; nf < 4; ++nf) acc[mf][nf] = (f32x4){0.f, 0.f, 0.f, 0.f};

  bf16x8 ra0, ra1, rb0, rb1;
  f32x4 sc0, sc1, of0, of1;
  bool v0 = true, v1 = true;
  auto load_step = [&](int ks) {
    const int khw = khw0 + ks / CB;
    const int cb = ks % CB;
    const int kh = khw >> 2, kw = khw & 3;
    const int kbyteoff = cb * 32 + sl * 8;
    {
      int ih = ihbs[0] + kh, iw = iwbs[0] + kw;
      v0 = ((unsigned)ih < (unsigned)HIN) & ((unsigned)iw < (unsigned)WIN);
      int off = v0 ? (rowbase[0] + (kh * WIN + kw) * CIN + kbyteoff) : PADOFF;
      ra0 = *(const bf16x8*)(x + off);
    }
    {
      int ih = ihbs[1] + kh, iw = iwbs[1] + kw;
      v1 = ((unsigned)ih < (unsigned)HIN) & ((unsigned)iw < (unsigned)WIN);
      int off = v1 ? (rowbase[1] + (kh * WIN + kw) * CIN + kbyteoff) : PADOFF;
      ra1 = *(const bf16x8*)(x + off);
    }
    const size_t kg = (size_t)khw * CB + cb;
    const size_t bo = kg * (COUT * 32) + bslab0;
    rb0 = *(const bf16x8*)(wf + bo);
    rb1 = *(const bf16x8*)(wf + bo + 2048);
    if (BNIN) {
      const int cbv = cb * 32 + sl * 8;
      sc0 = *(const f32x4*)(sbp + cbv);
      sc1 = *(const f32x4*)(sbp + cbv + 4);
      of0 = *(const f32x4*)(sbp + CIN + cbv);
      of1 = *(const f32x4*)(sbp + CIN + cbv + 4);
    }
  };

  load_step(0);
  for (int ks = 0; ks < NSTEP; ++ks) {
    __syncthreads();                         // prior step's ds_reads complete
    bf16x8 wa0 = ra0, wa1 = ra1;
    if (BNIN) {
      #pragma unroll
      for (int j = 0; j < 8; ++j) {
        float sc = (j < 4) ? sc0[j] : sc1[j - 4];
        float of = (j < 4) ? of0[j] : of1[j - 4];
        float f0 = fmaf(bf2f(wa0[j]), sc, of);
        f0 = fmaxf(f0, LRELU * f0);
        wa0[j] = v0 ? f2bf(f0) : (short)0;
        float f1 = fmaf(bf2f(wa1[j]), sc, of);
        f1 = fmaxf(f1, LRELU * f1);
        wa1[j] = v1 ? f2bf(f1) : (short)0;
      }
    }
    *(bf16x8*)(&As[sr0 * 32 + wchunk * 8]) = wa0;
    *(bf16x8*)(&As[(sr0 + 64) * 32 + wchunk * 8]) = wa1;
    *(bf16x8*)(&Bs[t * 8]) = rb0;
    *(bf16x8*)(&Bs[2048 + t * 8]) = rb1;
    __syncthreads();                         // tile visible
    if (ks + 1 < NSTEP) load_step(ks + 1);   // overlap next loads with MFMA
    bf16x8 af[4], bfr[4];
    #pragma unroll
    for (int mf = 0; mf < 4; ++mf) {
      const int ra = wm * 64 + mf * 16 + (lane & 15);
      const int rc = (lane >> 4) ^ (ra & 3);     // swizzled read chunk
      af[mf] = *(const bf16x8*)(&As[ra * 32 + rc * 8]);
    }
    #pragma unroll
    for (int nf = 0; nf < 4; ++nf)
      bfr[nf] = *(const bf16x8*)(&Bs[(wn * 4 + nf) * 512 + lane * 8]);
    #pragma unroll
    for (int mf = 0; mf < 4; ++mf)
      #pragma unroll
      for (int nf = 0; nf < 4; ++nf)
        acc[mf][nf] = __builtin_amdgcn_mfma_f32_16x16x32_bf16(af[mf], bfr[nf], acc[mf][nf], 0, 0, 0);
  }

  const int r0w = (lane >> 4) * 4;
  const int cw = nbase + wn * 64 + (lane & 15);
  #pragma unroll
  for (int mf = 0; mf < 4; ++mf)
    #pragma unroll
    for (int nf = 0; nf < 4; ++nf)
      #pragma unroll
      for (int r = 0; r < 4; ++r) {
        const int m = mbase + wm * 64 + mf * 16 + r0w + r;
        const int co = cw + nf * 16;
        if (SPLITK)
          outb[(size_t)blockIdx.z * M * COUT + (size_t)m * COUT + co] = __float2bfloat16(acc[mf][nf][r]);
        else
          outb[(size_t)m * COUT + co] = __float2bfloat16(acc[mf][nf][r]);
      }
}

// ---------------------------------------------------------------- 4x4-fragment implicit-GEMM conv (L5)
template<int CIN, int COUT, int HIN, int HOUT, int Z, bool SPLITK, bool BNIN, bool BF16P>
__global__ __launch_bounds__(256) void conv_mfma4(
    const __hip_bfloat16* __restrict__ x,
    const __hip_bfloat16* __restrict__ wf,
    const float* __restrict__ sbp,
    __hip_bfloat16* __restrict__ outb, float* __restrict__ outp)
{
  constexpr int WIN = HIN, WO = HOUT;
  constexpr int CB = CIN / 32;
  constexpr int KHW_PER = 16 / Z;
  constexpr int PADOFF = 16777216;
  constexpr int M = 64 * HOUT * WO;

  const int bx = xcd_swz(blockIdx.x, gridDim.x);
  const int lane = threadIdx.x & 63;
  const int wid  = threadIdx.x >> 6;
  const int wm = wid >> 1, wn = wid & 1;
  const int mbase = bx * 128 + wm * 64;
  const int nbase = blockIdx.y * 128 + wn * 64;
  const int khw0 = blockIdx.z * KHW_PER;

  int offm[4], ihb[4], iwb[4];
  #pragma unroll
  for (int mf = 0; mf < 4; ++mf) {
    int m = mbase + mf * 16 + (lane & 15);
    int n = m / (HOUT * WO);
    int hw = m - n * (HOUT * WO);
    int ho = hw / WO, wo = hw - ho * WO;
    ihb[mf] = 2 * ho - 1;
    iwb[mf] = 2 * wo - 1;
    offm[mf] = ((n * HIN + ihb[mf]) * WIN + iwb[mf]) * CIN;
  }
  const int koff = (lane >> 4) << 3;
  const __hip_bfloat16* wfp = wf + ((size_t)((nbase >> 4) * 64 + lane)) * 8;

  f32x4 acc[4][4];
  #pragma unroll
  for (int mf = 0; mf < 4; ++mf)
    #pragma unroll
    for (int nf = 0; nf < 4; ++nf) acc[mf][nf] = (f32x4){0.f, 0.f, 0.f, 0.f};

  #pragma unroll
  for (int cb = 0; cb < CB; ++cb) {
    f32x4 s0, s1, o0, o1;
    if (BNIN) {
      const int cbase = cb * 32 + koff;
      s0 = *(const f32x4*)(sbp + cbase);
      s1 = *(const f32x4*)(sbp + cbase + 4);
      o0 = *(const f32x4*)(sbp + CIN + cbase);
      o1 = *(const f32x4*)(sbp + CIN + cbase + 4);
    }
    #pragma unroll
    for (int ki = 0; ki < KHW_PER; ++ki) {
      const int khw = khw0 + ki;
      const int kh = khw >> 2, kw = khw & 3;
      bf16x8 a[4], b[4];
      bool vm[4];
      #pragma unroll
      for (int mf = 0; mf < 4; ++mf) {
        int ih = ihb[mf] + kh, iw = iwb[mf] + kw;
        vm[mf] = ((unsigned)ih < (unsigned)HIN) & ((unsigned)iw < (unsigned)WIN);
        int off = vm[mf] ? (offm[mf] + (kh * WIN + kw) * CIN + koff + cb * 32)
                         : (PADOFF + koff + cb * 32);
        a[mf] = *(const bf16x8*)(x + off);
      }
      const size_t ks = (size_t)khw * CB + cb;
      #pragma unroll
      for (int nf = 0; nf < 4; ++nf)
        b[nf] = *(const bf16x8*)(wfp + ks * (COUT * 32) + nf * 512);
      if (BNIN) {
        #pragma unroll
        for (int mf = 0; mf < 4; ++mf) {
          bf16x8 tt = a[mf];
          #pragma unroll
          for (int j = 0; j < 8; ++j) {
            float fv = bf2f(tt[j]);
            float sc = (j < 4) ? s0[j] : s1[j - 4];
            float of = (j < 4) ? o0[j] : o1[j - 4];
            fv = fmaf(fv, sc, of);
            fv = fmaxf(fv, LRELU * fv);
            tt[j] = vm[mf] ? f2bf(fv) : (short)0;
          }
          a[mf] = tt;
        }
      }
      #pragma unroll
      for (int mf = 0; mf < 4; ++mf)
        #pragma unroll
        for (int nf = 0; nf < 4; ++nf)
          acc[mf][nf] = __builtin_amdgcn_mfma_f32_16x16x32_bf16(a[mf], b[nf], acc[mf][nf], 0, 0, 0);
    }
  }

  const int r0 = (lane >> 4) * 4;
  const int cw = nbase + (lane & 15);
  #pragma unroll
  for (int mf = 0; mf < 4; ++mf)
    #pragma unroll
    for (int nf = 0; nf < 4; ++nf)
      #pragma unroll
      for (int r = 0; r < 4; ++r) {
        const int m = mbase + mf * 16 + r0 + r;
        const int co = cw + nf * 16;
        if (SPLITK) {
          if (BF16P)
            outb[(size_t)blockIdx.z * M * COUT + (size_t)m * COUT + co] = __float2bfloat16(acc[mf][nf][r]);
          else
            outp[(size_t)blockIdx.z * M * COUT + (size_t)m * COUT + co] = acc[mf][nf][r];
        } else {
          outb[(size_t)m * COUT + co] = __float2bfloat16(acc[mf][nf][r]);
        }
      }
}

// ---------------------------------------------------------------- fused: split-K reduce + bf16 write + BN partial stats
template<int Z, int MCHUNKS, bool BF16P>
__global__ __launch_bounds__(256) void sk_bn_fuse(const float* __restrict__ partf,
                                                  const __hip_bfloat16* __restrict__ partb,
                                                  __hip_bfloat16* __restrict__ xo,
                                                  float* __restrict__ statp, int M, int C) {
  const int chunk = blockIdx.x;
  const int c0 = blockIdx.y * 64 + (threadIdx.x & 7) * 8;
  const int mrow = threadIdx.x >> 3;
  const int rows = M / MCHUNKS;
  const size_t MC = (size_t)M * C;
  float s[8], s2[8];
  #pragma unroll
  for (int j = 0; j < 8; ++j) { s[j] = 0.f; s2[j] = 0.f; }
  for (int mi = mrow; mi < rows; mi += 32) {
    const int m = chunk * rows + mi;
    const size_t base = (size_t)m * C + c0;
    float av[8];
    if (BF16P) {
      bf16x8 v0 = *(const bf16x8*)(partb + base);
      #pragma unroll
      for (int j = 0; j < 8; ++j) av[j] = bf2f(v0[j]);
      #pragma unroll
      for (int z = 1; z < Z; ++z) {
        bf16x8 vz = *(const bf16x8*)(partb + (size_t)z * MC + base);
        #pragma unroll
        for (int j = 0; j < 8; ++j) av[j] += bf2f(vz[j]);
      }
    } else {
      f32x4 a = *(const f32x4*)(partf + base);
      f32x4 b = *(const f32x4*)(partf + base + 4);
      #pragma unroll
      for (int z = 1; z < Z; ++z) {
        a += *(const f32x4*)(partf + (size_t)z * MC + base);
        b += *(const f32x4*)(partf + (size_t)z * MC + base + 4);
      }
      #pragma unroll
      for (int j = 0; j < 4; ++j) { av[j] = a[j]; av[4 + j] = b[j]; }
    }
    bf16x8 o;
    #pragma unroll
    for (int j = 0; j < 8; ++j) {
      o[j] = f2bf(av[j]);
      s[j] += av[j];
      s2[j] = fmaf(av[j], av[j], s2[j]);
    }
    *(bf16x8*)(xo + base) = o;
  }
  __shared__ float ls[8][256], ls2[8][256];
  const int t = threadIdx.x;
  #pragma unroll
  for (int j = 0; j < 8; ++j) { ls[j][t] = s[j]; ls2[j][t] = s2[j]; }
  __syncthreads();
  #pragma unroll
  for (int off = 16; off >= 1; off >>= 1) {
    if (mrow < off) {
      #pragma unroll
      for (int j = 0; j < 8; ++j) {
        ls[j][t]  += ls[j][t + off * 8];
        ls2[j][t] += ls2[j][t + off * 8];
      }
    }
    __syncthreads();
  }
  if (t < 8) {
    #pragma unroll
    for (int j = 0; j < 8; ++j) {
      statp[(size_t)chunk * C + c0 + j] = ls[j][t];
      statp[(size_t)(MCHUNKS + chunk) * C + c0 + j] = ls2[j][t];
    }
  }
}

// ---------------------------------------------------------------- L6 MFMA conv (plain); writes flat part of out
__global__ __launch_bounds__(256) void conv_l6_mfma(
    const __hip_bfloat16* __restrict__ x,
    const __hip_bfloat16* __restrict__ wf,
    float* __restrict__ x6, float* __restrict__ out)
{
  constexpr int CIN = 512, COUT = 64, HIN = 4;
  constexpr int CB = CIN / 32;
  constexpr int PADOFF = 16777216;

  const int lane = threadIdx.x & 63;
  const int wid  = threadIdx.x >> 6;
  const int wm = wid >> 1, wn = wid & 1;
  const int mbase = blockIdx.x * 32 + wm * 16;

  int m0 = mbase + (lane & 15);
  int n = m0 >> 2;
  int hw = m0 & 3;
  int ho = hw >> 1, wo = hw & 1;
  int ihb = 2 * ho - 1;
  int iwb = 2 * wo - 1;
  int offm = ((n * HIN + ihb) * HIN + iwb) * CIN;

  const int koff = (lane >> 4) << 3;
  const __hip_bfloat16* wfp = wf + ((size_t)((wn * 2) * 64 + lane)) * 8;

  f32x4 acc[2];
  acc[0] = (f32x4){0.f, 0.f, 0.f, 0.f};
  acc[1] = (f32x4){0.f, 0.f, 0.f, 0.f};

  #pragma unroll
  for (int khw = 0; khw < 16; ++khw) {
    const int kh = khw >> 2, kw = khw & 3;
    const int ih = ihb + kh, iw = iwb + kw;
    const bool v = ((unsigned)ih < (unsigned)HIN) & ((unsigned)iw < (unsigned)HIN);
    const int off = v ? (offm + (kh * HIN + kw) * CIN + koff) : (PADOFF + koff);
    const __hip_bfloat16* ap = x + off;
    #pragma unroll
    for (int cb = 0; cb < CB; ++cb) {
      const int ks = khw * CB + cb;
      bf16x8 a = *(const bf16x8*)(ap + cb * 32);
      bf16x8 b0 = *(const bf16x8*)(wfp + (size_t)ks * (COUT * 32));
      bf16x8 b1 = *(const bf16x8*)(wfp + (size_t)ks * (COUT * 32) + 512);
      acc[0] = __builtin_amdgcn_mfma_f32_16x16x32_bf16(a, b0, acc[0], 0, 0, 0);
      acc[1] = __builtin_amdgcn_mfma_f32_16x16x32_bf16(a, b1, acc[1], 0, 0, 0);
    }
  }

  const int r0 = (lane >> 4) * 4;
  const int cw = wn * 32 + (lane & 15);
  #pragma unroll
  for (int nf = 0; nf < 2; ++nf)
    #pragma unroll
    for (int r = 0; r < 4; ++r) {
      int m = mbase + r0 + r;
      int nn = m >> 2, p = m & 3;
      float v = acc[nf][r];
      x6[(size_t)nn * 256 + (cw + nf * 16) * 4 + p] = v;
      out[(size_t)nn * 320 + (cw + nf * 16) * 4 + p] = v;
    }
}

// ---------------------------------------------------------------- BN stats (direct-output layers), vectorized
template<int MCHUNKS>
__global__ __launch_bounds__(256) void bn_stats_a(const __hip_bfloat16* __restrict__ x,
                                                  float* __restrict__ part, int M, int C) {
  const int chunk = blockIdx.x;
  const int c0 = blockIdx.y * 64 + (threadIdx.x & 7) * 8;
  const int mrow = threadIdx.x >> 3;
  const int rows = M / MCHUNKS;
  float s[8], s2[8];
  #pragma unroll
  for (int j = 0; j < 8; ++j) { s[j] = 0.f; s2[j] = 0.f; }
  for (int mi = mrow; mi < rows; mi += 32) {
    const int m = chunk * rows + mi;
    bf16x8 v = *(const bf16x8*)(x + (size_t)m * C + c0);
    #pragma unroll
    for (int j = 0; j < 8; ++j) {
      float f = bf2f(v[j]);
      s[j] += f;
      s2[j] = fmaf(f, f, s2[j]);
    }
  }
  __shared__ float ls[8][256], ls2[8][256];
  const int t = threadIdx.x;
  #pragma unroll
  for (int j = 0; j < 8; ++j) { ls[j][t] = s[j]; ls2[j][t] = s2[j]; }
  __syncthreads();
  #pragma unroll
  for (int off = 16; off >= 1; off >>= 1) {
    if (mrow < off) {
      #pragma unroll
      for (int j = 0; j < 8; ++j) {
        ls[j][t]  += ls[j][t + off * 8];
        ls2[j][t] += ls2[j][t + off * 8];
      }
    }
    __syncthreads();
  }
  if (t < 8) {
    #pragma unroll
    for (int j = 0; j < 8; ++j) {
      part[(size_t)chunk * C + c0 + j] = ls[j][t];
      part[(size_t)(MCHUNKS + chunk) * C + c0 + j] = ls2[j][t];
    }
  }
}

template<int MCHUNKS>
__global__ __launch_bounds__(64) void bn_stats_b(const float* __restrict__ part,
                                                 const float* __restrict__ g,
                                                 const float* __restrict__ b,
                                                 float* __restrict__ sb, int M, int C) {
  int c = blockIdx.x * 64 + threadIdx.x;
  float s = 0.f, s2 = 0.f;
  for (int ch = 0; ch < MCHUNKS; ++ch) {
    s  += part[(size_t)ch * C + c];
    s2 += part[(size_t)(MCHUNKS + ch) * C + c];
  }
  float invM = 1.f / (float)M;
  float mean = s * invM;
  float var = s2 * invM - mean * mean;
  float scale = g[c] * rsqrtf(var + BN_EPS);
  sb[c] = scale;
  sb[C + c] = b[c] - mean * scale;
}

// ---------------------------------------------------------------- BN apply (only x5 before L6)
__global__ __launch_bounds__(256) void bn_apply(__hip_bfloat16* __restrict__ x,
                                                const float* __restrict__ sb,
                                                int C, int nvec) {
  int idx = blockIdx.x * 256 + threadIdx.x;
  if (idx >= nvec) return;
  size_t e = (size_t)idx * 8;
  int c0 = (int)(e % (size_t)C);
  bf16x8 v = *(bf16x8*)(x + e);
  bf16x8 o;
  #pragma unroll
  for (int j = 0; j < 8; ++j) {
    int c = c0 + j;
    float f = bf2f(v[j]);
    f = fmaf(f, sb[c], sb[C + c]);
    f = (f >= 0.f) ? f : LRELU * f;
    o[j] = f2bf(f);
  }
  *(bf16x8*)(x + e) = o;
}

// ---------------------------------------------------------------- tail: Ms = flat @ T (256 blocks)
__global__ __launch_bounds__(256) void ms_kernel(const float* __restrict__ x6,
                                                 const float* __restrict__ T,
                                                 float* __restrict__ Ms) {
  const int cb = blockIdx.x;
  const int nb = blockIdx.y;
  const int c  = threadIdx.x & 63;
  const int ns = threadIdx.x >> 6;
  __shared__ float fsh[16][256];
  for (int t = threadIdx.x; t < 4096; t += 256) {
    int n = t >> 8, a = t & 255;
    fsh[n][a] = x6[(size_t)(nb * 16 + n) * 256 + a];
  }
  __syncthreads();
  const int col = cb * 64 + c;
  float acc0 = 0.f, acc1 = 0.f, acc2 = 0.f, acc3 = 0.f;
  #pragma unroll 8
  for (int a = 0; a < 256; ++a) {
    float tv = T[(size_t)a * 4096 + col];
    acc0 = fmaf(fsh[ns * 4 + 0][a], tv, acc0);
    acc1 = fmaf(fsh[ns * 4 + 1][a], tv, acc1);
    acc2 = fmaf(fsh[ns * 4 + 2][a], tv, acc2);
    acc3 = fmaf(fsh[ns * 4 + 3][a], tv, acc3);
  }
  const int nbase = nb * 16 + ns * 4;
  Ms[(size_t)(nbase + 0) * 4096 + col] = acc0;
  Ms[(size_t)(nbase + 1) * 4096 + col] = acc1;
  Ms[(size_t)(nbase + 2) * 4096 + col] = acc2;
  Ms[(size_t)(nbase + 3) * 4096 + col] = acc3;
}

// ---------------------------------------------------------------- minibatch discrimination (256 blocks)
__global__ __launch_bounds__(256) void mbd_kernel(const float* __restrict__ Ms,
                                                  float* __restrict__ out) {
  const int b  = blockIdx.x;
  const int ib = blockIdx.y;
  const int tid = threadIdx.x;
  __shared__ float Mb[64][65];
  for (int idx = tid; idx < 4096; idx += 256) {
    const int i = idx >> 6, cc = idx & 63;
    Mb[i][cc] = Ms[(size_t)i * 4096 + b * 64 + cc];
  }
  __syncthreads();
  const int i  = ib * 16 + (tid >> 4);
  const int jg = tid & 15;
  float ssum = 0.f;
  for (int j = jg; j < 64; j += 16) {
    float d = 0.f;
    #pragma unroll
    for (int cc = 0; cc < 64; ++cc) d += fabsf(Mb[i][cc] - Mb[j][cc]);
    ssum += expf(-d);
  }
  ssum += __shfl_xor(ssum, 1, 64);
  ssum += __shfl_xor(ssum, 2, 64);
  ssum += __shfl_xor(ssum, 4, 64);
  ssum += __shfl_xor(ssum, 8, 64);
  if (jg == 0) out[(size_t)i * 320 + 256 + b] = ssum;
}

// ---------------------------------------------------------------- launch
extern "C" void kernel_launch(void* const* d_in, const int* in_sizes, int n_in,
                              void* d_out, int out_size, void* d_ws, size_t ws_size,
                              hipStream_t stream) {
  const float* image = (const float*)d_in[0];
  const float* W[6] = {(const float*)d_in[1], (const float*)d_in[3], (const float*)d_in[5],
                       (const float*)d_in[7], (const float*)d_in[9], (const float*)d_in[11]};
  const float* U[6] = {(const float*)d_in[2], (const float*)d_in[4], (const float*)d_in[6],
                       (const float*)d_in[8], (const float*)d_in[10], (const float*)d_in[12]};
  const float* G[4] = {(const float*)d_in[13], (const float*)d_in[15],
                       (const float*)d_in[17], (const float*)d_in[19]};
  const float* Bb[4] = {(const float*)d_in[14], (const float*)d_in[16],
                        (const float*)d_in[18], (const float*)d_in[20]};
  const float* T = (const float*)d_in[21];
  float* out = (float*)d_out;

  // ---- workspace layout (floats)
  float* f = (float*)d_ws;
  float* inv_sigma = f;                                // 16
  float* part      = f + 1024;                         // 65536
  float* x6        = f + 1024 + 65536 + 1024;          // 16384
  float* Ms        = f + 1024 + 65536 + 1024 + 16384;  // 262144
  float* vbuf      = f + 360448;                       // 49152
  float* pA        = f + 360448 + 49152;               // 256 slots
  float* pB        = pA + 256;                         // 768
  float* rinv      = pB + 768;                         // 16
  float* sbL[4];                                       // per-layer BN scale/bias
  for (int i = 0; i < 4; ++i) sbL[i] = f + 412672 + i * 2048;
  __hip_bfloat16* bfb = (__hip_bfloat16*)(f + 524288);
  const size_t REGION = 16777216 + 2048;
  __hip_bfloat16* region0 = bfb;
  __hip_bfloat16* region1 = region0 + REGION;
  __hip_bfloat16* wf1 = region1 + REGION;
  __hip_bfloat16* wf2 = wf1 + 4096;
  __hip_bfloat16* wf3 = wf2 + 131072;
  __hip_bfloat16* wf4 = wf3 + 524288;
  __hip_bfloat16* wf5 = wf4 + 1048576;
  __hip_bfloat16* wf6 = wf5 + 2097152;
  float* skpart = (float*)(wf6 + 524288);              // 8388608 floats (also used as bf16)
  __hip_bfloat16* skpartb = (__hip_bfloat16*)skpart;
  float* vpart  = skpart + 8388608;                    // 393216 floats

  __hip_bfloat16* a2col = region0;
  __hip_bfloat16* x1 = region1;
  __hip_bfloat16* x2 = region0;
  __hip_bfloat16* x3 = region1;
  __hip_bfloat16* x4 = region0;
  __hip_bfloat16* x5 = region1;

  zero_pads<<<8, 256, 0, stream>>>(region0, region1);

  SNArgs sa;
  const int outc[6] = {64, 128, 256, 256, 512, 64};
  const int ink[6]  = {48, 1024, 2048, 4096, 4096, 8192};
  for (int l = 0; l < 6; ++l) { sa.w[l] = W[l]; sa.u[l] = U[l]; sa.outc[l] = outc[l]; sa.ink[l] = ink[l]; }

  sn_v<<<dim3(32, 8, 6), 256, 0, stream>>>(sa, vpart);
  sn_v_red<<<dim3(32, 6), 256, 0, stream>>>(sa, vpart, vbuf, pA);
  sn_norm1<<<6, 64, 0, stream>>>(sa, pA, rinv);
  sn_t2<<<dim3(128, 6), 256, 0, stream>>>(sa, vbuf, rinv, pB);
  sn_norm2<<<6, 64, 0, stream>>>(pB, inv_sigma);

  PPArgs pa;
  __hip_bfloat16* wfp_[6] = {wf1, wf2, wf3, wf4, wf5, wf6};
  const int cinr_[6]  = {3, 64, 128, 256, 256, 512};
  const int kpad_[6]  = {64, 1024, 2048, 4096, 4096, 8192};
  const int kreal_[6] = {48, 1024, 2048, 4096, 4096, 8192};
  for (int l = 0; l < 6; ++l) {
    pa.w[l] = W[l]; pa.dst[l] = wfp_[l]; pa.cinr[l] = cinr_[l];
    pa.cout[l] = outc[l]; pa.kpad[l] = kpad_[l]; pa.kreal[l] = kreal_[l];
  }
  prepack_all<<<dim3(8192, 6), 256, 0, stream>>>(pa, inv_sigma);

  im2col_l1<<<8192, 256, 0, stream>>>(image, a2col);

  // L1: [262144 x 64] @ [64 x 64], fused lrelu
  conv_mfma<64, 64, 4, true><<<dim3(2048, 1), 256, 0, stream>>>(a2col, wf1, x1);

  // L2: LDS-staged (swizzled), raw input, direct bf16 out
  conv_lds<64, 128, 64, 32, 1, false, false><<<dim3(512, 1, 1), 256, 0, stream>>>(x1, wf2, nullptr, x2);
  bn_stats_a<256><<<dim3(256, 2), 256, 0, stream>>>(x2, part, 65536, 128);
  bn_stats_b<256><<<2, 64, 0, stream>>>(part, G[0], Bb[0], sbL[0], 65536, 128);

  // L3: LDS-staged (swizzled), BN1+lrelu at stage, split-K Z=2 (bf16 partials); fused reduce+stats
  conv_lds<128, 256, 32, 16, 2, true, true><<<dim3(128, 2, 2), 256, 0, stream>>>(x2, wf3, sbL[0], skpartb);
  sk_bn_fuse<2, 128, true><<<dim3(128, 4), 256, 0, stream>>>(nullptr, skpartb, x3, part, 16384, 256);
  bn_stats_b<128><<<4, 64, 0, stream>>>(part, G[1], Bb[1], sbL[1], 16384, 256);

  // L4: LDS-staged (swizzled), BN2+lrelu at stage, split-K Z=8 (bf16 partials); fused reduce+stats
  conv_lds<256, 256, 16, 8, 8, true, true><<<dim3(32, 2, 8), 256, 0, stream>>>(x3, wf4, sbL[1], skpartb);
  sk_bn_fuse<8, 128, true><<<dim3(128, 4), 256, 0, stream>>>(nullptr, skpartb, x4, part, 4096, 256);
  bn_stats_b<128><<<4, 64, 0, stream>>>(part, G[2], Bb[2], sbL[2], 4096, 256);

  // L5: fragment-direct, BN3+lrelu fused; split-K Z=16 (bf16 partials); fused reduce+stats
  conv_mfma4<256, 512, 8, 4, 16, true, true, true><<<dim3(8, 4, 16), 256, 0, stream>>>(x4, wf5, sbL[2], skpartb, nullptr);
  sk_bn_fuse<16, 32, true><<<dim3(32, 8), 256, 0, stream>>>(nullptr, skpartb, x5, part, 1024, 512);
  bn_stats_b<32><<<8, 64, 0, stream>>>(part, G[3], Bb[3], sbL[3], 1024, 512);

  // BN4 apply on x5 (tiny: 1 MB), then plain L6
  bn_apply<<<256, 256, 0, stream>>>(x5, sbL[3], 512, 65536);
  conv_l6_mfma<<<8, 256, 0, stream>>>(x5, wf6, x6, out);

  ms_kernel<<<dim3(64, 4), 256, 0, stream>>>(x6, T, Ms);
  mbd_kernel<<<dim3(64, 4), 256, 0, stream>>>(Ms, out);
}